// Round 1
// baseline (1462.093 us; speedup 1.0000x reference)
//
#include <hip/hip_runtime.h>
#include <hip/hip_bf16.h>
#include <math.h>

// Problem dims (fixed by reference)
#define BB   256      // batch
#define LDE  64       // desc tokens len
#define NO   10240    // outer nodes
#define LO   32       // x tokens len
#define NM   81920    // mini nodes
#define LM   16       // mini tokens len
#define EO   81920    // outer edges
#define EM   327680   // mini edges
#define ED   128      // embed dim E
#define HIDD 256      // hidden
#define NH   8        // heads
#define DH   16       // head dim

// ---- monotone float<->uint mapping for atomicMax on floats ----
static __device__ __forceinline__ unsigned fkey(float f) {
  unsigned u = __float_as_uint(f);
  return (u & 0x80000000u) ? ~u : (u | 0x80000000u);
}
static __device__ __forceinline__ float funkey(unsigned k) {
  return (k & 0x80000000u) ? __uint_as_float(k & 0x7fffffffu) : __uint_as_float(~k);
}

// ---- embedding masked mean: one block (128 thr) per row ----
template<int L>
__global__ void embed_mean_k(const int* __restrict__ tokens, const float* __restrict__ table,
                             float* __restrict__ out) {
  int n = blockIdx.x, e = threadIdx.x;
  __shared__ int toks[L];
  if (threadIdx.x < L) toks[threadIdx.x] = tokens[(size_t)n * L + threadIdx.x];
  __syncthreads();
  float s = 0.f; int cnt = 0;
  #pragma unroll
  for (int l = 0; l < L; ++l) {
    int t = toks[l];
    if (t != 0) { s += table[(size_t)t * ED + e]; ++cnt; }
  }
  out[(size_t)n * ED + e] = s / (float)(cnt > 0 ? cnt : 1);
}

// ---- row GEMM: out[n,m] = sum_k A[n,k]*W[k,m] + bias[m]; block = M threads ----
__global__ void row_gemm_k(const float* __restrict__ A, const float* __restrict__ W,
                           const float* __restrict__ bias, float* __restrict__ out,
                           int K, int M) {
  int n = blockIdx.x, m = threadIdx.x;
  extern __shared__ float as[];
  const float* a = A + (size_t)n * K;
  for (int k = threadIdx.x; k < K; k += blockDim.x) as[k] = a[k];
  __syncthreads();
  float acc = bias ? bias[m] : 0.f;
  #pragma unroll 8
  for (int k = 0; k < K; ++k) acc = fmaf(as[k], W[(size_t)k * M + m], acc);
  out[(size_t)n * M + m] = acc;
}

// ---- transformer conv edge passes ----
__global__ void edge_score_k(const float* __restrict__ q, const float* __restrict__ kk,
                             const int* __restrict__ src, const int* __restrict__ dst,
                             float* __restrict__ score, unsigned* __restrict__ mbuf) {
  int idx = blockIdx.x * blockDim.x + threadIdx.x;
  if (idx >= EM * NH) return;
  int e = idx >> 3, h = idx & 7;
  int sn = src[e], dn = dst[e];
  const float* qp = q  + (size_t)dn * ED + h * DH;
  const float* kp = kk + (size_t)sn * ED + h * DH;
  float acc = 0.f;
  #pragma unroll
  for (int d = 0; d < DH; ++d) acc = fmaf(qp[d], kp[d], acc);
  acc *= 0.25f;  // 1/sqrt(16)
  score[idx] = acc;
  atomicMax(&mbuf[(size_t)dn * NH + h], fkey(acc));
}

__global__ void edge_exp_k(const int* __restrict__ dst, const unsigned* __restrict__ mbuf,
                           float* __restrict__ score, float* __restrict__ sbuf) {
  int idx = blockIdx.x * blockDim.x + threadIdx.x;
  if (idx >= EM * NH) return;
  int e = idx >> 3, h = idx & 7;
  int dn = dst[e];
  float m = funkey(mbuf[(size_t)dn * NH + h]);
  float ex = expf(score[idx] - m);
  score[idx] = ex;
  atomicAdd(&sbuf[(size_t)dn * NH + h], ex);
}

__global__ void edge_agg_k(const int* __restrict__ src, const int* __restrict__ dst,
                           const float* __restrict__ ebuf, const float* __restrict__ sbuf,
                           const float* __restrict__ v, float* __restrict__ hid) {
  int idx = blockIdx.x * blockDim.x + threadIdx.x;
  if (idx >= EM * ED) return;
  int e = idx >> 7, c = idx & 127, h = c >> 4;
  int sn = src[e], dn = dst[e];
  float alpha = ebuf[(size_t)e * NH + h] / (sbuf[(size_t)dn * NH + h] + 1e-16f);
  atomicAdd(&hid[(size_t)dn * ED + c], alpha * v[(size_t)sn * ED + c]);
}

// ---- gate = x @ Wg + bg : one wave per row ----
__global__ void gate_k(const float* __restrict__ x, const float* __restrict__ Wg,
                       const float* __restrict__ bg, float* __restrict__ gate) {
  int n = blockIdx.x, lane = threadIdx.x;
  float a = fmaf(x[(size_t)n * ED + lane], Wg[lane],
                 x[(size_t)n * ED + 64 + lane] * Wg[64 + lane]);
  #pragma unroll
  for (int o = 32; o > 0; o >>= 1) a += __shfl_down(a, o, 64);
  if (lane == 0) gate[n] = a + bg[0];
}

// ---- generic segment softmax over a scalar array ----
__global__ void seg_max_k(const float* __restrict__ val, const int* __restrict__ seg,
                          unsigned* __restrict__ mx, int N) {
  int i = blockIdx.x * blockDim.x + threadIdx.x;
  if (i >= N) return;
  atomicMax(&mx[seg[i]], fkey(val[i]));
}
__global__ void seg_exp_k(float* __restrict__ val, const int* __restrict__ seg,
                          const unsigned* __restrict__ mx, float* __restrict__ sum, int N) {
  int i = blockIdx.x * blockDim.x + threadIdx.x;
  if (i >= N) return;
  float e = expf(val[i] - funkey(mx[seg[i]]));
  val[i] = e;
  atomicAdd(&sum[seg[i]], e);
}
__global__ void seg_wsum_k(const float* __restrict__ x, const float* __restrict__ eg,
                           const float* __restrict__ gsum, const int* __restrict__ seg,
                           float* __restrict__ out, int N) {
  int idx = blockIdx.x * blockDim.x + threadIdx.x;
  if (idx >= N * ED) return;
  int n = idx >> 7, c = idx & 127;
  int b = seg[n];
  float a = eg[n] / (gsum[b] + 1e-16f);
  atomicAdd(&out[(size_t)b * ED + c], a * x[(size_t)n * ED + c]);
}

// ---- elementwise ----
__global__ void combine_half_k(float* __restrict__ a, const float* __restrict__ b, int N) {
  int i = blockIdx.x * blockDim.x + threadIdx.x;
  if (i < N) a[i] = (a[i] + b[i]) * 0.5f;
}
__global__ void relu_k(float* __restrict__ a, int N) {
  int i = blockIdx.x * blockDim.x + threadIdx.x;
  if (i < N) a[i] = fmaxf(a[i], 0.f);
}

// ---- GCN ----
__global__ void deg_init_k(float* __restrict__ d, int N) {
  int i = blockIdx.x * blockDim.x + threadIdx.x;
  if (i < N) d[i] = 1.f;   // self loop
}
__global__ void deg_acc_k(const int* __restrict__ dst, float* __restrict__ d, int E) {
  int i = blockIdx.x * blockDim.x + threadIdx.x;
  if (i < E) atomicAdd(&d[dst[i]], 1.f);
}
__global__ void deg_inv_k(float* __restrict__ d, int N) {
  int i = blockIdx.x * blockDim.x + threadIdx.x;
  if (i < N) d[i] = 1.f / sqrtf(d[i]);
}
__global__ void gcn_self_k(const float* __restrict__ xw, const float* __restrict__ dinv,
                           const float* __restrict__ bias, float* __restrict__ out,
                           int N, int M) {
  int idx = blockIdx.x * blockDim.x + threadIdx.x;
  if (idx >= N * M) return;
  int n = idx / M, m = idx - n * M;
  float di = dinv[n];
  out[idx] = bias[m] + xw[idx] * di * di;
}
__global__ void gcn_edge_k(const int* __restrict__ src, const int* __restrict__ dst,
                           const float* __restrict__ xw, const float* __restrict__ dinv,
                           float* __restrict__ out, int E, int M) {
  int idx = blockIdx.x * blockDim.x + threadIdx.x;
  if (idx >= E * M) return;
  int e = idx / M, m = idx - e * M;
  int s = src[e], d = dst[e];
  atomicAdd(&out[(size_t)d * M + m], dinv[s] * dinv[d] * xw[(size_t)s * M + m]);
}

// ---- cosine similarity: one wave per batch row ----
__global__ void cosine_k(const float* __restrict__ a, const float* __restrict__ b,
                         float* __restrict__ out) {
  int n = blockIdx.x, lane = threadIdx.x;
  float x0 = a[(size_t)n * ED + lane], x1 = a[(size_t)n * ED + 64 + lane];
  float y0 = b[(size_t)n * ED + lane], y1 = b[(size_t)n * ED + 64 + lane];
  float dot = x0 * y0 + x1 * y1;
  float na = x0 * x0 + x1 * x1;
  float nb = y0 * y0 + y1 * y1;
  #pragma unroll
  for (int o = 32; o > 0; o >>= 1) {
    dot += __shfl_down(dot, o, 64);
    na  += __shfl_down(na,  o, 64);
    nb  += __shfl_down(nb,  o, 64);
  }
  if (lane == 0)
    out[n] = dot / (fmaxf(sqrtf(na), 1e-8f) * fmaxf(sqrtf(nb), 1e-8f));
}

// ---- workspace layout (float offsets) ----
constexpr size_t OFF_HN    = 0;                                  // BB*ED
constexpr size_t OFF_STMT  = OFF_HN    + (size_t)BB * ED;        // NO*ED
constexpr size_t OFF_A     = OFF_STMT  + (size_t)NO * ED;        // NM*ED (mini_emb, recycled)
constexpr size_t OFF_QHID  = OFF_A     + (size_t)NM * ED;        // NM*ED (q, then hid)
constexpr size_t OFF_K     = OFF_QHID  + (size_t)NM * ED;        // NM*ED
constexpr size_t OFF_V     = OFF_K     + (size_t)NM * ED;        // NM*ED
constexpr size_t OFF_SCORE = OFF_V     + (size_t)NM * ED;        // EM*NH
constexpr size_t OFF_M     = OFF_SCORE + (size_t)EM * NH;        // NM*NH (uint)
constexpr size_t OFF_S     = OFF_M     + (size_t)NM * NH;        // NM*NH
constexpr size_t OFF_GATE  = OFF_S     + (size_t)NM * NH;        // NM
constexpr size_t OFF_GMAX  = OFF_GATE  + (size_t)NM;             // NO (uint)
constexpr size_t OFF_GSUM  = OFF_GMAX  + (size_t)NO;             // NO
constexpr size_t OFF_GMAX2 = OFF_GSUM  + (size_t)NO;             // BB (uint)
constexpr size_t OFF_GSUM2 = OFF_GMAX2 + (size_t)BB;             // BB
constexpr size_t OFF_FNREP = OFF_GSUM2 + (size_t)BB;             // BB*ED
// region-A recycled sub-buffers (after mini_emb is dead):
constexpr size_t OFF_MFN   = OFF_A;                              // NO*ED
constexpr size_t OFF_DINV  = OFF_MFN   + (size_t)NO * ED;        // NO
constexpr size_t OFF_XW    = OFF_DINV  + (size_t)NO;             // NO*HIDD
constexpr size_t OFF_H     = OFF_XW    + (size_t)NO * HIDD;      // NO*HIDD
constexpr size_t OFF_FIN   = OFF_H     + (size_t)NO * HIDD;      // NO*ED
constexpr size_t OFF_G2    = OFF_FIN   + (size_t)NO * ED;        // NO

static inline int nblk(long long n, int b) { return (int)((n + b - 1) / b); }

extern "C" void kernel_launch(void* const* d_in, const int* in_sizes, int n_in,
                              void* d_out, int out_size, void* d_ws, size_t ws_size,
                              hipStream_t stream) {
  const int* desc_tokens = (const int*)d_in[0];
  const int* x_tokens    = (const int*)d_in[1];
  const int* mini_tokens = (const int*)d_in[2];
  const int* src         = (const int*)d_in[3];
  const int* dst         = (const int*)d_in[4];
  const int* mini_src    = (const int*)d_in[5];
  const int* mini_dst    = (const int*)d_in[6];
  const int* mini_batch  = (const int*)d_in[7];
  const int* node_batch  = (const int*)d_in[8];
  const float* desc_table  = (const float*)d_in[9];
  const float* code_table  = (const float*)d_in[10];
  const float* code_table2 = (const float*)d_in[11];
  const float* Wq = (const float*)d_in[12]; const float* bq = (const float*)d_in[13];
  const float* Wk = (const float*)d_in[14]; const float* bk = (const float*)d_in[15];
  const float* Wv = (const float*)d_in[16]; const float* bv = (const float*)d_in[17];
  const float* Wskip = (const float*)d_in[18]; const float* bskip = (const float*)d_in[19];
  const float* W2 = (const float*)d_in[20]; const float* b2 = (const float*)d_in[21];
  const float* W3 = (const float*)d_in[22]; const float* b3 = (const float*)d_in[23];
  const float* Wg = (const float*)d_in[24]; const float* bg = (const float*)d_in[25];

  float* ws = (float*)d_ws;
  float* h_n   = ws + OFF_HN;
  float* stmt  = ws + OFF_STMT;
  float* miniE = ws + OFF_A;
  float* qhid  = ws + OFF_QHID;   // q, later hid
  float* kbuf  = ws + OFF_K;
  float* vbuf  = ws + OFF_V;
  float* score = ws + OFF_SCORE;
  unsigned* mbuf = (unsigned*)(ws + OFF_M);
  float* sbuf  = ws + OFF_S;
  float* gate  = ws + OFF_GATE;
  unsigned* gmax = (unsigned*)(ws + OFF_GMAX);
  float* gsum  = ws + OFF_GSUM;
  unsigned* gmax2 = (unsigned*)(ws + OFF_GMAX2);
  float* gsum2 = ws + OFF_GSUM2;
  float* fnrep = ws + OFF_FNREP;
  // recycled region A
  float* mini_fn = ws + OFF_MFN;
  float* dinv    = ws + OFF_DINV;
  float* xw      = ws + OFF_XW;
  float* hbuf    = ws + OFF_H;
  float* finalS  = ws + OFF_FIN;
  float* gate2   = ws + OFF_G2;
  float* outp    = (float*)d_out;

  // 1) embeddings
  embed_mean_k<LDE><<<BB, ED, 0, stream>>>(desc_tokens, desc_table, h_n);
  embed_mean_k<LO> <<<NO, ED, 0, stream>>>(x_tokens, code_table2, stmt);
  embed_mean_k<LM> <<<NM, ED, 0, stream>>>(mini_tokens, code_table, miniE);

  // 2) q,k,v
  row_gemm_k<<<NM, ED, ED * sizeof(float), stream>>>(miniE, Wq, bq, qhid, ED, ED);
  row_gemm_k<<<NM, ED, ED * sizeof(float), stream>>>(miniE, Wk, bk, kbuf, ED, ED);
  row_gemm_k<<<NM, ED, ED * sizeof(float), stream>>>(miniE, Wv, bv, vbuf, ED, ED);

  // 3) edge scores + segment max
  hipMemsetAsync(mbuf, 0, (size_t)NM * NH * 4, stream);
  hipMemsetAsync(sbuf, 0, (size_t)NM * NH * 4, stream);
  edge_score_k<<<nblk((long long)EM * NH, 256), 256, 0, stream>>>(qhid, kbuf, mini_src, mini_dst, score, mbuf);

  // 4) skip projection overwrites q buffer (q consumed above)
  row_gemm_k<<<NM, ED, ED * sizeof(float), stream>>>(miniE, Wskip, bskip, qhid, ED, ED);

  // 5) softmax exp+sum, then aggregate into hid
  edge_exp_k<<<nblk((long long)EM * NH, 256), 256, 0, stream>>>(mini_dst, mbuf, score, sbuf);
  edge_agg_k<<<nblk((long long)EM * ED, 256), 256, 0, stream>>>(mini_src, mini_dst, score, sbuf, vbuf, qhid);

  // 6) global attention mini -> NO  (mini_emb region now dead -> becomes mini_fn)
  gate_k<<<NM, 64, 0, stream>>>(qhid, Wg, bg, gate);
  hipMemsetAsync(gmax, 0, (size_t)NO * 4, stream);
  hipMemsetAsync(gsum, 0, (size_t)NO * 4, stream);
  seg_max_k<<<nblk(NM, 256), 256, 0, stream>>>(gate, mini_batch, gmax, NM);
  seg_exp_k<<<nblk(NM, 256), 256, 0, stream>>>(gate, mini_batch, gmax, gsum, NM);
  hipMemsetAsync(mini_fn, 0, (size_t)NO * ED * 4, stream);
  seg_wsum_k<<<nblk((long long)NM * ED, 256), 256, 0, stream>>>(qhid, gate, gsum, mini_batch, mini_fn, NM);

  // 7) mini_fn = (mini_fn + stmt)*0.5
  combine_half_k<<<nblk((long long)NO * ED, 256), 256, 0, stream>>>(mini_fn, stmt, NO * ED);

  // 8) degrees (shared by both GCN convs)
  deg_init_k<<<nblk(NO, 256), 256, 0, stream>>>(dinv, NO);
  deg_acc_k<<<nblk(EO, 256), 256, 0, stream>>>(dst, dinv, EO);
  deg_inv_k<<<nblk(NO, 256), 256, 0, stream>>>(dinv, NO);

  // 9) GCN conv 1: mini_fn @ W2 -> [NO,256], normalize-scatter, +b2, relu
  row_gemm_k<<<NO, HIDD, ED * sizeof(float), stream>>>(mini_fn, W2, nullptr, xw, ED, HIDD);
  gcn_self_k<<<nblk((long long)NO * HIDD, 256), 256, 0, stream>>>(xw, dinv, b2, hbuf, NO, HIDD);
  gcn_edge_k<<<nblk((long long)EO * HIDD, 256), 256, 0, stream>>>(src, dst, xw, dinv, hbuf, EO, HIDD);
  relu_k<<<nblk((long long)NO * HIDD, 256), 256, 0, stream>>>(hbuf, NO * HIDD);

  // 10) GCN conv 2: h @ W3 -> [NO,128] (xw region reused)
  row_gemm_k<<<NO, ED, HIDD * sizeof(float), stream>>>(hbuf, W3, nullptr, xw, HIDD, ED);
  gcn_self_k<<<nblk((long long)NO * ED, 256), 256, 0, stream>>>(xw, dinv, b3, finalS, NO, ED);
  gcn_edge_k<<<nblk((long long)EO * ED, 256), 256, 0, stream>>>(src, dst, xw, dinv, finalS, EO, ED);

  // 11) global attention NO -> BB
  gate_k<<<NO, 64, 0, stream>>>(finalS, Wg, bg, gate2);
  hipMemsetAsync(gmax2, 0, (size_t)BB * 4, stream);
  hipMemsetAsync(gsum2, 0, (size_t)BB * 4, stream);
  seg_max_k<<<nblk(NO, 256), 256, 0, stream>>>(gate2, node_batch, gmax2, NO);
  seg_exp_k<<<nblk(NO, 256), 256, 0, stream>>>(gate2, node_batch, gmax2, gsum2, NO);
  hipMemsetAsync(fnrep, 0, (size_t)BB * ED * 4, stream);
  seg_wsum_k<<<nblk((long long)NO * ED, 256), 256, 0, stream>>>(finalS, gate2, gsum2, node_batch, fnrep, NO);

  // 12) cosine similarity -> d_out [BB]
  cosine_k<<<BB, 64, 0, stream>>>(fnrep, h_n, outp);
}

// Round 2
// 971.054 us; speedup vs baseline: 1.5057x; 1.5057x over previous
//
#include <hip/hip_runtime.h>
#include <hip/hip_bf16.h>
#include <math.h>

// Problem dims (fixed by reference)
#define BB   256      // batch
#define LDE  64       // desc tokens len
#define NO   10240    // outer nodes
#define LO   32       // x tokens len
#define NM   81920    // mini nodes
#define LM   16       // mini tokens len
#define EO   81920    // outer edges
#define EM   327680   // mini edges
#define ED   128      // embed dim E
#define HIDD 256      // hidden
#define NH   8        // heads
#define DH   16       // head dim

// ---- monotone float<->uint mapping for atomicMax on floats ----
static __device__ __forceinline__ unsigned fkey(float f) {
  unsigned u = __float_as_uint(f);
  return (u & 0x80000000u) ? ~u : (u | 0x80000000u);
}
static __device__ __forceinline__ float funkey(unsigned k) {
  return (k & 0x80000000u) ? __uint_as_float(k & 0x7fffffffu) : __uint_as_float(~k);
}

// ---- embedding masked mean: one block (128 thr) per row ----
template<int L>
__global__ void embed_mean_k(const int* __restrict__ tokens, const float* __restrict__ table,
                             float* __restrict__ out) {
  int n = blockIdx.x;
  __shared__ int toks[L];
  if (threadIdx.x < L) toks[threadIdx.x] = tokens[(size_t)n * L + threadIdx.x];
  __syncthreads();
  int e = threadIdx.x;
  float s = 0.f; int cnt = 0;
  #pragma unroll
  for (int l = 0; l < L; ++l) {
    int t = toks[l];
    if (t != 0) { s += table[(size_t)t * ED + e]; ++cnt; }
  }
  out[(size_t)n * ED + e] = s / (float)(cnt > 0 ? cnt : 1);
}

// ================= tiled fp32 SGEMM =================
// C[N,M] = A[N,K] @ B[K,M] (+bias) (optional relu). Requires N%BM==0, M%BN==0, K%BK==0.
template<int BM, int BN, int BK, int TM, int TN, bool RELU>
__device__ __forceinline__ void sgemm_body(const float* __restrict__ A,
                                           const float* __restrict__ B,
                                           const float* __restrict__ bias,
                                           float* __restrict__ C,
                                           int K, int M, int bm0, int bn0) {
  constexpr int THREADS = (BM / TM) * (BN / TN);
  __shared__ float As[BK][BM + 4];   // A stored transposed: As[k][row]
  __shared__ float Bs[BK][BN + 4];
  const int tid = threadIdx.x;
  const int tx = tid % (BN / TN);    // col group
  const int ty = tid / (BN / TN);    // row group
  float acc[TM][TN] = {};

  for (int k0 = 0; k0 < K; k0 += BK) {
    // load A tile (BM x BK floats) as float4, store transposed
    #pragma unroll
    for (int i = tid; i < BM * BK / 4; i += THREADS) {
      int r = i / (BK / 4);
      int c = (i % (BK / 4)) * 4;
      float4 v = *(const float4*)(A + (size_t)(bm0 + r) * K + k0 + c);
      As[c + 0][r] = v.x; As[c + 1][r] = v.y; As[c + 2][r] = v.z; As[c + 3][r] = v.w;
    }
    // load B tile (BK x BN floats)
    #pragma unroll
    for (int i = tid; i < BK * BN / 4; i += THREADS) {
      int r = i / (BN / 4);
      int c = (i % (BN / 4)) * 4;
      *(float4*)(&Bs[r][c]) = *(const float4*)(B + (size_t)(k0 + r) * M + bn0 + c);
    }
    __syncthreads();
    #pragma unroll
    for (int k = 0; k < BK; ++k) {
      float4 a0 = *(const float4*)(&As[k][ty * TM]);
      float4 a1 = *(const float4*)(&As[k][ty * TM + 4]);
      float4 b0 = *(const float4*)(&Bs[k][tx * TN]);
      float4 b1 = *(const float4*)(&Bs[k][tx * TN + 4]);
      float ar[TM] = {a0.x, a0.y, a0.z, a0.w, a1.x, a1.y, a1.z, a1.w};
      float br[TN] = {b0.x, b0.y, b0.z, b0.w, b1.x, b1.y, b1.z, b1.w};
      #pragma unroll
      for (int i = 0; i < TM; ++i)
        #pragma unroll
        for (int j = 0; j < TN; ++j)
          acc[i][j] = fmaf(ar[i], br[j], acc[i][j]);
    }
    __syncthreads();
  }
  // epilogue
  #pragma unroll
  for (int i = 0; i < TM; ++i) {
    size_t row = (size_t)(bm0 + ty * TM + i);
    float* cp = C + row * M + bn0 + tx * TN;
    float out[TN];
    #pragma unroll
    for (int j = 0; j < TN; ++j) {
      float v = acc[i][j];
      if (bias) v += bias[bn0 + tx * TN + j];
      if (RELU) v = fmaxf(v, 0.f);
      out[j] = v;
    }
    *(float4*)(cp)     = make_float4(out[0], out[1], out[2], out[3]);
    *(float4*)(cp + 4) = make_float4(out[4], out[5], out[6], out[7]);
  }
}

template<int BM, int BN, int BK, int TM, int TN, bool RELU>
__global__ void __launch_bounds__(256)
sgemm_k(const float* __restrict__ A, const float* __restrict__ B,
        const float* __restrict__ bias, float* __restrict__ C, int K, int M) {
  sgemm_body<BM, BN, BK, TM, TN, RELU>(A, B, bias, C, K, M,
                                       blockIdx.y * BM, blockIdx.x * BN);
}

struct Ptr3 { const float* B[3]; const float* bias[3]; float* C[3]; };

// fused Q,K,V projections: blockIdx.x selects which weight/output (M=BN=128)
template<int BM, int BN, int BK, int TM, int TN>
__global__ void __launch_bounds__(256)
sgemm3_k(const float* __restrict__ A, Ptr3 p, int K) {
  int m = blockIdx.x;
  sgemm_body<BM, BN, BK, TM, TN, false>(A, p.B[m], p.bias[m], p.C[m], K, BN,
                                        blockIdx.y * BM, 0);
}

// ---- transformer conv edge passes ----
__global__ void edge_score_k(const float* __restrict__ q, const float* __restrict__ kk,
                             const int* __restrict__ src, const int* __restrict__ dst,
                             float* __restrict__ score, unsigned* __restrict__ mbuf) {
  int idx = blockIdx.x * blockDim.x + threadIdx.x;
  if (idx >= EM * NH) return;
  int e = idx >> 3, h = idx & 7;
  int sn = src[e], dn = dst[e];
  const float* qp = q  + (size_t)dn * ED + h * DH;
  const float* kp = kk + (size_t)sn * ED + h * DH;
  float acc = 0.f;
  #pragma unroll
  for (int d = 0; d < DH; ++d) acc = fmaf(qp[d], kp[d], acc);
  acc *= 0.25f;  // 1/sqrt(16)
  score[idx] = acc;
  atomicMax(&mbuf[(size_t)dn * NH + h], fkey(acc));
}

__global__ void edge_exp_k(const int* __restrict__ dst, const unsigned* __restrict__ mbuf,
                           float* __restrict__ score, float* __restrict__ sbuf) {
  int idx = blockIdx.x * blockDim.x + threadIdx.x;
  if (idx >= EM * NH) return;
  int e = idx >> 3, h = idx & 7;
  int dn = dst[e];
  float m = funkey(mbuf[(size_t)dn * NH + h]);
  float ex = expf(score[idx] - m);
  score[idx] = ex;
  atomicAdd(&sbuf[(size_t)dn * NH + h], ex);
}

__global__ void edge_agg_k(const int* __restrict__ src, const int* __restrict__ dst,
                           const float* __restrict__ ebuf, const float* __restrict__ sbuf,
                           const float* __restrict__ v, float* __restrict__ hid) {
  int idx = blockIdx.x * blockDim.x + threadIdx.x;
  if (idx >= EM * ED) return;
  int e = idx >> 7, c = idx & 127, h = c >> 4;
  int sn = src[e], dn = dst[e];
  float alpha = ebuf[(size_t)e * NH + h] / (sbuf[(size_t)dn * NH + h] + 1e-16f);
  atomicAdd(&hid[(size_t)dn * ED + c], alpha * v[(size_t)sn * ED + c]);
}

// ---- gate = x @ Wg + bg : one wave per row ----
__global__ void gate_k(const float* __restrict__ x, const float* __restrict__ Wg,
                       const float* __restrict__ bg, float* __restrict__ gate) {
  int n = blockIdx.x, lane = threadIdx.x;
  float a = fmaf(x[(size_t)n * ED + lane], Wg[lane],
                 x[(size_t)n * ED + 64 + lane] * Wg[64 + lane]);
  #pragma unroll
  for (int o = 32; o > 0; o >>= 1) a += __shfl_down(a, o, 64);
  if (lane == 0) gate[n] = a + bg[0];
}

// ---- generic segment softmax over a scalar array ----
__global__ void seg_max_k(const float* __restrict__ val, const int* __restrict__ seg,
                          unsigned* __restrict__ mx, int N) {
  int i = blockIdx.x * blockDim.x + threadIdx.x;
  if (i >= N) return;
  atomicMax(&mx[seg[i]], fkey(val[i]));
}
__global__ void seg_exp_k(float* __restrict__ val, const int* __restrict__ seg,
                          const unsigned* __restrict__ mx, float* __restrict__ sum, int N) {
  int i = blockIdx.x * blockDim.x + threadIdx.x;
  if (i >= N) return;
  float e = expf(val[i] - funkey(mx[seg[i]]));
  val[i] = e;
  atomicAdd(&sum[seg[i]], e);
}
__global__ void seg_wsum_k(const float* __restrict__ x, const float* __restrict__ eg,
                           const float* __restrict__ gsum, const int* __restrict__ seg,
                           float* __restrict__ out, int N) {
  int idx = blockIdx.x * blockDim.x + threadIdx.x;
  if (idx >= N * ED) return;
  int n = idx >> 7, c = idx & 127;
  int b = seg[n];
  float a = eg[n] / (gsum[b] + 1e-16f);
  atomicAdd(&out[(size_t)b * ED + c], a * x[(size_t)n * ED + c]);
}

// ---- elementwise ----
__global__ void combine_half_k(float* __restrict__ a, const float* __restrict__ b, int N) {
  int i = blockIdx.x * blockDim.x + threadIdx.x;
  if (i < N) a[i] = (a[i] + b[i]) * 0.5f;
}

// ---- GCN ----
__global__ void deg_init_k(float* __restrict__ d, int N) {
  int i = blockIdx.x * blockDim.x + threadIdx.x;
  if (i < N) d[i] = 1.f;   // self loop
}
__global__ void deg_acc_k(const int* __restrict__ dst, float* __restrict__ d, int E) {
  int i = blockIdx.x * blockDim.x + threadIdx.x;
  if (i < E) atomicAdd(&d[dst[i]], 1.f);
}
__global__ void deg_inv_k(float* __restrict__ d, int N) {
  int i = blockIdx.x * blockDim.x + threadIdx.x;
  if (i < N) d[i] = 1.f / sqrtf(d[i]);
}
// out[n,m] = x[n,m]*dinv[n]^2 (+ bias[m]) — full overwrite, then edges scatter-add on top
__global__ void gcn_self_k(const float* __restrict__ x, const float* __restrict__ dinv,
                           const float* __restrict__ bias, float* __restrict__ out,
                           int N, int M) {
  int idx = blockIdx.x * blockDim.x + threadIdx.x;
  if (idx >= N * M) return;
  int n = idx / M, m = idx - n * M;
  float di = dinv[n];
  float v = x[idx] * di * di;
  if (bias) v += bias[m];
  out[idx] = v;
}
__global__ void gcn_edge_k(const int* __restrict__ src, const int* __restrict__ dst,
                           const float* __restrict__ x, const float* __restrict__ dinv,
                           float* __restrict__ out, int E, int M) {
  int idx = blockIdx.x * blockDim.x + threadIdx.x;
  if (idx >= E * M) return;
  int e = idx / M, m = idx - e * M;
  int s = src[e], d = dst[e];
  atomicAdd(&out[(size_t)d * M + m], dinv[s] * dinv[d] * x[(size_t)s * M + m]);
}

// ---- cosine similarity: one wave per batch row ----
__global__ void cosine_k(const float* __restrict__ a, const float* __restrict__ b,
                         float* __restrict__ out) {
  int n = blockIdx.x, lane = threadIdx.x;
  float x0 = a[(size_t)n * ED + lane], x1 = a[(size_t)n * ED + 64 + lane];
  float y0 = b[(size_t)n * ED + lane], y1 = b[(size_t)n * ED + 64 + lane];
  float dot = x0 * y0 + x1 * y1;
  float na = x0 * x0 + x1 * x1;
  float nb = y0 * y0 + y1 * y1;
  #pragma unroll
  for (int o = 32; o > 0; o >>= 1) {
    dot += __shfl_down(dot, o, 64);
    na  += __shfl_down(na,  o, 64);
    nb  += __shfl_down(nb,  o, 64);
  }
  if (lane == 0)
    out[n] = dot / (fmaxf(sqrtf(na), 1e-8f) * fmaxf(sqrtf(nb), 1e-8f));
}

// ---- workspace layout (float offsets) — unchanged peak footprint vs R1 ----
constexpr size_t OFF_HN    = 0;                                  // BB*ED
constexpr size_t OFF_STMT  = OFF_HN    + (size_t)BB * ED;        // NO*ED
constexpr size_t OFF_A     = OFF_STMT  + (size_t)NO * ED;        // NM*ED (mini_emb, recycled)
constexpr size_t OFF_QHID  = OFF_A     + (size_t)NM * ED;        // NM*ED (q, then skip/hid)
constexpr size_t OFF_K     = OFF_QHID  + (size_t)NM * ED;        // NM*ED
constexpr size_t OFF_V     = OFF_K     + (size_t)NM * ED;        // NM*ED
constexpr size_t OFF_SCORE = OFF_V     + (size_t)NM * ED;        // EM*NH
constexpr size_t OFF_M     = OFF_SCORE + (size_t)EM * NH;        // NM*NH (uint)
constexpr size_t OFF_S     = OFF_M     + (size_t)NM * NH;        // NM*NH
constexpr size_t OFF_GATE  = OFF_S     + (size_t)NM * NH;        // NM
constexpr size_t OFF_GMAX  = OFF_GATE  + (size_t)NM;             // NO (uint)
constexpr size_t OFF_GSUM  = OFF_GMAX  + (size_t)NO;             // NO
constexpr size_t OFF_GMAX2 = OFF_GSUM  + (size_t)NO;             // BB (uint)
constexpr size_t OFF_GSUM2 = OFF_GMAX2 + (size_t)BB;             // BB
constexpr size_t OFF_FNREP = OFF_GSUM2 + (size_t)BB;             // BB*ED
// region-A recycled sub-buffers (after mini_emb is dead):
constexpr size_t OFF_MFN   = OFF_A;                              // NO*ED
constexpr size_t OFF_DINV  = OFF_MFN   + (size_t)NO * ED;        // NO
constexpr size_t OFF_AGG   = OFF_DINV  + (size_t)NO;             // NO*ED  (Â·mini_fn)
constexpr size_t OFF_H     = OFF_AGG   + (size_t)NO * ED;        // NO*HIDD
constexpr size_t OFF_T     = OFF_H     + (size_t)NO * HIDD;      // NO*ED  (h@W3)
constexpr size_t OFF_FIN   = OFF_T     + (size_t)NO * ED;        // NO*ED
constexpr size_t OFF_G2    = OFF_FIN   + (size_t)NO * ED;        // NO

static inline int nblk(long long n, int b) { return (int)((n + b - 1) / b); }

extern "C" void kernel_launch(void* const* d_in, const int* in_sizes, int n_in,
                              void* d_out, int out_size, void* d_ws, size_t ws_size,
                              hipStream_t stream) {
  const int* desc_tokens = (const int*)d_in[0];
  const int* x_tokens    = (const int*)d_in[1];
  const int* mini_tokens = (const int*)d_in[2];
  const int* src         = (const int*)d_in[3];
  const int* dst         = (const int*)d_in[4];
  const int* mini_src    = (const int*)d_in[5];
  const int* mini_dst    = (const int*)d_in[6];
  const int* mini_batch  = (const int*)d_in[7];
  const int* node_batch  = (const int*)d_in[8];
  const float* desc_table  = (const float*)d_in[9];
  const float* code_table  = (const float*)d_in[10];
  const float* code_table2 = (const float*)d_in[11];
  const float* Wq = (const float*)d_in[12]; const float* bq = (const float*)d_in[13];
  const float* Wk = (const float*)d_in[14]; const float* bk = (const float*)d_in[15];
  const float* Wv = (const float*)d_in[16]; const float* bv = (const float*)d_in[17];
  const float* Wskip = (const float*)d_in[18]; const float* bskip = (const float*)d_in[19];
  const float* W2 = (const float*)d_in[20]; const float* b2 = (const float*)d_in[21];
  const float* W3 = (const float*)d_in[22]; const float* b3 = (const float*)d_in[23];
  const float* Wg = (const float*)d_in[24]; const float* bg = (const float*)d_in[25];

  float* ws = (float*)d_ws;
  float* h_n   = ws + OFF_HN;
  float* stmt  = ws + OFF_STMT;
  float* miniE = ws + OFF_A;
  float* qhid  = ws + OFF_QHID;   // q, later skip+hid accumulator
  float* kbuf  = ws + OFF_K;
  float* vbuf  = ws + OFF_V;
  float* score = ws + OFF_SCORE;
  unsigned* mbuf = (unsigned*)(ws + OFF_M);
  float* sbuf  = ws + OFF_S;
  float* gate  = ws + OFF_GATE;
  unsigned* gmax = (unsigned*)(ws + OFF_GMAX);
  float* gsum  = ws + OFF_GSUM;
  unsigned* gmax2 = (unsigned*)(ws + OFF_GMAX2);
  float* gsum2 = ws + OFF_GSUM2;
  float* fnrep = ws + OFF_FNREP;
  // recycled region A
  float* mini_fn = ws + OFF_MFN;
  float* dinv    = ws + OFF_DINV;
  float* aggb    = ws + OFF_AGG;
  float* hbuf    = ws + OFF_H;
  float* tbuf    = ws + OFF_T;
  float* finalS  = ws + OFF_FIN;
  float* gate2   = ws + OFF_G2;
  float* outp    = (float*)d_out;

  // 1) embeddings
  embed_mean_k<LDE><<<BB, ED, 0, stream>>>(desc_tokens, desc_table, h_n);
  embed_mean_k<LO> <<<NO, ED, 0, stream>>>(x_tokens, code_table2, stmt);
  embed_mean_k<LM> <<<NM, ED, 0, stream>>>(mini_tokens, code_table, miniE);

  // 2) fused Q,K,V projections: [NM,128] @ [128,128] x3 in one launch
  Ptr3 p3;
  p3.B[0] = Wq; p3.B[1] = Wk; p3.B[2] = Wv;
  p3.bias[0] = bq; p3.bias[1] = bk; p3.bias[2] = bv;
  p3.C[0] = qhid; p3.C[1] = kbuf; p3.C[2] = vbuf;
  {
    dim3 g(3, NM / 128);
    sgemm3_k<128, 128, 16, 8, 8><<<g, 256, 0, stream>>>(miniE, p3, ED);
  }

  // 3) edge scores + segment max
  hipMemsetAsync(mbuf, 0, (size_t)NM * NH * 4, stream);
  hipMemsetAsync(sbuf, 0, (size_t)NM * NH * 4, stream);
  edge_score_k<<<nblk((long long)EM * NH, 256), 256, 0, stream>>>(qhid, kbuf, mini_src, mini_dst, score, mbuf);

  // 4) skip projection overwrites q buffer (q consumed above)
  {
    dim3 g(1, NM / 128);
    sgemm_k<128, 128, 16, 8, 8, false><<<g, 256, 0, stream>>>(miniE, Wskip, bskip, qhid, ED, ED);
  }

  // 5) softmax exp+sum, then aggregate into hid (= skip buffer)
  edge_exp_k<<<nblk((long long)EM * NH, 256), 256, 0, stream>>>(mini_dst, mbuf, score, sbuf);
  edge_agg_k<<<nblk((long long)EM * ED, 256), 256, 0, stream>>>(mini_src, mini_dst, score, sbuf, vbuf, qhid);

  // 6) global attention mini -> NO  (mini_emb region now dead -> becomes mini_fn)
  gate_k<<<NM, 64, 0, stream>>>(qhid, Wg, bg, gate);
  hipMemsetAsync(gmax, 0, (size_t)NO * 4, stream);
  hipMemsetAsync(gsum, 0, (size_t)NO * 4, stream);
  seg_max_k<<<nblk(NM, 256), 256, 0, stream>>>(gate, mini_batch, gmax, NM);
  seg_exp_k<<<nblk(NM, 256), 256, 0, stream>>>(gate, mini_batch, gmax, gsum, NM);
  hipMemsetAsync(mini_fn, 0, (size_t)NO * ED * 4, stream);
  seg_wsum_k<<<nblk((long long)NM * ED, 256), 256, 0, stream>>>(qhid, gate, gsum, mini_batch, mini_fn, NM);

  // 7) mini_fn = (mini_fn + stmt)*0.5
  combine_half_k<<<nblk((long long)NO * ED, 256), 256, 0, stream>>>(mini_fn, stmt, NO * ED);

  // 8) degrees (shared by both GCN convs)
  deg_init_k<<<nblk(NO, 256), 256, 0, stream>>>(dinv, NO);
  deg_acc_k<<<nblk(EO, 256), 256, 0, stream>>>(dst, dinv, EO);
  deg_inv_k<<<nblk(NO, 256), 256, 0, stream>>>(dinv, NO);

  // 9) GCN conv 1, reassociated: agg = Â·mini_fn (128-wide scatter), then
  //    h = relu(agg @ W2 + b2)  — bias+relu fused in GEMM epilogue
  gcn_self_k<<<nblk((long long)NO * ED, 256), 256, 0, stream>>>(mini_fn, dinv, nullptr, aggb, NO, ED);
  gcn_edge_k<<<nblk((long long)EO * ED, 256), 256, 0, stream>>>(src, dst, mini_fn, dinv, aggb, EO, ED);
  {
    dim3 g(HIDD / 128, NO / 128);
    sgemm_k<128, 128, 16, 8, 8, true><<<g, 256, 0, stream>>>(aggb, W2, b2, hbuf, ED, HIDD);
  }

  // 10) GCN conv 2: t = h @ W3, then final = Â·t + b3
  {
    dim3 g(1, NO / 128);
    sgemm_k<128, 128, 16, 8, 8, false><<<g, 256, 0, stream>>>(hbuf, W3, nullptr, tbuf, HIDD, ED);
  }
  gcn_self_k<<<nblk((long long)NO * ED, 256), 256, 0, stream>>>(tbuf, dinv, b3, finalS, NO, ED);
  gcn_edge_k<<<nblk((long long)EO * ED, 256), 256, 0, stream>>>(src, dst, tbuf, dinv, finalS, EO, ED);

  // 11) global attention NO -> BB
  gate_k<<<NO, 64, 0, stream>>>(finalS, Wg, bg, gate2);
  hipMemsetAsync(gmax2, 0, (size_t)BB * 4, stream);
  hipMemsetAsync(gsum2, 0, (size_t)BB * 4, stream);
  seg_max_k<<<nblk(NO, 256), 256, 0, stream>>>(gate2, node_batch, gmax2, NO);
  seg_exp_k<<<nblk(NO, 256), 256, 0, stream>>>(gate2, node_batch, gmax2, gsum2, NO);
  hipMemsetAsync(fnrep, 0, (size_t)BB * ED * 4, stream);
  seg_wsum_k<<<nblk((long long)NO * ED, 256), 256, 0, stream>>>(finalS, gate2, gsum2, node_batch, fnrep, NO);

  // 12) cosine similarity -> d_out [BB]
  cosine_k<<<BB, 64, 0, stream>>>(fnrep, h_n, outp);
}

// Round 3
// 700.191 us; speedup vs baseline: 2.0881x; 1.3868x over previous
//
#include <hip/hip_runtime.h>
#include <hip/hip_bf16.h>
#include <math.h>

// Problem dims (fixed by reference)
#define BB   256      // batch
#define LDE  64       // desc tokens len
#define NO   10240    // outer nodes
#define LO   32       // x tokens len
#define NM   81920    // mini nodes
#define LM   16       // mini tokens len
#define EO   81920    // outer edges
#define EM   327680   // mini edges
#define ED   128      // embed dim E
#define HIDD 256      // hidden
#define NH   8        // heads
#define DH   16       // head dim

static inline int nblk(long long n, int b) { return (int)((n + b - 1) / b); }

// ---- embedding masked mean: one block (128 thr) per row ----
template<int L>
__global__ void embed_mean_k(const int* __restrict__ tokens, const float* __restrict__ table,
                             float* __restrict__ out) {
  int n = blockIdx.x;
  __shared__ int toks[L];
  if (threadIdx.x < L) toks[threadIdx.x] = tokens[(size_t)n * L + threadIdx.x];
  __syncthreads();
  int e = threadIdx.x;
  float s = 0.f; int cnt = 0;
  #pragma unroll
  for (int l = 0; l < L; ++l) {
    int t = toks[l];
    if (t != 0) { s += table[(size_t)t * ED + e]; ++cnt; }
  }
  out[(size_t)n * ED + e] = s / (float)(cnt > 0 ? cnt : 1);
}

// ================= 128x128 tiled SGEMM, split micro-tile (bank-conflict-free) =========
// NOTE: A and C deliberately NOT __restrict__: used in-place (C==A) for the skip proj.
// Safe because block (bm0) only reads A rows [bm0,bm0+128) and writes the same rows
// in the epilogue after all its A reads.
template<bool RELU>
__device__ __forceinline__ void sgemm128_body(const float* A, const float* B,
                                              const float* __restrict__ bias,
                                              float* C, int K, int M, int bm0, int bn0) {
  __shared__ float As[16][132];   // A transposed: As[k][row]
  __shared__ float Bs[16][132];
  const int tid = threadIdx.x;
  const int tx = tid & 15;
  const int ty = tid >> 4;
  float acc[2][2][4][4] = {};
  for (int k0 = 0; k0 < K; k0 += 16) {
    {
      int i = tid;
      #pragma unroll
      for (int it = 0; it < 2; ++it, i += 256) {
        int r = i >> 2;
        int c = (i & 3) * 4;
        float4 v = *(const float4*)(A + (size_t)(bm0 + r) * K + k0 + c);
        As[c+0][r] = v.x; As[c+1][r] = v.y; As[c+2][r] = v.z; As[c+3][r] = v.w;
      }
    }
    {
      int i = tid;
      #pragma unroll
      for (int it = 0; it < 2; ++it, i += 256) {
        int r = i >> 5;
        int c = (i & 31) * 4;
        *(float4*)(&Bs[r][c]) = *(const float4*)(B + (size_t)(k0 + r) * M + bn0 + c);
      }
    }
    __syncthreads();
    #pragma unroll
    for (int k = 0; k < 16; ++k) {
      float4 a[2], b[2];
      a[0] = *(const float4*)(&As[k][ty*4]);
      a[1] = *(const float4*)(&As[k][ty*4+64]);
      b[0] = *(const float4*)(&Bs[k][tx*4]);
      b[1] = *(const float4*)(&Bs[k][tx*4+64]);
      #pragma unroll
      for (int ih = 0; ih < 2; ++ih) {
        const float ar[4] = {a[ih].x, a[ih].y, a[ih].z, a[ih].w};
        #pragma unroll
        for (int jh = 0; jh < 2; ++jh) {
          const float br[4] = {b[jh].x, b[jh].y, b[jh].z, b[jh].w};
          #pragma unroll
          for (int i2 = 0; i2 < 4; ++i2)
            #pragma unroll
            for (int j2 = 0; j2 < 4; ++j2)
              acc[ih][jh][i2][j2] = fmaf(ar[i2], br[j2], acc[ih][jh][i2][j2]);
        }
      }
    }
    __syncthreads();
  }
  #pragma unroll
  for (int ih = 0; ih < 2; ++ih)
    #pragma unroll
    for (int i2 = 0; i2 < 4; ++i2) {
      int row = bm0 + ih*64 + ty*4 + i2;
      #pragma unroll
      for (int jh = 0; jh < 2; ++jh) {
        int col = bn0 + jh*64 + tx*4;
        float o[4];
        #pragma unroll
        for (int j2 = 0; j2 < 4; ++j2) {
          float v = acc[ih][jh][i2][j2];
          if (bias) v += bias[col + j2];
          if (RELU) v = fmaxf(v, 0.f);
          o[j2] = v;
        }
        *(float4*)(C + (size_t)row * M + col) = make_float4(o[0], o[1], o[2], o[3]);
      }
    }
}

template<bool RELU>
__global__ void __launch_bounds__(256)
sgemm128_k(const float* A, const float* B, const float* __restrict__ bias,
           float* C, int K, int M) {
  sgemm128_body<RELU>(A, B, bias, C, K, M, blockIdx.y * 128, blockIdx.x * 128);
}

struct Ptr3 { const float* B[3]; const float* bias[3]; float* C[3]; };

// fused Q,K,V projections (M = 128)
__global__ void __launch_bounds__(256)
sgemm3_k(const float* A, Ptr3 p, int K) {
  int m = blockIdx.x;
  sgemm128_body<false>(A, p.B[m], p.bias[m], p.C[m], K, 128, blockIdx.y * 128, 0);
}

// ================= 64x64 tiled SGEMM =================
template<bool RELU>
__global__ void __launch_bounds__(256)
sgemm64_k(const float* A, const float* __restrict__ B, const float* __restrict__ bias,
          float* C, int K, int M) {
  __shared__ float As[16][68];
  __shared__ float Bs[16][68];
  const int bm0 = blockIdx.y * 64, bn0 = blockIdx.x * 64;
  const int tid = threadIdx.x, tx = tid & 15, ty = tid >> 4;
  float acc[4][4] = {};
  for (int k0 = 0; k0 < K; k0 += 16) {
    { int r = tid >> 2, c = (tid & 3) * 4;
      float4 v = *(const float4*)(A + (size_t)(bm0 + r) * K + k0 + c);
      As[c+0][r] = v.x; As[c+1][r] = v.y; As[c+2][r] = v.z; As[c+3][r] = v.w; }
    { int r = tid >> 4, c = (tid & 15) * 4;
      *(float4*)(&Bs[r][c]) = *(const float4*)(B + (size_t)(k0 + r) * M + bn0 + c); }
    __syncthreads();
    #pragma unroll
    for (int k = 0; k < 16; ++k) {
      float4 av = *(const float4*)(&As[k][ty*4]);
      float4 bv = *(const float4*)(&Bs[k][tx*4]);
      float ar[4] = {av.x, av.y, av.z, av.w};
      float br[4] = {bv.x, bv.y, bv.z, bv.w};
      #pragma unroll
      for (int i = 0; i < 4; ++i)
        #pragma unroll
        for (int j = 0; j < 4; ++j)
          acc[i][j] = fmaf(ar[i], br[j], acc[i][j]);
    }
    __syncthreads();
  }
  #pragma unroll
  for (int i = 0; i < 4; ++i) {
    int row = bm0 + ty*4 + i, col = bn0 + tx*4;
    float o[4];
    #pragma unroll
    for (int j = 0; j < 4; ++j) {
      float v = acc[i][j];
      if (bias) v += bias[col + j];
      if (RELU) v = fmaxf(v, 0.f);
      o[j] = v;
    }
    *(float4*)(C + (size_t)row * M + col) = make_float4(o[0], o[1], o[2], o[3]);
  }
}

// ================= CSR build =================
__global__ void hist_k(const int* __restrict__ dst, int* __restrict__ hist, int E) {
  int e = blockIdx.x * 256 + threadIdx.x;
  if (e < E) atomicAdd(&hist[dst[e]], 1);
}
__global__ void chunk_sum_k(const int* __restrict__ hist, int* __restrict__ partials, int N) {
  __shared__ int sd[256];
  int i = blockIdx.x * 256 + threadIdx.x;
  sd[threadIdx.x] = (i < N) ? hist[i] : 0;
  __syncthreads();
  for (int s = 128; s > 0; s >>= 1) {
    if (threadIdx.x < s) sd[threadIdx.x] += sd[threadIdx.x + s];
    __syncthreads();
  }
  if (threadIdx.x == 0) partials[blockIdx.x] = sd[0];
}
__global__ void scan_partials_k(int* __restrict__ p, int B) {  // one block, 512 thr
  __shared__ int sd[512];
  int t = threadIdx.x;
  int v = (t < B) ? p[t] : 0;
  sd[t] = v; __syncthreads();
  for (int off = 1; off < 512; off <<= 1) {
    int a = (t >= off) ? sd[t - off] : 0;
    __syncthreads();
    sd[t] += a;
    __syncthreads();
  }
  if (t < B) p[t] = sd[t] - v;   // exclusive
}
__global__ void scan_final_k(const int* __restrict__ hist, const int* __restrict__ partials,
                             int* __restrict__ offs, int* __restrict__ cursor, int N) {
  __shared__ int sd[256];
  int i = blockIdx.x * 256 + threadIdx.x;
  int v = (i < N) ? hist[i] : 0;
  sd[threadIdx.x] = v; __syncthreads();
  for (int off = 1; off < 256; off <<= 1) {
    int a = (threadIdx.x >= off) ? sd[threadIdx.x - off] : 0;
    __syncthreads();
    sd[threadIdx.x] += a;
    __syncthreads();
  }
  if (i < N) {
    int excl = sd[threadIdx.x] - v + partials[blockIdx.x];
    offs[i] = excl;
    cursor[i] = excl;
    if (i == N - 1) offs[N] = excl + v;
  }
}
__global__ void csr_scatter_k(const int* __restrict__ src, const int* __restrict__ dst,
                              int* __restrict__ cursor, int* __restrict__ csr_src, int E) {
  int e = blockIdx.x * 256 + threadIdx.x;
  if (e >= E) return;
  int pos = atomicAdd(&cursor[dst[e]], 1);
  csr_src[pos] = src[e];
}
__global__ void dinv_k(const int* __restrict__ hist, float* __restrict__ dinv, int N) {
  int i = blockIdx.x * 256 + threadIdx.x;
  if (i < N) dinv[i] = 1.f / sqrtf(1.f + (float)hist[i]);
}

// ============ fused TransformerConv: per-dst flash attention + skip + gate ============
// 128 threads/block, one block per dst node. qh is q on entry, hid on exit (in-place).
__global__ void attn_fused_k(float* qh, const float* __restrict__ kk,
                             const float* __restrict__ vv, const float* __restrict__ skip,
                             const int* __restrict__ offs, const int* __restrict__ csr,
                             const float* __restrict__ Wg, const float* __restrict__ bg,
                             float* __restrict__ gateOut) {
  int n = blockIdx.x, t = threadIdx.x;
  float qt = qh[(size_t)n * ED + t];
  int lo = offs[n], hi = offs[n + 1];
  float O = 0.f, m = -INFINITY, l = 0.f;
  for (int e = lo; e < hi; ++e) {
    int s = csr[e];
    float kt = kk[(size_t)s * ED + t];
    float vt = vv[(size_t)s * ED + t];
    float p = qt * kt;
    #pragma unroll
    for (int o = 8; o > 0; o >>= 1) p += __shfl_xor(p, o, 16);
    float sc = p * 0.25f;               // 1/sqrt(Dh)
    float mn = fmaxf(m, sc);
    float scale = __expf(m - mn);       // exp(-inf)=0 handles first edge
    float pe = __expf(sc - mn);
    l = l * scale + pe;
    O = O * scale + pe * vt;
    m = mn;
  }
  float out = O / (l + 1e-16f) + skip[(size_t)n * ED + t];
  qh[(size_t)n * ED + t] = out;
  // fused gate = hid @ Wg + bg
  __shared__ float red[2];
  float ps = out * Wg[t];
  #pragma unroll
  for (int o = 32; o > 0; o >>= 1) ps += __shfl_down(ps, o, 64);
  if ((t & 63) == 0) red[t >> 6] = ps;
  __syncthreads();
  if (t == 0) gateOut[n] = red[0] + red[1] + bg[0];
}

// ============ GCN gather: out[d] = dinv[d]^2 x[d] + dinv[d] * sum dinv[s] x[s] (+bias)
// optional fused gate output
__global__ void gcn_gather_k(const float* __restrict__ x, const float* __restrict__ dinv,
                             const int* __restrict__ offs, const int* __restrict__ csr,
                             const float* __restrict__ bias, float* __restrict__ out,
                             const float* __restrict__ Wg, const float* __restrict__ bg,
                             float* __restrict__ gateOut) {
  int n = blockIdx.x, t = threadIdx.x;
  float di = dinv[n];
  float acc = di * di * x[(size_t)n * ED + t];
  int lo = offs[n], hi = offs[n + 1];
  for (int e = lo; e < hi; ++e) {
    int s = csr[e];
    acc = fmaf(di * dinv[s], x[(size_t)s * ED + t], acc);
  }
  float v = acc + (bias ? bias[t] : 0.f);
  out[(size_t)n * ED + t] = v;
  if (gateOut) {
    __shared__ float red[2];
    float ps = v * Wg[t];
    #pragma unroll
    for (int o = 32; o > 0; o >>= 1) ps += __shfl_down(ps, o, 64);
    if ((t & 63) == 0) red[t >> 6] = ps;
    __syncthreads();
    if (t == 0) gateOut[n] = red[0] + red[1] + bg[0];
  }
}

// ============ global attention over contiguous (sorted) segments ============
static __device__ __forceinline__ int lower_bound_d(const int* a, int n, int key) {
  int lo = 0, hi = n;
  while (lo < hi) { int mid = (lo + hi) >> 1; if (a[mid] < key) lo = mid + 1; else hi = mid; }
  return lo;
}
template<bool COMBINE>
__global__ void gattn_k(const float* __restrict__ x, const float* __restrict__ gate,
                        const int* __restrict__ seg, int Ntot,
                        const float* __restrict__ other, float* __restrict__ out) {
  int n = blockIdx.x, t = threadIdx.x;   // 128 threads
  __shared__ int sh[2];
  if (t == 0) { sh[0] = lower_bound_d(seg, Ntot, n); sh[1] = lower_bound_d(seg, Ntot, n + 1); }
  __syncthreads();
  int lo = sh[0], hi = sh[1];
  float m = -INFINITY;
  for (int j = lo; j < hi; ++j) m = fmaxf(m, gate[j]);
  float ssum = 0.f;
  for (int j = lo; j < hi; ++j) ssum += __expf(gate[j] - m);
  float inv = 1.f / (ssum + 1e-16f);
  float acc = 0.f;
  for (int j = lo; j < hi; ++j)
    acc = fmaf(__expf(gate[j] - m) * inv, x[(size_t)j * ED + t], acc);
  float r = acc;
  if (COMBINE) r = (r + other[(size_t)n * ED + t]) * 0.5f;
  out[(size_t)n * ED + t] = r;
}

// ---- cosine similarity: one wave per batch row ----
__global__ void cosine_k(const float* __restrict__ a, const float* __restrict__ b,
                         float* __restrict__ out) {
  int n = blockIdx.x, lane = threadIdx.x;
  float x0 = a[(size_t)n * ED + lane], x1 = a[(size_t)n * ED + 64 + lane];
  float y0 = b[(size_t)n * ED + lane], y1 = b[(size_t)n * ED + 64 + lane];
  float dot = x0 * y0 + x1 * y1;
  float na = x0 * x0 + x1 * x1;
  float nb = y0 * y0 + y1 * y1;
  #pragma unroll
  for (int o = 32; o > 0; o >>= 1) {
    dot += __shfl_down(dot, o, 64);
    na  += __shfl_down(na,  o, 64);
    nb  += __shfl_down(nb,  o, 64);
  }
  if (lane == 0)
    out[n] = dot / (fmaxf(sqrtf(na), 1e-8f) * fmaxf(sqrtf(nb), 1e-8f));
}

// ---- workspace layout (4-byte element offsets); peak <= R2's proven footprint ----
constexpr size_t OFF_HN    = 0;                                  // BB*ED
constexpr size_t OFF_STMT  = OFF_HN    + (size_t)BB * ED;        // NO*ED
constexpr size_t OFF_A     = OFF_STMT  + (size_t)NO * ED;        // NM*ED (miniE -> skip -> recycled)
constexpr size_t OFF_QHID  = OFF_A     + (size_t)NM * ED;        // NM*ED (q -> hid, in place)
constexpr size_t OFF_K     = OFF_QHID  + (size_t)NM * ED;        // NM*ED
constexpr size_t OFF_V     = OFF_K     + (size_t)NM * ED;        // NM*ED
// tail scratch (replaces old score/mbuf/sbuf area)
constexpr size_t T0        = OFF_V     + (size_t)NM * ED;
constexpr size_t OFF_GATE  = T0;                                 // NM
constexpr size_t OFF_GATE2 = OFF_GATE  + (size_t)NM;             // NO
constexpr size_t OFF_FNREP = OFF_GATE2 + (size_t)NO;             // BB*ED
constexpr size_t OFF_DINV  = OFF_FNREP + (size_t)BB * ED;        // NO
constexpr size_t OFF_HISTM = OFF_DINV  + (size_t)NO;             // NM (int)
constexpr size_t OFF_OFFSM = OFF_HISTM + (size_t)NM;             // NM+1
constexpr size_t OFF_CURM  = OFF_OFFSM + (size_t)NM + 1;         // NM
constexpr size_t OFF_CSRM  = OFF_CURM  + (size_t)NM;             // EM
constexpr size_t OFF_HISTO = OFF_CSRM  + (size_t)EM;             // NO
constexpr size_t OFF_OFFSO = OFF_HISTO + (size_t)NO;             // NO+1
constexpr size_t OFF_CURO  = OFF_OFFSO + (size_t)NO + 1;         // NO
constexpr size_t OFF_CSRO  = OFF_CURO  + (size_t)NO;             // EO
constexpr size_t OFF_PART  = OFF_CSRO  + (size_t)EO;             // 512 (int)
// region-A recycling after attn (skip dead):
constexpr size_t OFF_MFN   = OFF_A;                              // NO*ED
constexpr size_t OFF_AGG   = OFF_MFN   + (size_t)NO * ED;        // NO*ED
constexpr size_t OFF_H     = OFF_AGG   + (size_t)NO * ED;        // NO*HIDD
constexpr size_t OFF_T     = OFF_H     + (size_t)NO * HIDD;      // NO*ED
constexpr size_t OFF_FIN   = OFF_T     + (size_t)NO * ED;        // NO*ED

extern "C" void kernel_launch(void* const* d_in, const int* in_sizes, int n_in,
                              void* d_out, int out_size, void* d_ws, size_t ws_size,
                              hipStream_t stream) {
  const int* desc_tokens = (const int*)d_in[0];
  const int* x_tokens    = (const int*)d_in[1];
  const int* mini_tokens = (const int*)d_in[2];
  const int* src         = (const int*)d_in[3];
  const int* dst         = (const int*)d_in[4];
  const int* mini_src    = (const int*)d_in[5];
  const int* mini_dst    = (const int*)d_in[6];
  const int* mini_batch  = (const int*)d_in[7];
  const int* node_batch  = (const int*)d_in[8];
  const float* desc_table  = (const float*)d_in[9];
  const float* code_table  = (const float*)d_in[10];
  const float* code_table2 = (const float*)d_in[11];
  const float* Wq = (const float*)d_in[12]; const float* bq = (const float*)d_in[13];
  const float* Wk = (const float*)d_in[14]; const float* bk = (const float*)d_in[15];
  const float* Wv = (const float*)d_in[16]; const float* bv = (const float*)d_in[17];
  const float* Wskip = (const float*)d_in[18]; const float* bskip = (const float*)d_in[19];
  const float* W2 = (const float*)d_in[20]; const float* b2 = (const float*)d_in[21];
  const float* W3 = (const float*)d_in[22]; const float* b3 = (const float*)d_in[23];
  const float* Wg = (const float*)d_in[24]; const float* bg = (const float*)d_in[25];

  float* ws = (float*)d_ws;
  float* h_n   = ws + OFF_HN;
  float* stmt  = ws + OFF_STMT;
  float* miniE = ws + OFF_A;      // becomes skip in-place
  float* qhid  = ws + OFF_QHID;   // q -> hid in-place
  float* kbuf  = ws + OFF_K;
  float* vbuf  = ws + OFF_V;
  float* gate  = ws + OFF_GATE;
  float* gate2 = ws + OFF_GATE2;
  float* fnrep = ws + OFF_FNREP;
  float* dinv  = ws + OFF_DINV;
  int* histm = (int*)(ws + OFF_HISTM);
  int* offsm = (int*)(ws + OFF_OFFSM);
  int* curm  = (int*)(ws + OFF_CURM);
  int* csrm  = (int*)(ws + OFF_CSRM);
  int* histo = (int*)(ws + OFF_HISTO);
  int* offso = (int*)(ws + OFF_OFFSO);
  int* curo  = (int*)(ws + OFF_CURO);
  int* csro  = (int*)(ws + OFF_CSRO);
  int* part  = (int*)(ws + OFF_PART);
  float* mini_fn = ws + OFF_MFN;
  float* aggb    = ws + OFF_AGG;
  float* hbuf    = ws + OFF_H;
  float* tbuf    = ws + OFF_T;
  float* finalS  = ws + OFF_FIN;
  float* outp    = (float*)d_out;

  // ---- CSR build: mini graph (by dst) + outer graph (by dst) + degrees ----
  hipMemsetAsync(histm, 0, (size_t)NM * 4, stream);
  hipMemsetAsync(histo, 0, (size_t)NO * 4, stream);
  hist_k<<<nblk(EM, 256), 256, 0, stream>>>(mini_dst, histm, EM);
  hist_k<<<nblk(EO, 256), 256, 0, stream>>>(dst, histo, EO);
  chunk_sum_k<<<NM / 256, 256, 0, stream>>>(histm, part, NM);
  scan_partials_k<<<1, 512, 0, stream>>>(part, NM / 256);
  scan_final_k<<<NM / 256, 256, 0, stream>>>(histm, part, offsm, curm, NM);
  csr_scatter_k<<<nblk(EM, 256), 256, 0, stream>>>(mini_src, mini_dst, curm, csrm, EM);
  chunk_sum_k<<<NO / 256, 256, 0, stream>>>(histo, part, NO);
  scan_partials_k<<<1, 512, 0, stream>>>(part, NO / 256);
  scan_final_k<<<NO / 256, 256, 0, stream>>>(histo, part, offso, curo, NO);
  csr_scatter_k<<<nblk(EO, 256), 256, 0, stream>>>(src, dst, curo, csro, EO);
  dinv_k<<<nblk(NO, 256), 256, 0, stream>>>(histo, dinv, NO);

  // ---- embeddings ----
  embed_mean_k<LDE><<<BB, ED, 0, stream>>>(desc_tokens, desc_table, h_n);
  embed_mean_k<LO> <<<NO, ED, 0, stream>>>(x_tokens, code_table2, stmt);
  embed_mean_k<LM> <<<NM, ED, 0, stream>>>(mini_tokens, code_table, miniE);

  // ---- Q,K,V projections (fused) ----
  Ptr3 p3;
  p3.B[0] = Wq; p3.B[1] = Wk; p3.B[2] = Wv;
  p3.bias[0] = bq; p3.bias[1] = bk; p3.bias[2] = bv;
  p3.C[0] = qhid; p3.C[1] = kbuf; p3.C[2] = vbuf;
  { dim3 g(3, NM / 128); sgemm3_k<<<g, 256, 0, stream>>>(miniE, p3, ED); }

  // ---- skip projection IN-PLACE: miniE <- miniE @ Wskip + bskip ----
  { dim3 g(1, NM / 128); sgemm128_k<false><<<g, 256, 0, stream>>>(miniE, Wskip, bskip, miniE, ED, ED); }

  // ---- fused transformer conv (flash per dst) + gate; hid overwrites q ----
  attn_fused_k<<<NM, ED, 0, stream>>>(qhid, kbuf, vbuf, miniE, offsm, csrm, Wg, bg, gate);

  // ---- global attention mini -> NO, fused with (x + stmt)*0.5 ----
  gattn_k<true><<<NO, ED, 0, stream>>>(qhid, gate, mini_batch, NM, stmt, mini_fn);

  // ---- GCN conv 1: agg = A_hat * mini_fn ; h = relu(agg @ W2 + b2) ----
  gcn_gather_k<<<NO, ED, 0, stream>>>(mini_fn, dinv, offso, csro, nullptr, aggb,
                                      nullptr, nullptr, nullptr);
  { dim3 g(HIDD / 64, NO / 64); sgemm64_k<true><<<g, 256, 0, stream>>>(aggb, W2, b2, hbuf, ED, HIDD); }

  // ---- GCN conv 2: t = h @ W3 ; final = A_hat * t + b3 (+ fused gate2) ----
  { dim3 g(ED / 64, NO / 64); sgemm64_k<false><<<g, 256, 0, stream>>>(hbuf, W3, nullptr, tbuf, HIDD, ED); }
  gcn_gather_k<<<NO, ED, 0, stream>>>(tbuf, dinv, offso, csro, b3, finalS, Wg, bg, gate2);

  // ---- global attention NO -> BB ----
  gattn_k<false><<<BB, ED, 0, stream>>>(finalS, gate2, node_batch, NO, nullptr, fnrep);

  // ---- cosine similarity -> d_out [BB] ----
  cosine_k<<<BB, 64, 0, stream>>>(fnrep, h_n, outp);
}

// Round 4
// 558.323 us; speedup vs baseline: 2.6187x; 1.2541x over previous
//
#include <hip/hip_runtime.h>
#include <hip/hip_bf16.h>
#include <math.h>

// Problem dims (fixed by reference)
#define BB   256      // batch
#define LDE  64       // desc tokens len
#define NO   10240    // outer nodes
#define LO   32       // x tokens len
#define NM   81920    // mini nodes
#define LM   16       // mini tokens len
#define EO   81920    // outer edges
#define EM   327680   // mini edges
#define ED   128      // embed dim E
#define HIDD 256      // hidden
#define NH   8        // heads
#define DH   16       // head dim

static inline int nblk(long long n, int b) { return (int)((n + b - 1) / b); }

// ---- embedding masked mean, vectorized: 256 thr = 8 rows x 32 float4-lanes ----
template<int L>
__global__ void __launch_bounds__(256)
embed_mean_k(const int* __restrict__ tokens, const float* __restrict__ table,
             float* __restrict__ out) {
  const int r = threadIdx.x >> 5, lane = threadIdx.x & 31;
  const int n0 = blockIdx.x * 8;
  __shared__ int toks[8][L];
  for (int i = threadIdx.x; i < 8 * L; i += 256)
    toks[i / L][i % L] = tokens[(size_t)n0 * L + i];
  __syncthreads();
  float4 acc = make_float4(0.f, 0.f, 0.f, 0.f);
  int cnt = 0;
  #pragma unroll
  for (int l = 0; l < L; ++l) {
    int t = toks[r][l];
    // unconditional load (row 0 is valid memory) keeps 16 loads in flight
    float4 v = *(const float4*)(table + (size_t)t * ED + lane * 4);
    float msk = (t != 0) ? 1.f : 0.f;
    cnt += (t != 0);
    acc.x = fmaf(msk, v.x, acc.x); acc.y = fmaf(msk, v.y, acc.y);
    acc.z = fmaf(msk, v.z, acc.z); acc.w = fmaf(msk, v.w, acc.w);
  }
  float inv = 1.f / (float)(cnt > 0 ? cnt : 1);
  acc.x *= inv; acc.y *= inv; acc.z *= inv; acc.w *= inv;
  *(float4*)(out + (size_t)(n0 + r) * ED + lane * 4) = acc;
}

// ================= 128x128 tiled SGEMM, split micro-tile (bank-conflict-free) =========
// NOTE: A and C deliberately NOT __restrict__: used in-place (C==A) for the skip proj.
template<bool RELU>
__device__ __forceinline__ void sgemm128_body(const float* A, const float* B,
                                              const float* __restrict__ bias,
                                              float* C, int K, int M, int bm0, int bn0) {
  __shared__ float As[16][132];   // A transposed: As[k][row]
  __shared__ float Bs[16][132];
  const int tid = threadIdx.x;
  const int tx = tid & 15;
  const int ty = tid >> 4;
  float acc[2][2][4][4] = {};
  for (int k0 = 0; k0 < K; k0 += 16) {
    {
      int i = tid;
      #pragma unroll
      for (int it = 0; it < 2; ++it, i += 256) {
        int r = i >> 2;
        int c = (i & 3) * 4;
        float4 v = *(const float4*)(A + (size_t)(bm0 + r) * K + k0 + c);
        As[c+0][r] = v.x; As[c+1][r] = v.y; As[c+2][r] = v.z; As[c+3][r] = v.w;
      }
    }
    {
      int i = tid;
      #pragma unroll
      for (int it = 0; it < 2; ++it, i += 256) {
        int r = i >> 5;
        int c = (i & 31) * 4;
        *(float4*)(&Bs[r][c]) = *(const float4*)(B + (size_t)(k0 + r) * M + bn0 + c);
      }
    }
    __syncthreads();
    #pragma unroll
    for (int k = 0; k < 16; ++k) {
      float4 a[2], b[2];
      a[0] = *(const float4*)(&As[k][ty*4]);
      a[1] = *(const float4*)(&As[k][ty*4+64]);
      b[0] = *(const float4*)(&Bs[k][tx*4]);
      b[1] = *(const float4*)(&Bs[k][tx*4+64]);
      #pragma unroll
      for (int ih = 0; ih < 2; ++ih) {
        const float ar[4] = {a[ih].x, a[ih].y, a[ih].z, a[ih].w};
        #pragma unroll
        for (int jh = 0; jh < 2; ++jh) {
          const float br[4] = {b[jh].x, b[jh].y, b[jh].z, b[jh].w};
          #pragma unroll
          for (int i2 = 0; i2 < 4; ++i2)
            #pragma unroll
            for (int j2 = 0; j2 < 4; ++j2)
              acc[ih][jh][i2][j2] = fmaf(ar[i2], br[j2], acc[ih][jh][i2][j2]);
        }
      }
    }
    __syncthreads();
  }
  #pragma unroll
  for (int ih = 0; ih < 2; ++ih)
    #pragma unroll
    for (int i2 = 0; i2 < 4; ++i2) {
      int row = bm0 + ih*64 + ty*4 + i2;
      #pragma unroll
      for (int jh = 0; jh < 2; ++jh) {
        int col = bn0 + jh*64 + tx*4;
        float o[4];
        #pragma unroll
        for (int j2 = 0; j2 < 4; ++j2) {
          float v = acc[ih][jh][i2][j2];
          if (bias) v += bias[col + j2];
          if (RELU) v = fmaxf(v, 0.f);
          o[j2] = v;
        }
        *(float4*)(C + (size_t)row * M + col) = make_float4(o[0], o[1], o[2], o[3]);
      }
    }
}

template<bool RELU>
__global__ void __launch_bounds__(256)
sgemm128_k(const float* A, const float* B, const float* __restrict__ bias,
           float* C, int K, int M) {
  sgemm128_body<RELU>(A, B, bias, C, K, M, blockIdx.y * 128, blockIdx.x * 128);
}

struct Ptr3 { const float* B[3]; const float* bias[3]; float* C[3]; };

// fused Q,K,V projections (M = 128)
__global__ void __launch_bounds__(256)
sgemm3_k(const float* A, Ptr3 p, int K) {
  int m = blockIdx.x;
  sgemm128_body<false>(A, p.B[m], p.bias[m], p.C[m], K, 128, blockIdx.y * 128, 0);
}

// ================= 64x64 tiled SGEMM =================
template<bool RELU>
__global__ void __launch_bounds__(256)
sgemm64_k(const float* A, const float* __restrict__ B, const float* __restrict__ bias,
          float* C, int K, int M) {
  __shared__ float As[16][68];
  __shared__ float Bs[16][68];
  const int bm0 = blockIdx.y * 64, bn0 = blockIdx.x * 64;
  const int tid = threadIdx.x, tx = tid & 15, ty = tid >> 4;
  float acc[4][4] = {};
  for (int k0 = 0; k0 < K; k0 += 16) {
    { int r = tid >> 2, c = (tid & 3) * 4;
      float4 v = *(const float4*)(A + (size_t)(bm0 + r) * K + k0 + c);
      As[c+0][r] = v.x; As[c+1][r] = v.y; As[c+2][r] = v.z; As[c+3][r] = v.w; }
    { int r = tid >> 4, c = (tid & 15) * 4;
      *(float4*)(&Bs[r][c]) = *(const float4*)(B + (size_t)(k0 + r) * M + bn0 + c); }
    __syncthreads();
    #pragma unroll
    for (int k = 0; k < 16; ++k) {
      float4 av = *(const float4*)(&As[k][ty*4]);
      float4 bv = *(const float4*)(&Bs[k][tx*4]);
      float ar[4] = {av.x, av.y, av.z, av.w};
      float br[4] = {bv.x, bv.y, bv.z, bv.w};
      #pragma unroll
      for (int i = 0; i < 4; ++i)
        #pragma unroll
        for (int j = 0; j < 4; ++j)
          acc[i][j] = fmaf(ar[i], br[j], acc[i][j]);
    }
    __syncthreads();
  }
  #pragma unroll
  for (int i = 0; i < 4; ++i) {
    int row = bm0 + ty*4 + i, col = bn0 + tx*4;
    float o[4];
    #pragma unroll
    for (int j = 0; j < 4; ++j) {
      float v = acc[i][j];
      if (bias) v += bias[col + j];
      if (RELU) v = fmaxf(v, 0.f);
      o[j] = v;
    }
    *(float4*)(C + (size_t)row * M + col) = make_float4(o[0], o[1], o[2], o[3]);
  }
}

// ================= CSR build =================
__global__ void hist_k(const int* __restrict__ dst, int* __restrict__ hist, int E) {
  int e = blockIdx.x * 256 + threadIdx.x;
  if (e < E) atomicAdd(&hist[dst[e]], 1);
}
__global__ void chunk_sum_k(const int* __restrict__ hist, int* __restrict__ partials, int N) {
  __shared__ int sd[256];
  int i = blockIdx.x * 256 + threadIdx.x;
  sd[threadIdx.x] = (i < N) ? hist[i] : 0;
  __syncthreads();
  for (int s = 128; s > 0; s >>= 1) {
    if (threadIdx.x < s) sd[threadIdx.x] += sd[threadIdx.x + s];
    __syncthreads();
  }
  if (threadIdx.x == 0) partials[blockIdx.x] = sd[0];
}
__global__ void scan_partials_k(int* __restrict__ p, int B) {  // one block, 512 thr
  __shared__ int sd[512];
  int t = threadIdx.x;
  int v = (t < B) ? p[t] : 0;
  sd[t] = v; __syncthreads();
  for (int off = 1; off < 512; off <<= 1) {
    int a = (t >= off) ? sd[t - off] : 0;
    __syncthreads();
    sd[t] += a;
    __syncthreads();
  }
  if (t < B) p[t] = sd[t] - v;   // exclusive
}
__global__ void scan_final_k(const int* __restrict__ hist, const int* __restrict__ partials,
                             int* __restrict__ offs, int* __restrict__ cursor, int N) {
  __shared__ int sd[256];
  int i = blockIdx.x * 256 + threadIdx.x;
  int v = (i < N) ? hist[i] : 0;
  sd[threadIdx.x] = v; __syncthreads();
  for (int off = 1; off < 256; off <<= 1) {
    int a = (threadIdx.x >= off) ? sd[threadIdx.x - off] : 0;
    __syncthreads();
    sd[threadIdx.x] += a;
    __syncthreads();
  }
  if (i < N) {
    int excl = sd[threadIdx.x] - v + partials[blockIdx.x];
    offs[i] = excl;
    cursor[i] = excl;
    if (i == N - 1) offs[N] = excl + v;
  }
}
__global__ void csr_scatter_k(const int* __restrict__ src, const int* __restrict__ dst,
                              int* __restrict__ cursor, int* __restrict__ csr_src, int E) {
  int e = blockIdx.x * 256 + threadIdx.x;
  if (e >= E) return;
  int pos = atomicAdd(&cursor[dst[e]], 1);
  csr_src[pos] = src[e];
}
__global__ void dinv_k(const int* __restrict__ hist, float* __restrict__ dinv, int N) {
  int i = blockIdx.x * 256 + threadIdx.x;
  if (i < N) dinv[i] = 1.f / sqrtf(1.f + (float)hist[i]);
}

// ============ fused TransformerConv: per-dst flash attention + skip + gate ============
// 128 thr = 4 nodes x 32 float4-lanes. qh is q on entry, hid on exit (in-place).
// head h = lane>>2 (4 lanes per head); per-head dot reduces over 2 shfl steps.
__global__ void __launch_bounds__(128)
attn_fused_k(float* qh, const float* __restrict__ kk,
             const float* __restrict__ vv, const float* __restrict__ skip,
             const int* __restrict__ offs, const int* __restrict__ csr,
             const float* __restrict__ Wg, const float* __restrict__ bg,
             float* __restrict__ gateOut) {
  const int g = threadIdx.x >> 5, lane = threadIdx.x & 31;
  const int n = blockIdx.x * 4 + g;
  float4 q = *(const float4*)(qh + (size_t)n * ED + lane * 4);
  int lo = offs[n], hi = offs[n + 1];
  float4 O = make_float4(0.f, 0.f, 0.f, 0.f);
  float m = -INFINITY, l = 0.f;
  for (int e = lo; e < hi; ++e) {
    int s = csr[e];
    float4 kt = *(const float4*)(kk + (size_t)s * ED + lane * 4);
    float4 vt = *(const float4*)(vv + (size_t)s * ED + lane * 4);
    float p = q.x * kt.x + q.y * kt.y + q.z * kt.z + q.w * kt.w;
    p += __shfl_xor(p, 1, 64);
    p += __shfl_xor(p, 2, 64);
    float sc = p * 0.25f;               // 1/sqrt(Dh)
    float mn = fmaxf(m, sc);
    float scale = __expf(m - mn);       // exp(-inf)=0 handles first edge
    float pe = __expf(sc - mn);
    l = l * scale + pe;
    O.x = O.x * scale + pe * vt.x; O.y = O.y * scale + pe * vt.y;
    O.z = O.z * scale + pe * vt.z; O.w = O.w * scale + pe * vt.w;
    m = mn;
  }
  float inv = 1.f / (l + 1e-16f);
  float4 sk = *(const float4*)(skip + (size_t)n * ED + lane * 4);
  float4 out = make_float4(O.x * inv + sk.x, O.y * inv + sk.y,
                           O.z * inv + sk.z, O.w * inv + sk.w);
  *(float4*)(qh + (size_t)n * ED + lane * 4) = out;
  // fused gate = hid @ Wg + bg (reduce over the 32 lanes of this node)
  float4 wg = *(const float4*)(Wg + lane * 4);
  float ps = out.x * wg.x + out.y * wg.y + out.z * wg.z + out.w * wg.w;
  #pragma unroll
  for (int o = 1; o <= 16; o <<= 1) ps += __shfl_xor(ps, o, 64);
  if (lane == 0) gateOut[n] = ps + bg[0];
}

// ============ GCN gather (vectorized): 4 nodes x 32 float4-lanes ============
__global__ void __launch_bounds__(128)
gcn_gather_k(const float* __restrict__ x, const float* __restrict__ dinv,
             const int* __restrict__ offs, const int* __restrict__ csr,
             const float* __restrict__ bias, float* __restrict__ out,
             const float* __restrict__ Wg, const float* __restrict__ bg,
             float* __restrict__ gateOut) {
  const int g = threadIdx.x >> 5, lane = threadIdx.x & 31;
  const int n = blockIdx.x * 4 + g;
  float di = dinv[n];
  float4 xs = *(const float4*)(x + (size_t)n * ED + lane * 4);
  float w0 = di * di;
  float4 acc = make_float4(w0 * xs.x, w0 * xs.y, w0 * xs.z, w0 * xs.w);
  int lo = offs[n], hi = offs[n + 1];
  for (int e = lo; e < hi; ++e) {
    int s = csr[e];
    float w = di * dinv[s];
    float4 v = *(const float4*)(x + (size_t)s * ED + lane * 4);
    acc.x = fmaf(w, v.x, acc.x); acc.y = fmaf(w, v.y, acc.y);
    acc.z = fmaf(w, v.z, acc.z); acc.w = fmaf(w, v.w, acc.w);
  }
  if (bias) {
    float4 b4 = *(const float4*)(bias + lane * 4);
    acc.x += b4.x; acc.y += b4.y; acc.z += b4.z; acc.w += b4.w;
  }
  *(float4*)(out + (size_t)n * ED + lane * 4) = acc;
  if (gateOut) {
    float4 wg = *(const float4*)(Wg + lane * 4);
    float ps = acc.x * wg.x + acc.y * wg.y + acc.z * wg.z + acc.w * wg.w;
    #pragma unroll
    for (int o = 1; o <= 16; o <<= 1) ps += __shfl_xor(ps, o, 64);
    if (lane == 0) gateOut[n] = ps + bg[0];
  }
}

// ============ global attention over contiguous (sorted) segments ============
static __device__ __forceinline__ int lower_bound_d(const int* a, int n, int key) {
  int lo = 0, hi = n;
  while (lo < hi) { int mid = (lo + hi) >> 1; if (a[mid] < key) lo = mid + 1; else hi = mid; }
  return lo;
}
// 128 thr = 4 output rows x 32 float4-lanes
template<bool COMBINE>
__global__ void __launch_bounds__(128)
gattn_k(const float* __restrict__ x, const float* __restrict__ gate,
        const int* __restrict__ seg, int Ntot,
        const float* __restrict__ other, float* __restrict__ out) {
  const int g = threadIdx.x >> 5, lane = threadIdx.x & 31;
  const int n = blockIdx.x * 4 + g;
  __shared__ int sh[4][2];
  if (lane == 0) {
    sh[g][0] = lower_bound_d(seg, Ntot, n);
    sh[g][1] = lower_bound_d(seg, Ntot, n + 1);
  }
  __syncthreads();
  int lo = sh[g][0], hi = sh[g][1];
  float m = -INFINITY;
  for (int j = lo; j < hi; ++j) m = fmaxf(m, gate[j]);
  float ssum = 0.f;
  for (int j = lo; j < hi; ++j) ssum += __expf(gate[j] - m);
  float inv = 1.f / (ssum + 1e-16f);
  float4 acc = make_float4(0.f, 0.f, 0.f, 0.f);
  for (int j = lo; j < hi; ++j) {
    float a = __expf(gate[j] - m) * inv;
    float4 v = *(const float4*)(x + (size_t)j * ED + lane * 4);
    acc.x = fmaf(a, v.x, acc.x); acc.y = fmaf(a, v.y, acc.y);
    acc.z = fmaf(a, v.z, acc.z); acc.w = fmaf(a, v.w, acc.w);
  }
  if (COMBINE) {
    float4 o4 = *(const float4*)(other + (size_t)n * ED + lane * 4);
    acc.x = (acc.x + o4.x) * 0.5f; acc.y = (acc.y + o4.y) * 0.5f;
    acc.z = (acc.z + o4.z) * 0.5f; acc.w = (acc.w + o4.w) * 0.5f;
  }
  *(float4*)(out + (size_t)n * ED + lane * 4) = acc;
}

// ---- cosine similarity: one wave per batch row ----
__global__ void cosine_k(const float* __restrict__ a, const float* __restrict__ b,
                         float* __restrict__ out) {
  int n = blockIdx.x, lane = threadIdx.x;
  float x0 = a[(size_t)n * ED + lane], x1 = a[(size_t)n * ED + 64 + lane];
  float y0 = b[(size_t)n * ED + lane], y1 = b[(size_t)n * ED + 64 + lane];
  float dot = x0 * y0 + x1 * y1;
  float na = x0 * x0 + x1 * x1;
  float nb = y0 * y0 + y1 * y1;
  #pragma unroll
  for (int o = 32; o > 0; o >>= 1) {
    dot += __shfl_down(dot, o, 64);
    na  += __shfl_down(na,  o, 64);
    nb  += __shfl_down(nb,  o, 64);
  }
  if (lane == 0)
    out[n] = dot / (fmaxf(sqrtf(na), 1e-8f) * fmaxf(sqrtf(nb), 1e-8f));
}

// ---- workspace layout (4-byte element offsets) ----
constexpr size_t OFF_HN    = 0;                                  // BB*ED
constexpr size_t OFF_STMT  = OFF_HN    + (size_t)BB * ED;        // NO*ED
constexpr size_t OFF_A     = OFF_STMT  + (size_t)NO * ED;        // NM*ED (miniE -> skip -> recycled)
constexpr size_t OFF_QHID  = OFF_A     + (size_t)NM * ED;        // NM*ED (q -> hid, in place)
constexpr size_t OFF_K     = OFF_QHID  + (size_t)NM * ED;        // NM*ED
constexpr size_t OFF_V     = OFF_K     + (size_t)NM * ED;        // NM*ED
constexpr size_t T0        = OFF_V     + (size_t)NM * ED;
constexpr size_t OFF_GATE  = T0;                                 // NM
constexpr size_t OFF_GATE2 = OFF_GATE  + (size_t)NM;             // NO
constexpr size_t OFF_FNREP = OFF_GATE2 + (size_t)NO;             // BB*ED
constexpr size_t OFF_DINV  = OFF_FNREP + (size_t)BB * ED;        // NO
constexpr size_t OFF_HISTM = OFF_DINV  + (size_t)NO;             // NM (int)
constexpr size_t OFF_OFFSM = OFF_HISTM + (size_t)NM;             // NM+1
constexpr size_t OFF_CURM  = OFF_OFFSM + (size_t)NM + 1;         // NM
constexpr size_t OFF_CSRM  = OFF_CURM  + (size_t)NM;             // EM
constexpr size_t OFF_HISTO = OFF_CSRM  + (size_t)EM;             // NO
constexpr size_t OFF_OFFSO = OFF_HISTO + (size_t)NO;             // NO+1
constexpr size_t OFF_CURO  = OFF_OFFSO + (size_t)NO + 1;         // NO
constexpr size_t OFF_CSRO  = OFF_CURO  + (size_t)NO;             // EO
constexpr size_t OFF_PART  = OFF_CSRO  + (size_t)EO;             // 512 (int)
// region-A recycling after attn (skip dead):
constexpr size_t OFF_MFN   = OFF_A;                              // NO*ED
constexpr size_t OFF_AGG   = OFF_MFN   + (size_t)NO * ED;        // NO*ED
constexpr size_t OFF_H     = OFF_AGG   + (size_t)NO * ED;        // NO*HIDD
constexpr size_t OFF_T     = OFF_H     + (size_t)NO * HIDD;      // NO*ED
constexpr size_t OFF_FIN   = OFF_T     + (size_t)NO * ED;        // NO*ED

extern "C" void kernel_launch(void* const* d_in, const int* in_sizes, int n_in,
                              void* d_out, int out_size, void* d_ws, size_t ws_size,
                              hipStream_t stream) {
  const int* desc_tokens = (const int*)d_in[0];
  const int* x_tokens    = (const int*)d_in[1];
  const int* mini_tokens = (const int*)d_in[2];
  const int* src         = (const int*)d_in[3];
  const int* dst         = (const int*)d_in[4];
  const int* mini_src    = (const int*)d_in[5];
  const int* mini_dst    = (const int*)d_in[6];
  const int* mini_batch  = (const int*)d_in[7];
  const int* node_batch  = (const int*)d_in[8];
  const float* desc_table  = (const float*)d_in[9];
  const float* code_table  = (const float*)d_in[10];
  const float* code_table2 = (const float*)d_in[11];
  const float* Wq = (const float*)d_in[12]; const float* bq = (const float*)d_in[13];
  const float* Wk = (const float*)d_in[14]; const float* bk = (const float*)d_in[15];
  const float* Wv = (const float*)d_in[16]; const float* bv = (const float*)d_in[17];
  const float* Wskip = (const float*)d_in[18]; const float* bskip = (const float*)d_in[19];
  const float* W2 = (const float*)d_in[20]; const float* b2 = (const float*)d_in[21];
  const float* W3 = (const float*)d_in[22]; const float* b3 = (const float*)d_in[23];
  const float* Wg = (const float*)d_in[24]; const float* bg = (const float*)d_in[25];

  float* ws = (float*)d_ws;
  float* h_n   = ws + OFF_HN;
  float* stmt  = ws + OFF_STMT;
  float* miniE = ws + OFF_A;      // becomes skip in-place
  float* qhid  = ws + OFF_QHID;   // q -> hid in-place
  float* kbuf  = ws + OFF_K;
  float* vbuf  = ws + OFF_V;
  float* gate  = ws + OFF_GATE;
  float* gate2 = ws + OFF_GATE2;
  float* fnrep = ws + OFF_FNREP;
  float* dinv  = ws + OFF_DINV;
  int* histm = (int*)(ws + OFF_HISTM);
  int* offsm = (int*)(ws + OFF_OFFSM);
  int* curm  = (int*)(ws + OFF_CURM);
  int* csrm  = (int*)(ws + OFF_CSRM);
  int* histo = (int*)(ws + OFF_HISTO);
  int* offso = (int*)(ws + OFF_OFFSO);
  int* curo  = (int*)(ws + OFF_CURO);
  int* csro  = (int*)(ws + OFF_CSRO);
  int* part  = (int*)(ws + OFF_PART);
  float* mini_fn = ws + OFF_MFN;
  float* aggb    = ws + OFF_AGG;
  float* hbuf    = ws + OFF_H;
  float* tbuf    = ws + OFF_T;
  float* finalS  = ws + OFF_FIN;
  float* outp    = (float*)d_out;

  // ---- CSR build: mini graph (by dst) + outer graph (by dst) + degrees ----
  hipMemsetAsync(histm, 0, (size_t)NM * 4, stream);
  hipMemsetAsync(histo, 0, (size_t)NO * 4, stream);
  hist_k<<<nblk(EM, 256), 256, 0, stream>>>(mini_dst, histm, EM);
  hist_k<<<nblk(EO, 256), 256, 0, stream>>>(dst, histo, EO);
  chunk_sum_k<<<NM / 256, 256, 0, stream>>>(histm, part, NM);
  scan_partials_k<<<1, 512, 0, stream>>>(part, NM / 256);
  scan_final_k<<<NM / 256, 256, 0, stream>>>(histm, part, offsm, curm, NM);
  csr_scatter_k<<<nblk(EM, 256), 256, 0, stream>>>(mini_src, mini_dst, curm, csrm, EM);
  chunk_sum_k<<<NO / 256, 256, 0, stream>>>(histo, part, NO);
  scan_partials_k<<<1, 512, 0, stream>>>(part, NO / 256);
  scan_final_k<<<NO / 256, 256, 0, stream>>>(histo, part, offso, curo, NO);
  csr_scatter_k<<<nblk(EO, 256), 256, 0, stream>>>(src, dst, curo, csro, EO);
  dinv_k<<<nblk(NO, 256), 256, 0, stream>>>(histo, dinv, NO);

  // ---- embeddings (vectorized, 8 rows/block) ----
  embed_mean_k<LDE><<<BB / 8, 256, 0, stream>>>(desc_tokens, desc_table, h_n);
  embed_mean_k<LO> <<<NO / 8, 256, 0, stream>>>(x_tokens, code_table2, stmt);
  embed_mean_k<LM> <<<NM / 8, 256, 0, stream>>>(mini_tokens, code_table, miniE);

  // ---- Q,K,V projections (fused) ----
  Ptr3 p3;
  p3.B[0] = Wq; p3.B[1] = Wk; p3.B[2] = Wv;
  p3.bias[0] = bq; p3.bias[1] = bk; p3.bias[2] = bv;
  p3.C[0] = qhid; p3.C[1] = kbuf; p3.C[2] = vbuf;
  { dim3 g(3, NM / 128); sgemm3_k<<<g, 256, 0, stream>>>(miniE, p3, ED); }

  // ---- skip projection IN-PLACE: miniE <- miniE @ Wskip + bskip ----
  { dim3 g(1, NM / 128); sgemm128_k<false><<<g, 256, 0, stream>>>(miniE, Wskip, bskip, miniE, ED, ED); }

  // ---- fused transformer conv (flash per dst) + gate; hid overwrites q ----
  attn_fused_k<<<NM / 4, 128, 0, stream>>>(qhid, kbuf, vbuf, miniE, offsm, csrm, Wg, bg, gate);

  // ---- global attention mini -> NO, fused with (x + stmt)*0.5 ----
  gattn_k<true><<<NO / 4, 128, 0, stream>>>(qhid, gate, mini_batch, NM, stmt, mini_fn);

  // ---- GCN conv 1: agg = A_hat * mini_fn ; h = relu(agg @ W2 + b2) ----
  gcn_gather_k<<<NO / 4, 128, 0, stream>>>(mini_fn, dinv, offso, csro, nullptr, aggb,
                                           nullptr, nullptr, nullptr);
  { dim3 g(HIDD / 64, NO / 64); sgemm64_k<true><<<g, 256, 0, stream>>>(aggb, W2, b2, hbuf, ED, HIDD); }

  // ---- GCN conv 2: t = h @ W3 ; final = A_hat * t + b3 (+ fused gate2) ----
  { dim3 g(ED / 64, NO / 64); sgemm64_k<false><<<g, 256, 0, stream>>>(hbuf, W3, nullptr, tbuf, HIDD, ED); }
  gcn_gather_k<<<NO / 4, 128, 0, stream>>>(tbuf, dinv, offso, csro, b3, finalS, Wg, bg, gate2);

  // ---- global attention NO -> BB ----
  gattn_k<false><<<BB / 4, 128, 0, stream>>>(finalS, gate2, node_batch, NO, nullptr, fnrep);

  // ---- cosine similarity -> d_out [BB] ----
  cosine_k<<<BB, 64, 0, stream>>>(fnrep, h_n, outp);
}

// Round 5
// 495.761 us; speedup vs baseline: 2.9492x; 1.1262x over previous
//
#include <hip/hip_runtime.h>
#include <hip/hip_bf16.h>
#include <math.h>

// Problem dims (fixed by reference)
#define BB   256      // batch
#define LDE  64       // desc tokens len
#define NO   10240    // outer nodes
#define LO   32       // x tokens len
#define NM   81920    // mini nodes
#define LM   16       // mini tokens len
#define EO   81920    // outer edges
#define EM   327680   // mini edges
#define ED   128      // embed dim E
#define HIDD 256      // hidden
#define NH   8        // heads
#define DH   16       // head dim

static inline int nblk(long long n, int b) { return (int)((n + b - 1) / b); }

typedef __attribute__((ext_vector_type(8))) short short8;
typedef __attribute__((ext_vector_type(4))) float f32x4;

// ---- fp32 -> bf16 (RNE) helpers ----
static __device__ __forceinline__ unsigned short bf16_rne(float f) {
  unsigned u = __float_as_uint(f);
  return (unsigned short)((u + 0x7fffu + ((u >> 16) & 1u)) >> 16);
}
static __device__ __forceinline__ float bf16_to_f(unsigned short h) {
  return __uint_as_float(((unsigned)h) << 16);
}

// ---- embedding masked mean, vectorized: 256 thr = 8 rows x 32 float4-lanes ----
template<int L>
__global__ void __launch_bounds__(256)
embed_mean_k(const int* __restrict__ tokens, const float* __restrict__ table,
             float* __restrict__ out) {
  const int r = threadIdx.x >> 5, lane = threadIdx.x & 31;
  const int n0 = blockIdx.x * 8;
  __shared__ int toks[8][L];
  for (int i = threadIdx.x; i < 8 * L; i += 256)
    toks[i / L][i % L] = tokens[(size_t)n0 * L + i];
  __syncthreads();
  float4 acc = make_float4(0.f, 0.f, 0.f, 0.f);
  int cnt = 0;
  #pragma unroll
  for (int l = 0; l < L; ++l) {
    int t = toks[r][l];
    float4 v = *(const float4*)(table + (size_t)t * ED + lane * 4);
    float msk = (t != 0) ? 1.f : 0.f;
    cnt += (t != 0);
    acc.x = fmaf(msk, v.x, acc.x); acc.y = fmaf(msk, v.y, acc.y);
    acc.z = fmaf(msk, v.z, acc.z); acc.w = fmaf(msk, v.w, acc.w);
  }
  float inv = 1.f / (float)(cnt > 0 ? cnt : 1);
  acc.x *= inv; acc.y *= inv; acc.z *= inv; acc.w *= inv;
  *(float4*)(out + (size_t)(n0 + r) * ED + lane * 4) = acc;
}

// ================= weight -> MFMA-fragment-layout conversion (split bf16) ============
// Frag layout: octet index = (kb * (M/16) + nt) * 64 + lane ; element j of octet =
// B[kb*32 + (lane>>4)*8 + j][nt*16 + (lane&15)].
__global__ void wconv_k(const float* __restrict__ W, int K, int M,
                        short8* __restrict__ hi, short8* __restrict__ lo) {
  int idx = blockIdx.x * 256 + threadIdx.x;
  int total = (K / 32) * (M / 16) * 64;
  if (idx >= total) return;
  int lane = idx & 63;
  int nt = (idx >> 6) % (M / 16);
  int kb = (idx >> 6) / (M / 16);
  int n = nt * 16 + (lane & 15);
  int k0 = kb * 32 + ((lane >> 4) << 3);
  short8 h, l;
  #pragma unroll
  for (int j = 0; j < 8; ++j) {
    float v = W[(size_t)(k0 + j) * M + n];
    unsigned short hb = bf16_rne(v);
    h[j] = (short)hb;
    l[j] = (short)bf16_rne(v - bf16_to_f(hb));
  }
  hi[idx] = h; lo[idx] = l;
}

// ================= MFMA GEMM: C[N,M] = A[N,K] @ B[K,M] (+bias)(relu) ================
// Split-bf16: D += Ah*Bh + Ah*Bl + Al*Bh (Al*Bl ~2^-16 rel, dropped).
// 256 thr = 4 waves (2x2 over 128x128 tile). BK=32. A NOT __restrict__ (in-place skip).
template<bool RELU>
__device__ __forceinline__ void mgemm_body(const float* A,
                                           const short8* __restrict__ Bh,
                                           const short8* __restrict__ Bl,
                                           const float* __restrict__ bias,
                                           float* C, int K, int M, int bm0, int bn0) {
  __shared__ short8 Ah[8][64];   // [m-tile][lane] : frag-ready, lane-linear
  __shared__ short8 Al[8][64];
  const int tid = threadIdx.x;
  const int w = tid >> 6, lane = tid & 63;
  const int wm = (w & 1) * 4;    // local m-tile base
  const int wn = (w >> 1) * 4;   // local n-tile base
  const int NTm = M / 16;
  f32x4 acc[4][4];
  #pragma unroll
  for (int i = 0; i < 4; ++i)
    #pragma unroll
    for (int j = 0; j < 4; ++j) acc[i][j] = (f32x4){0.f, 0.f, 0.f, 0.f};

  const int kbn = K / 32;
  for (int kb = 0; kb < kbn; ++kb) {
    __syncthreads();   // previous iter's LDS reads done before overwrite
    #pragma unroll
    for (int it = 0; it < 2; ++it) {
      int u = tid + it * 256;            // 512 octets: [mt][lane]
      int mt = u >> 6, l = u & 63;
      int m = bm0 + mt * 16 + (l & 15);
      int k = kb * 32 + ((l >> 4) << 3);
      const float* ap = A + (size_t)m * K + k;
      float4 v0 = *(const float4*)ap;
      float4 v1 = *(const float4*)(ap + 4);
      float f[8] = {v0.x, v0.y, v0.z, v0.w, v1.x, v1.y, v1.z, v1.w};
      short8 hh, ll;
      #pragma unroll
      for (int j = 0; j < 8; ++j) {
        unsigned short hb = bf16_rne(f[j]);
        hh[j] = (short)hb;
        ll[j] = (short)bf16_rne(f[j] - bf16_to_f(hb));
      }
      Ah[mt][l] = hh; Al[mt][l] = ll;
    }
    __syncthreads();
    short8 bh[4], bl[4];
    #pragma unroll
    for (int j = 0; j < 4; ++j) {
      size_t bi = ((size_t)kb * NTm + (bn0 >> 4) + wn + j) * 64 + lane;
      bh[j] = Bh[bi]; bl[j] = Bl[bi];
    }
    #pragma unroll
    for (int i = 0; i < 4; ++i) {
      short8 ah = Ah[wm + i][lane];
      short8 al = Al[wm + i][lane];
      #pragma unroll
      for (int j = 0; j < 4; ++j) {
        acc[i][j] = __builtin_amdgcn_mfma_f32_16x16x32_bf16(ah, bh[j], acc[i][j], 0, 0, 0);
        acc[i][j] = __builtin_amdgcn_mfma_f32_16x16x32_bf16(ah, bl[j], acc[i][j], 0, 0, 0);
        acc[i][j] = __builtin_amdgcn_mfma_f32_16x16x32_bf16(al, bh[j], acc[i][j], 0, 0, 0);
      }
    }
  }
  // epilogue: D row = quad*4+r, col = lane&15
  const int q = lane >> 4, c = lane & 15;
  #pragma unroll
  for (int i = 0; i < 4; ++i) {
    #pragma unroll
    for (int j = 0; j < 4; ++j) {
      int col = bn0 + (wn + j) * 16 + c;
      float bv = bias ? bias[col] : 0.f;
      #pragma unroll
      for (int r = 0; r < 4; ++r) {
        int row = bm0 + (wm + i) * 16 + q * 4 + r;
        float v = acc[i][j][r] + bv;
        if (RELU) v = fmaxf(v, 0.f);
        C[(size_t)row * M + col] = v;
      }
    }
  }
}

struct GDesc { const short8* bh; const short8* bl; const float* bias; float* C; };
struct GDesc3 { GDesc d[3]; };

__global__ void __launch_bounds__(256)
mgemm_qkv_k(const float* A, GDesc3 g3, int K) {
  const GDesc d = g3.d[blockIdx.x];
  mgemm_body<false>(A, d.bh, d.bl, d.bias, d.C, K, 128, blockIdx.y * 128, 0);
}
template<bool RELU>
__global__ void __launch_bounds__(256)
mgemm_k(const float* A, const short8* __restrict__ bh, const short8* __restrict__ bl,
        const float* __restrict__ bias, float* C, int K, int M) {
  mgemm_body<RELU>(A, bh, bl, bias, C, K, M, blockIdx.y * 128, blockIdx.x * 128);
}

// ================= CSR build =================
__global__ void hist_k(const int* __restrict__ dst, int* __restrict__ hist, int E) {
  int e = blockIdx.x * 256 + threadIdx.x;
  if (e < E) atomicAdd(&hist[dst[e]], 1);
}
__global__ void chunk_sum_k(const int* __restrict__ hist, int* __restrict__ partials, int N) {
  __shared__ int sd[256];
  int i = blockIdx.x * 256 + threadIdx.x;
  sd[threadIdx.x] = (i < N) ? hist[i] : 0;
  __syncthreads();
  for (int s = 128; s > 0; s >>= 1) {
    if (threadIdx.x < s) sd[threadIdx.x] += sd[threadIdx.x + s];
    __syncthreads();
  }
  if (threadIdx.x == 0) partials[blockIdx.x] = sd[0];
}
__global__ void scan_partials_k(int* __restrict__ p, int B) {  // one block, 512 thr
  __shared__ int sd[512];
  int t = threadIdx.x;
  int v = (t < B) ? p[t] : 0;
  sd[t] = v; __syncthreads();
  for (int off = 1; off < 512; off <<= 1) {
    int a = (t >= off) ? sd[t - off] : 0;
    __syncthreads();
    sd[t] += a;
    __syncthreads();
  }
  if (t < B) p[t] = sd[t] - v;   // exclusive
}
__global__ void scan_final_k(const int* __restrict__ hist, const int* __restrict__ partials,
                             int* __restrict__ offs, int* __restrict__ cursor, int N) {
  __shared__ int sd[256];
  int i = blockIdx.x * 256 + threadIdx.x;
  int v = (i < N) ? hist[i] : 0;
  sd[threadIdx.x] = v; __syncthreads();
  for (int off = 1; off < 256; off <<= 1) {
    int a = (threadIdx.x >= off) ? sd[threadIdx.x - off] : 0;
    __syncthreads();
    sd[threadIdx.x] += a;
    __syncthreads();
  }
  if (i < N) {
    int excl = sd[threadIdx.x] - v + partials[blockIdx.x];
    offs[i] = excl;
    cursor[i] = excl;
    if (i == N - 1) offs[N] = excl + v;
  }
}
__global__ void csr_scatter_k(const int* __restrict__ src, const int* __restrict__ dst,
                              int* __restrict__ cursor, int* __restrict__ csr_src, int E) {
  int e = blockIdx.x * 256 + threadIdx.x;
  if (e >= E) return;
  int pos = atomicAdd(&cursor[dst[e]], 1);
  csr_src[pos] = src[e];
}
__global__ void dinv_k(const int* __restrict__ hist, float* __restrict__ dinv, int N) {
  int i = blockIdx.x * 256 + threadIdx.x;
  if (i < N) dinv[i] = 1.f / sqrtf(1.f + (float)hist[i]);
}

// ============ fused TransformerConv: per-dst flash attention + skip + gate ============
__global__ void __launch_bounds__(128)
attn_fused_k(float* qh, const float* __restrict__ kk,
             const float* __restrict__ vv, const float* __restrict__ skip,
             const int* __restrict__ offs, const int* __restrict__ csr,
             const float* __restrict__ Wg, const float* __restrict__ bg,
             float* __restrict__ gateOut) {
  const int g = threadIdx.x >> 5, lane = threadIdx.x & 31;
  const int n = blockIdx.x * 4 + g;
  float4 q = *(const float4*)(qh + (size_t)n * ED + lane * 4);
  int lo = offs[n], hi = offs[n + 1];
  float4 O = make_float4(0.f, 0.f, 0.f, 0.f);
  float m = -INFINITY, l = 0.f;
  for (int e = lo; e < hi; ++e) {
    int s = csr[e];
    float4 kt = *(const float4*)(kk + (size_t)s * ED + lane * 4);
    float4 vt = *(const float4*)(vv + (size_t)s * ED + lane * 4);
    float p = q.x * kt.x + q.y * kt.y + q.z * kt.z + q.w * kt.w;
    p += __shfl_xor(p, 1, 64);
    p += __shfl_xor(p, 2, 64);
    float sc = p * 0.25f;               // 1/sqrt(Dh)
    float mn = fmaxf(m, sc);
    float scale = __expf(m - mn);
    float pe = __expf(sc - mn);
    l = l * scale + pe;
    O.x = O.x * scale + pe * vt.x; O.y = O.y * scale + pe * vt.y;
    O.z = O.z * scale + pe * vt.z; O.w = O.w * scale + pe * vt.w;
    m = mn;
  }
  float inv = 1.f / (l + 1e-16f);
  float4 sk = *(const float4*)(skip + (size_t)n * ED + lane * 4);
  float4 out = make_float4(O.x * inv + sk.x, O.y * inv + sk.y,
                           O.z * inv + sk.z, O.w * inv + sk.w);
  *(float4*)(qh + (size_t)n * ED + lane * 4) = out;
  float4 wg = *(const float4*)(Wg + lane * 4);
  float ps = out.x * wg.x + out.y * wg.y + out.z * wg.z + out.w * wg.w;
  #pragma unroll
  for (int o = 1; o <= 16; o <<= 1) ps += __shfl_xor(ps, o, 64);
  if (lane == 0) gateOut[n] = ps + bg[0];
}

// ============ GCN gather (vectorized): 4 nodes x 32 float4-lanes ============
__global__ void __launch_bounds__(128)
gcn_gather_k(const float* __restrict__ x, const float* __restrict__ dinv,
             const int* __restrict__ offs, const int* __restrict__ csr,
             const float* __restrict__ bias, float* __restrict__ out,
             const float* __restrict__ Wg, const float* __restrict__ bg,
             float* __restrict__ gateOut) {
  const int g = threadIdx.x >> 5, lane = threadIdx.x & 31;
  const int n = blockIdx.x * 4 + g;
  float di = dinv[n];
  float4 xs = *(const float4*)(x + (size_t)n * ED + lane * 4);
  float w0 = di * di;
  float4 acc = make_float4(w0 * xs.x, w0 * xs.y, w0 * xs.z, w0 * xs.w);
  int lo = offs[n], hi = offs[n + 1];
  for (int e = lo; e < hi; ++e) {
    int s = csr[e];
    float w = di * dinv[s];
    float4 v = *(const float4*)(x + (size_t)s * ED + lane * 4);
    acc.x = fmaf(w, v.x, acc.x); acc.y = fmaf(w, v.y, acc.y);
    acc.z = fmaf(w, v.z, acc.z); acc.w = fmaf(w, v.w, acc.w);
  }
  if (bias) {
    float4 b4 = *(const float4*)(bias + lane * 4);
    acc.x += b4.x; acc.y += b4.y; acc.z += b4.z; acc.w += b4.w;
  }
  *(float4*)(out + (size_t)n * ED + lane * 4) = acc;
  if (gateOut) {
    float4 wg = *(const float4*)(Wg + lane * 4);
    float ps = acc.x * wg.x + acc.y * wg.y + acc.z * wg.z + acc.w * wg.w;
    #pragma unroll
    for (int o = 1; o <= 16; o <<= 1) ps += __shfl_xor(ps, o, 64);
    if (lane == 0) gateOut[n] = ps + bg[0];
  }
}

// ============ global attention over contiguous (sorted) segments ============
static __device__ __forceinline__ int lower_bound_d(const int* a, int n, int key) {
  int lo = 0, hi = n;
  while (lo < hi) { int mid = (lo + hi) >> 1; if (a[mid] < key) lo = mid + 1; else hi = mid; }
  return lo;
}
template<bool COMBINE>
__global__ void __launch_bounds__(128)
gattn_k(const float* __restrict__ x, const float* __restrict__ gate,
        const int* __restrict__ seg, int Ntot,
        const float* __restrict__ other, float* __restrict__ out) {
  const int g = threadIdx.x >> 5, lane = threadIdx.x & 31;
  const int n = blockIdx.x * 4 + g;
  __shared__ int sh[4][2];
  if (lane == 0) {
    sh[g][0] = lower_bound_d(seg, Ntot, n);
    sh[g][1] = lower_bound_d(seg, Ntot, n + 1);
  }
  __syncthreads();
  int lo = sh[g][0], hi = sh[g][1];
  float m = -INFINITY;
  for (int j = lo; j < hi; ++j) m = fmaxf(m, gate[j]);
  float ssum = 0.f;
  for (int j = lo; j < hi; ++j) ssum += __expf(gate[j] - m);
  float inv = 1.f / (ssum + 1e-16f);
  float4 acc = make_float4(0.f, 0.f, 0.f, 0.f);
  for (int j = lo; j < hi; ++j) {
    float a = __expf(gate[j] - m) * inv;
    float4 v = *(const float4*)(x + (size_t)j * ED + lane * 4);
    acc.x = fmaf(a, v.x, acc.x); acc.y = fmaf(a, v.y, acc.y);
    acc.z = fmaf(a, v.z, acc.z); acc.w = fmaf(a, v.w, acc.w);
  }
  if (COMBINE) {
    float4 o4 = *(const float4*)(other + (size_t)n * ED + lane * 4);
    acc.x = (acc.x + o4.x) * 0.5f; acc.y = (acc.y + o4.y) * 0.5f;
    acc.z = (acc.z + o4.z) * 0.5f; acc.w = (acc.w + o4.w) * 0.5f;
  }
  *(float4*)(out + (size_t)n * ED + lane * 4) = acc;
}

// ---- cosine similarity: one wave per batch row ----
__global__ void cosine_k(const float* __restrict__ a, const float* __restrict__ b,
                         float* __restrict__ out) {
  int n = blockIdx.x, lane = threadIdx.x;
  float x0 = a[(size_t)n * ED + lane], x1 = a[(size_t)n * ED + 64 + lane];
  float y0 = b[(size_t)n * ED + lane], y1 = b[(size_t)n * ED + 64 + lane];
  float dot = x0 * y0 + x1 * y1;
  float na = x0 * x0 + x1 * x1;
  float nb = y0 * y0 + y1 * y1;
  #pragma unroll
  for (int o = 32; o > 0; o >>= 1) {
    dot += __shfl_down(dot, o, 64);
    na  += __shfl_down(na,  o, 64);
    nb  += __shfl_down(nb,  o, 64);
  }
  if (lane == 0)
    out[n] = dot / (fmaxf(sqrtf(na), 1e-8f) * fmaxf(sqrtf(nb), 1e-8f));
}

// ---- workspace layout (4-byte element offsets) ----
constexpr size_t OFF_HN    = 0;                                  // BB*ED
constexpr size_t OFF_STMT  = OFF_HN    + (size_t)BB * ED;        // NO*ED
constexpr size_t OFF_A     = OFF_STMT  + (size_t)NO * ED;        // NM*ED (miniE -> skip -> recycled)
constexpr size_t OFF_QHID  = OFF_A     + (size_t)NM * ED;        // NM*ED (q -> hid, in place)
constexpr size_t OFF_K     = OFF_QHID  + (size_t)NM * ED;        // NM*ED
constexpr size_t OFF_V     = OFF_K     + (size_t)NM * ED;        // NM*ED
constexpr size_t T0        = OFF_V     + (size_t)NM * ED;
constexpr size_t OFF_GATE  = T0;                                 // NM
constexpr size_t OFF_GATE2 = OFF_GATE  + (size_t)NM;             // NO
constexpr size_t OFF_FNREP = OFF_GATE2 + (size_t)NO;             // BB*ED
constexpr size_t OFF_DINV  = OFF_FNREP + (size_t)BB * ED;        // NO
constexpr size_t OFF_HISTM = OFF_DINV  + (size_t)NO;             // NM (int)
constexpr size_t OFF_OFFSM = OFF_HISTM + (size_t)NM;             // NM+1
constexpr size_t OFF_CURM  = OFF_OFFSM + (size_t)NM + 1;         // NM
constexpr size_t OFF_CSRM  = OFF_CURM  + (size_t)NM;             // EM
constexpr size_t OFF_HISTO = OFF_CSRM  + (size_t)EM;             // NO
constexpr size_t OFF_OFFSO = OFF_HISTO + (size_t)NO;             // NO+1
constexpr size_t OFF_CURO  = OFF_OFFSO + (size_t)NO + 1;         // NO
constexpr size_t OFF_CSRO  = OFF_CURO  + (size_t)NO;             // EO
constexpr size_t OFF_PART  = OFF_CSRO  + (size_t)EO;             // 512 (int)
// weight fragment scratch (split bf16), 16384 octets hi + 16384 lo = 512 KB
constexpr size_t OFF_WFHI  = OFF_PART  + 512;                    // 65536 floats
constexpr size_t OFF_WFLO  = OFF_WFHI  + 65536;                  // 65536 floats
// octet offsets within the frag arrays: Q,K,V,S @128x128 ; W2 @128x256 ; W3 @256x128
constexpr size_t WO_Q  = 0, WO_K = 2048, WO_V = 4096, WO_S = 6144, WO_W2 = 8192, WO_W3 = 12288;
// region-A recycling after attn (skip dead):
constexpr size_t OFF_MFN   = OFF_A;                              // NO*ED
constexpr size_t OFF_AGG   = OFF_MFN   + (size_t)NO * ED;        // NO*ED
constexpr size_t OFF_H     = OFF_AGG   + (size_t)NO * ED;        // NO*HIDD
constexpr size_t OFF_T     = OFF_H     + (size_t)NO * HIDD;      // NO*ED
constexpr size_t OFF_FIN   = OFF_T     + (size_t)NO * ED;        // NO*ED

extern "C" void kernel_launch(void* const* d_in, const int* in_sizes, int n_in,
                              void* d_out, int out_size, void* d_ws, size_t ws_size,
                              hipStream_t stream) {
  const int* desc_tokens = (const int*)d_in[0];
  const int* x_tokens    = (const int*)d_in[1];
  const int* mini_tokens = (const int*)d_in[2];
  const int* src         = (const int*)d_in[3];
  const int* dst         = (const int*)d_in[4];
  const int* mini_src    = (const int*)d_in[5];
  const int* mini_dst    = (const int*)d_in[6];
  const int* mini_batch  = (const int*)d_in[7];
  const int* node_batch  = (const int*)d_in[8];
  const float* desc_table  = (const float*)d_in[9];
  const float* code_table  = (const float*)d_in[10];
  const float* code_table2 = (const float*)d_in[11];
  const float* Wq = (const float*)d_in[12]; const float* bq = (const float*)d_in[13];
  const float* Wk = (const float*)d_in[14]; const float* bk = (const float*)d_in[15];
  const float* Wv = (const float*)d_in[16]; const float* bv = (const float*)d_in[17];
  const float* Wskip = (const float*)d_in[18]; const float* bskip = (const float*)d_in[19];
  const float* W2 = (const float*)d_in[20]; const float* b2 = (const float*)d_in[21];
  const float* W3 = (const float*)d_in[22]; const float* b3 = (const float*)d_in[23];
  const float* Wg = (const float*)d_in[24]; const float* bg = (const float*)d_in[25];

  float* ws = (float*)d_ws;
  float* h_n   = ws + OFF_HN;
  float* stmt  = ws + OFF_STMT;
  float* miniE = ws + OFF_A;      // becomes skip in-place
  float* qhid  = ws + OFF_QHID;   // q -> hid in-place
  float* kbuf  = ws + OFF_K;
  float* vbuf  = ws + OFF_V;
  float* gate  = ws + OFF_GATE;
  float* gate2 = ws + OFF_GATE2;
  float* fnrep = ws + OFF_FNREP;
  float* dinv  = ws + OFF_DINV;
  int* histm = (int*)(ws + OFF_HISTM);
  int* offsm = (int*)(ws + OFF_OFFSM);
  int* curm  = (int*)(ws + OFF_CURM);
  int* csrm  = (int*)(ws + OFF_CSRM);
  int* histo = (int*)(ws + OFF_HISTO);
  int* offso = (int*)(ws + OFF_OFFSO);
  int* curo  = (int*)(ws + OFF_CURO);
  int* csro  = (int*)(ws + OFF_CSRO);
  int* part  = (int*)(ws + OFF_PART);
  short8* wfhi = (short8*)(ws + OFF_WFHI);
  short8* wflo = (short8*)(ws + OFF_WFLO);
  float* mini_fn = ws + OFF_MFN;
  float* aggb    = ws + OFF_AGG;
  float* hbuf    = ws + OFF_H;
  float* tbuf    = ws + OFF_T;
  float* finalS  = ws + OFF_FIN;
  float* outp    = (float*)d_out;

  // ---- weight fragment conversion (tiny) ----
  wconv_k<<<8, 256, 0, stream>>>(Wq,    ED,   ED,   wfhi + WO_Q,  wflo + WO_Q);
  wconv_k<<<8, 256, 0, stream>>>(Wk,    ED,   ED,   wfhi + WO_K,  wflo + WO_K);
  wconv_k<<<8, 256, 0, stream>>>(Wv,    ED,   ED,   wfhi + WO_V,  wflo + WO_V);
  wconv_k<<<8, 256, 0, stream>>>(Wskip, ED,   ED,   wfhi + WO_S,  wflo + WO_S);
  wconv_k<<<16, 256, 0, stream>>>(W2,   ED,   HIDD, wfhi + WO_W2, wflo + WO_W2);
  wconv_k<<<16, 256, 0, stream>>>(W3,   HIDD, ED,   wfhi + WO_W3, wflo + WO_W3);

  // ---- CSR build: mini graph (by dst) + outer graph (by dst) + degrees ----
  hipMemsetAsync(histm, 0, (size_t)NM * 4, stream);
  hipMemsetAsync(histo, 0, (size_t)NO * 4, stream);
  hist_k<<<nblk(EM, 256), 256, 0, stream>>>(mini_dst, histm, EM);
  hist_k<<<nblk(EO, 256), 256, 0, stream>>>(dst, histo, EO);
  chunk_sum_k<<<NM / 256, 256, 0, stream>>>(histm, part, NM);
  scan_partials_k<<<1, 512, 0, stream>>>(part, NM / 256);
  scan_final_k<<<NM / 256, 256, 0, stream>>>(histm, part, offsm, curm, NM);
  csr_scatter_k<<<nblk(EM, 256), 256, 0, stream>>>(mini_src, mini_dst, curm, csrm, EM);
  chunk_sum_k<<<NO / 256, 256, 0, stream>>>(histo, part, NO);
  scan_partials_k<<<1, 512, 0, stream>>>(part, NO / 256);
  scan_final_k<<<NO / 256, 256, 0, stream>>>(histo, part, offso, curo, NO);
  csr_scatter_k<<<nblk(EO, 256), 256, 0, stream>>>(src, dst, curo, csro, EO);
  dinv_k<<<nblk(NO, 256), 256, 0, stream>>>(histo, dinv, NO);

  // ---- embeddings (vectorized, 8 rows/block) ----
  embed_mean_k<LDE><<<BB / 8, 256, 0, stream>>>(desc_tokens, desc_table, h_n);
  embed_mean_k<LO> <<<NO / 8, 256, 0, stream>>>(x_tokens, code_table2, stmt);
  embed_mean_k<LM> <<<NM / 8, 256, 0, stream>>>(mini_tokens, code_table, miniE);

  // ---- Q,K,V projections: MFMA split-bf16, one dispatch ----
  GDesc3 g3;
  g3.d[0] = {wfhi + WO_Q, wflo + WO_Q, bq, qhid};
  g3.d[1] = {wfhi + WO_K, wflo + WO_K, bk, kbuf};
  g3.d[2] = {wfhi + WO_V, wflo + WO_V, bv, vbuf};
  { dim3 g(3, NM / 128); mgemm_qkv_k<<<g, 256, 0, stream>>>(miniE, g3, ED); }

  // ---- skip projection IN-PLACE (separate dispatch: QKV reads miniE first) ----
  { dim3 g(1, NM / 128);
    mgemm_k<false><<<g, 256, 0, stream>>>(miniE, wfhi + WO_S, wflo + WO_S, bskip, miniE, ED, ED); }

  // ---- fused transformer conv (flash per dst) + gate; hid overwrites q ----
  attn_fused_k<<<NM / 4, 128, 0, stream>>>(qhid, kbuf, vbuf, miniE, offsm, csrm, Wg, bg, gate);

  // ---- global attention mini -> NO, fused with (x + stmt)*0.5 ----
  gattn_k<true><<<NO / 4, 128, 0, stream>>>(qhid, gate, mini_batch, NM, stmt, mini_fn);

  // ---- GCN conv 1: agg = A_hat * mini_fn ; h = relu(agg @ W2 + b2) ----
  gcn_gather_k<<<NO / 4, 128, 0, stream>>>(mini_fn, dinv, offso, csro, nullptr, aggb,
                                           nullptr, nullptr, nullptr);
  { dim3 g(HIDD / 128, NO / 128);
    mgemm_k<true><<<g, 256, 0, stream>>>(aggb, wfhi + WO_W2, wflo + WO_W2, b2, hbuf, ED, HIDD); }

  // ---- GCN conv 2: t = h @ W3 ; final = A_hat * t + b3 (+ fused gate2) ----
  { dim3 g(1, NO / 128);
    mgemm_k<false><<<g, 256, 0, stream>>>(hbuf, wfhi + WO_W3, wflo + WO_W3, nullptr, tbuf, HIDD, ED); }
  gcn_gather_k<<<NO / 4, 128, 0, stream>>>(tbuf, dinv, offso, csro, b3, finalS, Wg, bg, gate2);

  // ---- global attention NO -> BB ----
  gattn_k<false><<<BB / 4, 128, 0, stream>>>(finalS, gate2, node_batch, NO, nullptr, fnrep);

  // ---- cosine similarity -> d_out [BB] ----
  cosine_k<<<BB, 64, 0, stream>>>(fnrep, h_n, outp);
}

// Round 6
// 453.360 us; speedup vs baseline: 3.2250x; 1.0935x over previous
//
#include <hip/hip_runtime.h>
#include <hip/hip_bf16.h>
#include <math.h>

// Problem dims (fixed by reference)
#define BB   256      // batch
#define LDE  64       // desc tokens len
#define NO   10240    // outer nodes
#define LO   32       // x tokens len
#define NM   81920    // mini nodes
#define LM   16       // mini tokens len
#define EO   81920    // outer edges
#define EM   327680   // mini edges
#define ED   128      // embed dim E
#define HIDD 256      // hidden
#define NH   8        // heads
#define DH   16       // head dim

static inline int nblk(long long n, int b) { return (int)((n + b - 1) / b); }

typedef __attribute__((ext_vector_type(8))) short short8;
typedef __attribute__((ext_vector_type(4))) float f32x4;

// ---- fp32 <-> bf16 (RNE) helpers ----
static __device__ __forceinline__ unsigned short bf16_rne(float f) {
  unsigned u = __float_as_uint(f);
  return (unsigned short)((u + 0x7fffu + ((u >> 16) & 1u)) >> 16);
}
static __device__ __forceinline__ float bf16_to_f(unsigned short h) {
  return __uint_as_float(((unsigned)h) << 16);
}
static __device__ __forceinline__ float4 b4f(ushort4 h) {
  return make_float4(bf16_to_f(h.x), bf16_to_f(h.y), bf16_to_f(h.z), bf16_to_f(h.w));
}

// ---- embedding masked mean, vectorized: 256 thr = 8 rows x 32 float4-lanes ----
template<int L>
__global__ void __launch_bounds__(256)
embed_mean_k(const int* __restrict__ tokens, const float* __restrict__ table,
             float* __restrict__ out) {
  const int r = threadIdx.x >> 5, lane = threadIdx.x & 31;
  const int n0 = blockIdx.x * 8;
  __shared__ int toks[8][L];
  for (int i = threadIdx.x; i < 8 * L; i += 256)
    toks[i / L][i % L] = tokens[(size_t)n0 * L + i];
  __syncthreads();
  float4 acc = make_float4(0.f, 0.f, 0.f, 0.f);
  int cnt = 0;
  #pragma unroll
  for (int l = 0; l < L; ++l) {
    int t = toks[r][l];
    float4 v = *(const float4*)(table + (size_t)t * ED + lane * 4);
    float msk = (t != 0) ? 1.f : 0.f;
    cnt += (t != 0);
    acc.x = fmaf(msk, v.x, acc.x); acc.y = fmaf(msk, v.y, acc.y);
    acc.z = fmaf(msk, v.z, acc.z); acc.w = fmaf(msk, v.w, acc.w);
  }
  float inv = 1.f / (float)(cnt > 0 ? cnt : 1);
  acc.x *= inv; acc.y *= inv; acc.z *= inv; acc.w *= inv;
  *(float4*)(out + (size_t)(n0 + r) * ED + lane * 4) = acc;
}

// ================= weight -> MFMA-fragment-layout conversion (split bf16) ============
__global__ void wconv_k(const float* __restrict__ W, int K, int M,
                        short8* __restrict__ hi, short8* __restrict__ lo) {
  int idx = blockIdx.x * 256 + threadIdx.x;
  int total = (K / 32) * (M / 16) * 64;
  if (idx >= total) return;
  int lane = idx & 63;
  int nt = (idx >> 6) % (M / 16);
  int kb = (idx >> 6) / (M / 16);
  int n = nt * 16 + (lane & 15);
  int k0 = kb * 32 + ((lane >> 4) << 3);
  short8 h, l;
  #pragma unroll
  for (int j = 0; j < 8; ++j) {
    float v = W[(size_t)(k0 + j) * M + n];
    unsigned short hb = bf16_rne(v);
    h[j] = (short)hb;
    l[j] = (short)bf16_rne(v - bf16_to_f(hb));
  }
  hi[idx] = h; lo[idx] = l;
}

// ================= MFMA GEMM: C[N,M] = A[N,K] @ B[K,M] (+bias)(relu) ================
// Split-bf16: D += Ah*Bh + Ah*Bl + Al*Bh (Al*Bl ~2^-16 rel, dropped).
// 256 thr = 4 waves (2x2 over 128x128 tile). BK=32. OUTBF: store C as bf16.
template<bool RELU, bool OUTBF>
__device__ __forceinline__ void mgemm_body(const float* __restrict__ A,
                                           const short8* __restrict__ Bh,
                                           const short8* __restrict__ Bl,
                                           const float* __restrict__ bias,
                                           void* C, int K, int M, int bm0, int bn0) {
  __shared__ short8 Ah[8][64];   // [m-tile][lane] : frag-ready, lane-linear
  __shared__ short8 Al[8][64];
  const int tid = threadIdx.x;
  const int w = tid >> 6, lane = tid & 63;
  const int wm = (w & 1) * 4;    // local m-tile base
  const int wn = (w >> 1) * 4;   // local n-tile base
  const int NTm = M / 16;
  f32x4 acc[4][4];
  #pragma unroll
  for (int i = 0; i < 4; ++i)
    #pragma unroll
    for (int j = 0; j < 4; ++j) acc[i][j] = (f32x4){0.f, 0.f, 0.f, 0.f};

  const int kbn = K / 32;
  for (int kb = 0; kb < kbn; ++kb) {
    __syncthreads();
    #pragma unroll
    for (int it = 0; it < 2; ++it) {
      int u = tid + it * 256;            // 512 octets: [mt][lane]
      int mt = u >> 6, l = u & 63;
      int m = bm0 + mt * 16 + (l & 15);
      int k = kb * 32 + ((l >> 4) << 3);
      const float* ap = A + (size_t)m * K + k;
      float4 v0 = *(const float4*)ap;
      float4 v1 = *(const float4*)(ap + 4);
      float f[8] = {v0.x, v0.y, v0.z, v0.w, v1.x, v1.y, v1.z, v1.w};
      short8 hh, ll;
      #pragma unroll
      for (int j = 0; j < 8; ++j) {
        unsigned short hb = bf16_rne(f[j]);
        hh[j] = (short)hb;
        ll[j] = (short)bf16_rne(f[j] - bf16_to_f(hb));
      }
      Ah[mt][l] = hh; Al[mt][l] = ll;
    }
    __syncthreads();
    short8 bh[4], bl[4];
    #pragma unroll
    for (int j = 0; j < 4; ++j) {
      size_t bi = ((size_t)kb * NTm + (bn0 >> 4) + wn + j) * 64 + lane;
      bh[j] = Bh[bi]; bl[j] = Bl[bi];
    }
    #pragma unroll
    for (int i = 0; i < 4; ++i) {
      short8 ah = Ah[wm + i][lane];
      short8 al = Al[wm + i][lane];
      #pragma unroll
      for (int j = 0; j < 4; ++j) {
        acc[i][j] = __builtin_amdgcn_mfma_f32_16x16x32_bf16(ah, bh[j], acc[i][j], 0, 0, 0);
        acc[i][j] = __builtin_amdgcn_mfma_f32_16x16x32_bf16(ah, bl[j], acc[i][j], 0, 0, 0);
        acc[i][j] = __builtin_amdgcn_mfma_f32_16x16x32_bf16(al, bh[j], acc[i][j], 0, 0, 0);
      }
    }
  }
  // epilogue: D row = quad*4+r, col = lane&15
  const int q = lane >> 4, c = lane & 15;
  #pragma unroll
  for (int i = 0; i < 4; ++i) {
    #pragma unroll
    for (int j = 0; j < 4; ++j) {
      int col = bn0 + (wn + j) * 16 + c;
      float bv = bias ? bias[col] : 0.f;
      #pragma unroll
      for (int r = 0; r < 4; ++r) {
        int row = bm0 + (wm + i) * 16 + q * 4 + r;
        float v = acc[i][j][r] + bv;
        if (RELU) v = fmaxf(v, 0.f);
        if (OUTBF) ((unsigned short*)C)[(size_t)row * M + col] = bf16_rne(v);
        else       ((float*)C)[(size_t)row * M + col] = v;
      }
    }
  }
}

struct GDescB { const short8* bh; const short8* bl; const float* bias; unsigned short* C; };
struct GDesc4 { GDescB d[4]; };

// fused Q,K,V,Skip projections (M = 128, bf16 outputs)
__global__ void __launch_bounds__(256)
mgemm_qkvs_k(const float* __restrict__ A, GDesc4 g4, int K) {
  const GDescB d = g4.d[blockIdx.x];
  mgemm_body<false, true>(A, d.bh, d.bl, d.bias, d.C, K, 128, blockIdx.y * 128, 0);
}
template<bool RELU>
__global__ void __launch_bounds__(256)
mgemm_k(const float* __restrict__ A, const short8* __restrict__ bh,
        const short8* __restrict__ bl, const float* __restrict__ bias,
        float* C, int K, int M) {
  mgemm_body<RELU, false>(A, bh, bl, bias, C, K, M, blockIdx.y * 128, blockIdx.x * 128);
}

// ================= CSR build =================
__global__ void hist_k(const int* __restrict__ dst, int* __restrict__ hist, int E) {
  int e = blockIdx.x * 256 + threadIdx.x;
  if (e < E) atomicAdd(&hist[dst[e]], 1);
}
__global__ void chunk_sum_k(const int* __restrict__ hist, int* __restrict__ partials, int N) {
  __shared__ int sd[256];
  int i = blockIdx.x * 256 + threadIdx.x;
  sd[threadIdx.x] = (i < N) ? hist[i] : 0;
  __syncthreads();
  for (int s = 128; s > 0; s >>= 1) {
    if (threadIdx.x < s) sd[threadIdx.x] += sd[threadIdx.x + s];
    __syncthreads();
  }
  if (threadIdx.x == 0) partials[blockIdx.x] = sd[0];
}
__global__ void scan_partials_k(int* __restrict__ p, int B) {  // one block, 512 thr
  __shared__ int sd[512];
  int t = threadIdx.x;
  int v = (t < B) ? p[t] : 0;
  sd[t] = v; __syncthreads();
  for (int off = 1; off < 512; off <<= 1) {
    int a = (t >= off) ? sd[t - off] : 0;
    __syncthreads();
    sd[t] += a;
    __syncthreads();
  }
  if (t < B) p[t] = sd[t] - v;   // exclusive
}
__global__ void scan_final_k(const int* __restrict__ hist, const int* __restrict__ partials,
                             int* __restrict__ offs, int* __restrict__ cursor, int N) {
  __shared__ int sd[256];
  int i = blockIdx.x * 256 + threadIdx.x;
  int v = (i < N) ? hist[i] : 0;
  sd[threadIdx.x] = v; __syncthreads();
  for (int off = 1; off < 256; off <<= 1) {
    int a = (threadIdx.x >= off) ? sd[threadIdx.x - off] : 0;
    __syncthreads();
    sd[threadIdx.x] += a;
    __syncthreads();
  }
  if (i < N) {
    int excl = sd[threadIdx.x] - v + partials[blockIdx.x];
    offs[i] = excl;
    cursor[i] = excl;
    if (i == N - 1) offs[N] = excl + v;
  }
}
__global__ void csr_scatter_k(const int* __restrict__ src, const int* __restrict__ dst,
                              int* __restrict__ cursor, int* __restrict__ csr_src, int E) {
  int e = blockIdx.x * 256 + threadIdx.x;
  if (e >= E) return;
  int pos = atomicAdd(&cursor[dst[e]], 1);
  csr_src[pos] = src[e];
}
__global__ void dinv_k(const int* __restrict__ hist, float* __restrict__ dinv, int N) {
  int i = blockIdx.x * 256 + threadIdx.x;
  if (i < N) dinv[i] = 1.f / sqrtf(1.f + (float)hist[i]);
}

// ============ fused TransformerConv (bf16 streams): flash per dst + skip + gate ======
// 128 thr = 4 nodes x 32 lanes; each lane owns 4 channels (8 B bf16 loads).
__global__ void __launch_bounds__(128)
attn_fused_k(unsigned short* qh, const unsigned short* __restrict__ kk,
             const unsigned short* __restrict__ vv, const unsigned short* __restrict__ skip,
             const int* __restrict__ offs, const int* __restrict__ csr,
             const float* __restrict__ Wg, const float* __restrict__ bg,
             float* __restrict__ gateOut) {
  const int g = threadIdx.x >> 5, lane = threadIdx.x & 31;
  const int n = blockIdx.x * 4 + g;
  float4 q = b4f(*(const ushort4*)(qh + (size_t)n * ED + lane * 4));
  int lo = offs[n], hi = offs[n + 1];
  float4 O = make_float4(0.f, 0.f, 0.f, 0.f);
  float m = -INFINITY, l = 0.f;
  for (int e = lo; e < hi; ++e) {
    int s = csr[e];
    float4 kt = b4f(*(const ushort4*)(kk + (size_t)s * ED + lane * 4));
    float4 vt = b4f(*(const ushort4*)(vv + (size_t)s * ED + lane * 4));
    float p = q.x * kt.x + q.y * kt.y + q.z * kt.z + q.w * kt.w;
    p += __shfl_xor(p, 1, 64);
    p += __shfl_xor(p, 2, 64);
    float sc = p * 0.25f;               // 1/sqrt(Dh)
    float mn = fmaxf(m, sc);
    float scale = __expf(m - mn);       // exp(-inf)=0 handles first edge
    float pe = __expf(sc - mn);
    l = l * scale + pe;
    O.x = O.x * scale + pe * vt.x; O.y = O.y * scale + pe * vt.y;
    O.z = O.z * scale + pe * vt.z; O.w = O.w * scale + pe * vt.w;
    m = mn;
  }
  float inv = 1.f / (l + 1e-16f);
  float4 sk = b4f(*(const ushort4*)(skip + (size_t)n * ED + lane * 4));
  float4 out = make_float4(O.x * inv + sk.x, O.y * inv + sk.y,
                           O.z * inv + sk.z, O.w * inv + sk.w);
  ushort4 ob = make_ushort4(bf16_rne(out.x), bf16_rne(out.y),
                            bf16_rne(out.z), bf16_rne(out.w));
  *(ushort4*)(qh + (size_t)n * ED + lane * 4) = ob;
  // fused gate = hid @ Wg + bg (reduce over the 32 lanes of this node)
  float4 wg = *(const float4*)(Wg + lane * 4);
  float ps = out.x * wg.x + out.y * wg.y + out.z * wg.z + out.w * wg.w;
  #pragma unroll
  for (int o = 1; o <= 16; o <<= 1) ps += __shfl_xor(ps, o, 64);
  if (lane == 0) gateOut[n] = ps + bg[0];
}

// ============ GCN gather (fp32): 4 nodes x 32 float4-lanes ============
__global__ void __launch_bounds__(128)
gcn_gather_k(const float* __restrict__ x, const float* __restrict__ dinv,
             const int* __restrict__ offs, const int* __restrict__ csr,
             const float* __restrict__ bias, float* __restrict__ out,
             const float* __restrict__ Wg, const float* __restrict__ bg,
             float* __restrict__ gateOut) {
  const int g = threadIdx.x >> 5, lane = threadIdx.x & 31;
  const int n = blockIdx.x * 4 + g;
  float di = dinv[n];
  float4 xs = *(const float4*)(x + (size_t)n * ED + lane * 4);
  float w0 = di * di;
  float4 acc = make_float4(w0 * xs.x, w0 * xs.y, w0 * xs.z, w0 * xs.w);
  int lo = offs[n], hi = offs[n + 1];
  for (int e = lo; e < hi; ++e) {
    int s = csr[e];
    float w = di * dinv[s];
    float4 v = *(const float4*)(x + (size_t)s * ED + lane * 4);
    acc.x = fmaf(w, v.x, acc.x); acc.y = fmaf(w, v.y, acc.y);
    acc.z = fmaf(w, v.z, acc.z); acc.w = fmaf(w, v.w, acc.w);
  }
  if (bias) {
    float4 b4 = *(const float4*)(bias + lane * 4);
    acc.x += b4.x; acc.y += b4.y; acc.z += b4.z; acc.w += b4.w;
  }
  *(float4*)(out + (size_t)n * ED + lane * 4) = acc;
  if (gateOut) {
    float4 wg = *(const float4*)(Wg + lane * 4);
    float ps = acc.x * wg.x + acc.y * wg.y + acc.z * wg.z + acc.w * wg.w;
    #pragma unroll
    for (int o = 1; o <= 16; o <<= 1) ps += __shfl_xor(ps, o, 64);
    if (lane == 0) gateOut[n] = ps + bg[0];
  }
}

// ============ global attention over contiguous (sorted) segments ============
static __device__ __forceinline__ int lower_bound_d(const int* a, int n, int key) {
  int lo = 0, hi = n;
  while (lo < hi) { int mid = (lo + hi) >> 1; if (a[mid] < key) lo = mid + 1; else hi = mid; }
  return lo;
}
// XBF: x rows stored bf16. 128 thr = 4 output rows x 32 lanes (4 ch/lane).
template<bool COMBINE, bool XBF>
__global__ void __launch_bounds__(128)
gattn_k(const void* __restrict__ xv, const float* __restrict__ gate,
        const int* __restrict__ seg, int Ntot,
        const float* __restrict__ other, float* __restrict__ out) {
  const int g = threadIdx.x >> 5, lane = threadIdx.x & 31;
  const int n = blockIdx.x * 4 + g;
  __shared__ int sh[4][2];
  if (lane == 0) {
    sh[g][0] = lower_bound_d(seg, Ntot, n);
    sh[g][1] = lower_bound_d(seg, Ntot, n + 1);
  }
  __syncthreads();
  int lo = sh[g][0], hi = sh[g][1];
  float m = -INFINITY;
  for (int j = lo; j < hi; ++j) m = fmaxf(m, gate[j]);
  float ssum = 0.f;
  for (int j = lo; j < hi; ++j) ssum += __expf(gate[j] - m);
  float inv = 1.f / (ssum + 1e-16f);
  float4 acc = make_float4(0.f, 0.f, 0.f, 0.f);
  for (int j = lo; j < hi; ++j) {
    float a = __expf(gate[j] - m) * inv;
    float4 v;
    if (XBF) v = b4f(*((const ushort4*)((const unsigned short*)xv + (size_t)j * ED + lane * 4)));
    else     v = *((const float4*)((const float*)xv + (size_t)j * ED) + lane);
    acc.x = fmaf(a, v.x, acc.x); acc.y = fmaf(a, v.y, acc.y);
    acc.z = fmaf(a, v.z, acc.z); acc.w = fmaf(a, v.w, acc.w);
  }
  if (COMBINE) {
    float4 o4 = *(const float4*)(other + (size_t)n * ED + lane * 4);
    acc.x = (acc.x + o4.x) * 0.5f; acc.y = (acc.y + o4.y) * 0.5f;
    acc.z = (acc.z + o4.z) * 0.5f; acc.w = (acc.w + o4.w) * 0.5f;
  }
  *(float4*)(out + (size_t)n * ED + lane * 4) = acc;
}

// ---- cosine similarity: one wave per batch row ----
__global__ void cosine_k(const float* __restrict__ a, const float* __restrict__ b,
                         float* __restrict__ out) {
  int n = blockIdx.x, lane = threadIdx.x;
  float x0 = a[(size_t)n * ED + lane], x1 = a[(size_t)n * ED + 64 + lane];
  float y0 = b[(size_t)n * ED + lane], y1 = b[(size_t)n * ED + 64 + lane];
  float dot = x0 * y0 + x1 * y1;
  float na = x0 * x0 + x1 * x1;
  float nb = y0 * y0 + y1 * y1;
  #pragma unroll
  for (int o = 32; o > 0; o >>= 1) {
    dot += __shfl_down(dot, o, 64);
    na  += __shfl_down(na,  o, 64);
    nb  += __shfl_down(nb,  o, 64);
  }
  if (lane == 0)
    out[n] = dot / (fmaxf(sqrtf(na), 1e-8f) * fmaxf(sqrtf(nb), 1e-8f));
}

// ---- workspace layout (4-byte element offsets) ----
// q/k/v/skip are bf16 now: q in first half of QHID region; k in first half of K
// region; skip in second half of K region; v in first half of V region.
constexpr size_t OFF_HN    = 0;                                  // BB*ED
constexpr size_t OFF_STMT  = OFF_HN    + (size_t)BB * ED;        // NO*ED
constexpr size_t OFF_A     = OFF_STMT  + (size_t)NO * ED;        // NM*ED (miniE -> recycled)
constexpr size_t OFF_QHID  = OFF_A     + (size_t)NM * ED;        // NM*ED floats (bf16 q->hid in half)
constexpr size_t OFF_K     = OFF_QHID  + (size_t)NM * ED;        // NM*ED floats (bf16 k + bf16 skip)
constexpr size_t OFF_V     = OFF_K     + (size_t)NM * ED;        // NM*ED floats (bf16 v in half)
constexpr size_t T0        = OFF_V     + (size_t)NM * ED;
constexpr size_t OFF_GATE  = T0;                                 // NM
constexpr size_t OFF_GATE2 = OFF_GATE  + (size_t)NM;             // NO
constexpr size_t OFF_FNREP = OFF_GATE2 + (size_t)NO;             // BB*ED
constexpr size_t OFF_DINV  = OFF_FNREP + (size_t)BB * ED;        // NO
constexpr size_t OFF_HISTM = OFF_DINV  + (size_t)NO;             // NM (int)
constexpr size_t OFF_OFFSM = OFF_HISTM + (size_t)NM;             // NM+1
constexpr size_t OFF_CURM  = OFF_OFFSM + (size_t)NM + 1;         // NM
constexpr size_t OFF_CSRM  = OFF_CURM  + (size_t)NM;             // EM
constexpr size_t OFF_HISTO = OFF_CSRM  + (size_t)EM;             // NO
constexpr size_t OFF_OFFSO = OFF_HISTO + (size_t)NO;             // NO+1
constexpr size_t OFF_CURO  = OFF_OFFSO + (size_t)NO + 1;         // NO
constexpr size_t OFF_CSRO  = OFF_CURO  + (size_t)NO;             // EO
constexpr size_t OFF_PART  = OFF_CSRO  + (size_t)EO;             // 512 (int)
constexpr size_t OFF_WFHI  = OFF_PART  + 512;                    // 65536 floats
constexpr size_t OFF_WFLO  = OFF_WFHI  + 65536;                  // 65536 floats
constexpr size_t WO_Q  = 0, WO_K = 2048, WO_V = 4096, WO_S = 6144, WO_W2 = 8192, WO_W3 = 12288;
// region-A recycling after attn (miniE dead):
constexpr size_t OFF_MFN   = OFF_A;                              // NO*ED
constexpr size_t OFF_AGG   = OFF_MFN   + (size_t)NO * ED;        // NO*ED
constexpr size_t OFF_H     = OFF_AGG   + (size_t)NO * ED;        // NO*HIDD
constexpr size_t OFF_T     = OFF_H     + (size_t)NO * HIDD;      // NO*ED
constexpr size_t OFF_FIN   = OFF_T     + (size_t)NO * ED;        // NO*ED

extern "C" void kernel_launch(void* const* d_in, const int* in_sizes, int n_in,
                              void* d_out, int out_size, void* d_ws, size_t ws_size,
                              hipStream_t stream) {
  const int* desc_tokens = (const int*)d_in[0];
  const int* x_tokens    = (const int*)d_in[1];
  const int* mini_tokens = (const int*)d_in[2];
  const int* src         = (const int*)d_in[3];
  const int* dst         = (const int*)d_in[4];
  const int* mini_src    = (const int*)d_in[5];
  const int* mini_dst    = (const int*)d_in[6];
  const int* mini_batch  = (const int*)d_in[7];
  const int* node_batch  = (const int*)d_in[8];
  const float* desc_table  = (const float*)d_in[9];
  const float* code_table  = (const float*)d_in[10];
  const float* code_table2 = (const float*)d_in[11];
  const float* Wq = (const float*)d_in[12]; const float* bq = (const float*)d_in[13];
  const float* Wk = (const float*)d_in[14]; const float* bk = (const float*)d_in[15];
  const float* Wv = (const float*)d_in[16]; const float* bv = (const float*)d_in[17];
  const float* Wskip = (const float*)d_in[18]; const float* bskip = (const float*)d_in[19];
  const float* W2 = (const float*)d_in[20]; const float* b2 = (const float*)d_in[21];
  const float* W3 = (const float*)d_in[22]; const float* b3 = (const float*)d_in[23];
  const float* Wg = (const float*)d_in[24]; const float* bg = (const float*)d_in[25];

  float* ws = (float*)d_ws;
  float* h_n   = ws + OFF_HN;
  float* stmt  = ws + OFF_STMT;
  float* miniE = ws + OFF_A;
  unsigned short* qhid_b = (unsigned short*)(ws + OFF_QHID);  // q -> hid, bf16
  unsigned short* kbuf_b = (unsigned short*)(ws + OFF_K);     // k, bf16
  unsigned short* skip_b = kbuf_b + (size_t)NM * ED;          // skip, bf16 (2nd half)
  unsigned short* vbuf_b = (unsigned short*)(ws + OFF_V);     // v, bf16
  float* gate  = ws + OFF_GATE;
  float* gate2 = ws + OFF_GATE2;
  float* fnrep = ws + OFF_FNREP;
  float* dinv  = ws + OFF_DINV;
  int* histm = (int*)(ws + OFF_HISTM);
  int* offsm = (int*)(ws + OFF_OFFSM);
  int* curm  = (int*)(ws + OFF_CURM);
  int* csrm  = (int*)(ws + OFF_CSRM);
  int* histo = (int*)(ws + OFF_HISTO);
  int* offso = (int*)(ws + OFF_OFFSO);
  int* curo  = (int*)(ws + OFF_CURO);
  int* csro  = (int*)(ws + OFF_CSRO);
  int* part  = (int*)(ws + OFF_PART);
  short8* wfhi = (short8*)(ws + OFF_WFHI);
  short8* wflo = (short8*)(ws + OFF_WFLO);
  float* mini_fn = ws + OFF_MFN;
  float* aggb    = ws + OFF_AGG;
  float* hbuf    = ws + OFF_H;
  float* tbuf    = ws + OFF_T;
  float* finalS  = ws + OFF_FIN;
  float* outp    = (float*)d_out;

  // ---- weight fragment conversion (tiny) ----
  wconv_k<<<8, 256, 0, stream>>>(Wq,    ED,   ED,   wfhi + WO_Q,  wflo + WO_Q);
  wconv_k<<<8, 256, 0, stream>>>(Wk,    ED,   ED,   wfhi + WO_K,  wflo + WO_K);
  wconv_k<<<8, 256, 0, stream>>>(Wv,    ED,   ED,   wfhi + WO_V,  wflo + WO_V);
  wconv_k<<<8, 256, 0, stream>>>(Wskip, ED,   ED,   wfhi + WO_S,  wflo + WO_S);
  wconv_k<<<16, 256, 0, stream>>>(W2,   ED,   HIDD, wfhi + WO_W2, wflo + WO_W2);
  wconv_k<<<16, 256, 0, stream>>>(W3,   HIDD, ED,   wfhi + WO_W3, wflo + WO_W3);

  // ---- CSR build: mini graph (by dst) + outer graph (by dst) + degrees ----
  hipMemsetAsync(histm, 0, (size_t)NM * 4, stream);
  hipMemsetAsync(histo, 0, (size_t)NO * 4, stream);
  hist_k<<<nblk(EM, 256), 256, 0, stream>>>(mini_dst, histm, EM);
  hist_k<<<nblk(EO, 256), 256, 0, stream>>>(dst, histo, EO);
  chunk_sum_k<<<NM / 256, 256, 0, stream>>>(histm, part, NM);
  scan_partials_k<<<1, 512, 0, stream>>>(part, NM / 256);
  scan_final_k<<<NM / 256, 256, 0, stream>>>(histm, part, offsm, curm, NM);
  csr_scatter_k<<<nblk(EM, 256), 256, 0, stream>>>(mini_src, mini_dst, curm, csrm, EM);
  chunk_sum_k<<<NO / 256, 256, 0, stream>>>(histo, part, NO);
  scan_partials_k<<<1, 512, 0, stream>>>(part, NO / 256);
  scan_final_k<<<NO / 256, 256, 0, stream>>>(histo, part, offso, curo, NO);
  csr_scatter_k<<<nblk(EO, 256), 256, 0, stream>>>(src, dst, curo, csro, EO);
  dinv_k<<<nblk(NO, 256), 256, 0, stream>>>(histo, dinv, NO);

  // ---- embeddings (vectorized, 8 rows/block) ----
  embed_mean_k<LDE><<<BB / 8, 256, 0, stream>>>(desc_tokens, desc_table, h_n);
  embed_mean_k<LO> <<<NO / 8, 256, 0, stream>>>(x_tokens, code_table2, stmt);
  embed_mean_k<LM> <<<NM / 8, 256, 0, stream>>>(mini_tokens, code_table, miniE);

  // ---- Q,K,V,Skip projections: MFMA split-bf16, bf16 outputs, ONE dispatch ----
  GDesc4 g4;
  g4.d[0] = {wfhi + WO_Q, wflo + WO_Q, bq,    qhid_b};
  g4.d[1] = {wfhi + WO_K, wflo + WO_K, bk,    kbuf_b};
  g4.d[2] = {wfhi + WO_V, wflo + WO_V, bv,    vbuf_b};
  g4.d[3] = {wfhi + WO_S, wflo + WO_S, bskip, skip_b};
  { dim3 g(4, NM / 128); mgemm_qkvs_k<<<g, 256, 0, stream>>>(miniE, g4, ED); }

  // ---- fused transformer conv (flash per dst, bf16 streams) + gate ----
  attn_fused_k<<<NM / 4, 128, 0, stream>>>(qhid_b, kbuf_b, vbuf_b, skip_b,
                                           offsm, csrm, Wg, bg, gate);

  // ---- global attention mini -> NO, fused with (x + stmt)*0.5 ----
  gattn_k<true, true><<<NO / 4, 128, 0, stream>>>(qhid_b, gate, mini_batch, NM, stmt, mini_fn);

  // ---- GCN conv 1: agg = A_hat * mini_fn ; h = relu(agg @ W2 + b2) ----
  gcn_gather_k<<<NO / 4, 128, 0, stream>>>(mini_fn, dinv, offso, csro, nullptr, aggb,
                                           nullptr, nullptr, nullptr);
  { dim3 g(HIDD / 128, NO / 128);
    mgemm_k<true><<<g, 256, 0, stream>>>(aggb, wfhi + WO_W2, wflo + WO_W2, b2, hbuf, ED, HIDD); }

  // ---- GCN conv 2: t = h @ W3 ; final = A_hat * t + b3 (+ fused gate2) ----
  { dim3 g(1, NO / 128);
    mgemm_k<false><<<g, 256, 0, stream>>>(hbuf, wfhi + WO_W3, wflo + WO_W3, nullptr, tbuf, HIDD, ED); }
  gcn_gather_k<<<NO / 4, 128, 0, stream>>>(tbuf, dinv, offso, csro, b3, finalS, Wg, bg, gate2);

  // ---- global attention NO -> BB ----
  gattn_k<false, false><<<BB / 4, 128, 0, stream>>>(finalS, gate2, node_batch, NO, nullptr, fnrep);

  // ---- cosine similarity -> d_out [BB] ----
  cosine_k<<<BB, 64, 0, stream>>>(fnrep, h_n, outp);
}

// Round 7
// 428.549 us; speedup vs baseline: 3.4117x; 1.0579x over previous
//
#include <hip/hip_runtime.h>
#include <hip/hip_bf16.h>
#include <math.h>

// Problem dims (fixed by reference)
#define BB   256      // batch
#define LDE  64       // desc tokens len
#define NO   10240    // outer nodes
#define LO   32       // x tokens len
#define NM   81920    // mini nodes
#define LM   16       // mini tokens len
#define EO   81920    // outer edges
#define EM   327680   // mini edges
#define ED   128      // embed dim E
#define HIDD 256      // hidden
#define NH   8        // heads
#define DH   16       // head dim
#define VV   10000    // vocab

static inline int nblk(long long n, int b) { return (int)((n + b - 1) / b); }

typedef __attribute__((ext_vector_type(8))) short short8;
typedef __attribute__((ext_vector_type(4))) float f32x4;

// ---- fp32 <-> bf16 (RNE) helpers ----
static __device__ __forceinline__ unsigned short bf16_rne(float f) {
  unsigned u = __float_as_uint(f);
  return (unsigned short)((u + 0x7fffu + ((u >> 16) & 1u)) >> 16);
}
static __device__ __forceinline__ float bf16_to_f(unsigned short h) {
  return __uint_as_float(((unsigned)h) << 16);
}
static __device__ __forceinline__ float4 b4f(ushort4 h) {
  return make_float4(bf16_to_f(h.x), bf16_to_f(h.y), bf16_to_f(h.z), bf16_to_f(h.w));
}

// ---- table fp32 -> bf16 conversion ----
__global__ void tconv_k(const float* __restrict__ t, unsigned short* __restrict__ o, int n4) {
  int i = blockIdx.x * 256 + threadIdx.x;
  if (i >= n4) return;
  float4 v = *(const float4*)(t + (size_t)i * 4);
  *(ushort4*)(o + (size_t)i * 4) =
      make_ushort4(bf16_rne(v.x), bf16_rne(v.y), bf16_rne(v.z), bf16_rne(v.w));
}

// ---- embedding masked mean: 256 thr = 8 rows x 32 4-elem lanes ----
// TBF: table stored bf16. OUTBF: output stored bf16.
template<int L, bool TBF, bool OUTBF>
__global__ void __launch_bounds__(256)
embed_mean_k(const int* __restrict__ tokens, const void* __restrict__ table,
             void* __restrict__ out) {
  const int r = threadIdx.x >> 5, lane = threadIdx.x & 31;
  const int n0 = blockIdx.x * 8;
  __shared__ int toks[8][L];
  for (int i = threadIdx.x; i < 8 * L; i += 256)
    toks[i / L][i % L] = tokens[(size_t)n0 * L + i];
  __syncthreads();
  float4 acc = make_float4(0.f, 0.f, 0.f, 0.f);
  int cnt = 0;
  #pragma unroll
  for (int l = 0; l < L; ++l) {
    int t = toks[r][l];
    float4 v;
    if (TBF) v = b4f(*((const ushort4*)((const unsigned short*)table + (size_t)t * ED + lane * 4)));
    else     v = *(const float4*)((const float*)table + (size_t)t * ED + lane * 4);
    float msk = (t != 0) ? 1.f : 0.f;
    cnt += (t != 0);
    acc.x = fmaf(msk, v.x, acc.x); acc.y = fmaf(msk, v.y, acc.y);
    acc.z = fmaf(msk, v.z, acc.z); acc.w = fmaf(msk, v.w, acc.w);
  }
  float inv = 1.f / (float)(cnt > 0 ? cnt : 1);
  acc.x *= inv; acc.y *= inv; acc.z *= inv; acc.w *= inv;
  if (OUTBF)
    *(ushort4*)((unsigned short*)out + (size_t)(n0 + r) * ED + lane * 4) =
        make_ushort4(bf16_rne(acc.x), bf16_rne(acc.y), bf16_rne(acc.z), bf16_rne(acc.w));
  else
    *(float4*)((float*)out + (size_t)(n0 + r) * ED + lane * 4) = acc;
}

// ================= weight -> MFMA-fragment-layout conversion (split bf16) ============
__global__ void wconv_k(const float* __restrict__ W, int K, int M,
                        short8* __restrict__ hi, short8* __restrict__ lo) {
  int idx = blockIdx.x * 256 + threadIdx.x;
  int total = (K / 32) * (M / 16) * 64;
  if (idx >= total) return;
  int lane = idx & 63;
  int nt = (idx >> 6) % (M / 16);
  int kb = (idx >> 6) / (M / 16);
  int n = nt * 16 + (lane & 15);
  int k0 = kb * 32 + ((lane >> 4) << 3);
  short8 h, l;
  #pragma unroll
  for (int j = 0; j < 8; ++j) {
    float v = W[(size_t)(k0 + j) * M + n];
    unsigned short hb = bf16_rne(v);
    h[j] = (short)hb;
    l[j] = (short)bf16_rne(v - bf16_to_f(hb));
  }
  hi[idx] = h; lo[idx] = l;
}

// ========== fused QKVS GEMM: A (bf16, NMx128) staged to LDS once; 4 matrices ==========
// Per matrix: D = A @ W (2-term: A*Wh + A*Wl); outputs bf16.
struct QDesc { const short8* bh; const short8* bl; const float* bias; unsigned short* C; };
struct QDesc4 { QDesc d[4]; };

__global__ void __launch_bounds__(256)
mgemm_qkvs2_k(const unsigned short* __restrict__ Ab, QDesc4 g4) {
  __shared__ unsigned short Asl[128][136];   // +8 pad: 2-way-max bank aliasing
  const int tid = threadIdx.x;
  const int n0 = blockIdx.x * 128;
  // stage A block (32 KB) as 2048 16B chunks, perfectly coalesced
  #pragma unroll
  for (int i = 0; i < 8; ++i) {
    int c = tid + i * 256;
    int row = c >> 4, koct = c & 15;
    *(short8*)&Asl[row][koct * 8] =
        *(const short8*)(Ab + (size_t)(n0 + row) * ED + koct * 8);
  }
  __syncthreads();
  const int w = tid >> 6, lane = tid & 63;
  const int wm = (w & 1) * 4, wn = (w >> 1) * 4;
  const int r = lane & 15, qd = lane >> 4;
  #pragma unroll
  for (int mi = 0; mi < 4; ++mi) {
    const QDesc d = g4.d[mi];
    f32x4 acc[4][4];
    #pragma unroll
    for (int i = 0; i < 4; ++i)
      #pragma unroll
      for (int j = 0; j < 4; ++j) acc[i][j] = (f32x4){0.f, 0.f, 0.f, 0.f};
    #pragma unroll
    for (int kb = 0; kb < 4; ++kb) {
      short8 bh[4], bl[4];
      #pragma unroll
      for (int j = 0; j < 4; ++j) {
        size_t bi = ((size_t)kb * 8 + wn + j) * 64 + lane;
        bh[j] = d.bh[bi]; bl[j] = d.bl[bi];
      }
      #pragma unroll
      for (int i = 0; i < 4; ++i) {
        short8 a = *(const short8*)&Asl[(wm + i) * 16 + r][kb * 32 + qd * 8];
        #pragma unroll
        for (int j = 0; j < 4; ++j) {
          acc[i][j] = __builtin_amdgcn_mfma_f32_16x16x32_bf16(a, bh[j], acc[i][j], 0, 0, 0);
          acc[i][j] = __builtin_amdgcn_mfma_f32_16x16x32_bf16(a, bl[j], acc[i][j], 0, 0, 0);
        }
      }
    }
    // epilogue: row = quad*4+rr, col = lane&15 ; bf16 stores
    #pragma unroll
    for (int i = 0; i < 4; ++i)
      #pragma unroll
      for (int j = 0; j < 4; ++j) {
        int col = (wn + j) * 16 + r;
        float bv = d.bias[col];
        #pragma unroll
        for (int rr = 0; rr < 4; ++rr) {
          int row = (wm + i) * 16 + qd * 4 + rr;
          d.C[(size_t)(n0 + row) * ED + col] = bf16_rne(acc[i][j][rr] + bv);
        }
      }
  }
}

// ================= MFMA GEMM (fp32 A, split-bf16 3-term): W2 / W3 path ==============
template<bool RELU>
__global__ void __launch_bounds__(256)
mgemm_k(const float* __restrict__ A, const short8* __restrict__ Bh,
        const short8* __restrict__ Bl, const float* __restrict__ bias,
        float* C, int K, int M) {
  __shared__ short8 Ah[8][64];
  __shared__ short8 Al[8][64];
  const int bm0 = blockIdx.y * 128, bn0 = blockIdx.x * 128;
  const int tid = threadIdx.x;
  const int w = tid >> 6, lane = tid & 63;
  const int wm = (w & 1) * 4, wn = (w >> 1) * 4;
  const int NTm = M / 16;
  f32x4 acc[4][4];
  #pragma unroll
  for (int i = 0; i < 4; ++i)
    #pragma unroll
    for (int j = 0; j < 4; ++j) acc[i][j] = (f32x4){0.f, 0.f, 0.f, 0.f};
  const int kbn = K / 32;
  for (int kb = 0; kb < kbn; ++kb) {
    __syncthreads();
    #pragma unroll
    for (int it = 0; it < 2; ++it) {
      int u = tid + it * 256;
      int mt = u >> 6, l = u & 63;
      int m = bm0 + mt * 16 + (l & 15);
      int k = kb * 32 + ((l >> 4) << 3);
      const float* ap = A + (size_t)m * K + k;
      float4 v0 = *(const float4*)ap;
      float4 v1 = *(const float4*)(ap + 4);
      float f[8] = {v0.x, v0.y, v0.z, v0.w, v1.x, v1.y, v1.z, v1.w};
      short8 hh, ll;
      #pragma unroll
      for (int j = 0; j < 8; ++j) {
        unsigned short hb = bf16_rne(f[j]);
        hh[j] = (short)hb;
        ll[j] = (short)bf16_rne(f[j] - bf16_to_f(hb));
      }
      Ah[mt][l] = hh; Al[mt][l] = ll;
    }
    __syncthreads();
    short8 bh[4], bl[4];
    #pragma unroll
    for (int j = 0; j < 4; ++j) {
      size_t bi = ((size_t)kb * NTm + (bn0 >> 4) + wn + j) * 64 + lane;
      bh[j] = Bh[bi]; bl[j] = Bl[bi];
    }
    #pragma unroll
    for (int i = 0; i < 4; ++i) {
      short8 ah = Ah[wm + i][lane];
      short8 al = Al[wm + i][lane];
      #pragma unroll
      for (int j = 0; j < 4; ++j) {
        acc[i][j] = __builtin_amdgcn_mfma_f32_16x16x32_bf16(ah, bh[j], acc[i][j], 0, 0, 0);
        acc[i][j] = __builtin_amdgcn_mfma_f32_16x16x32_bf16(ah, bl[j], acc[i][j], 0, 0, 0);
        acc[i][j] = __builtin_amdgcn_mfma_f32_16x16x32_bf16(al, bh[j], acc[i][j], 0, 0, 0);
      }
    }
  }
  const int q = lane >> 4, c = lane & 15;
  #pragma unroll
  for (int i = 0; i < 4; ++i)
    #pragma unroll
    for (int j = 0; j < 4; ++j) {
      int col = bn0 + (wn + j) * 16 + c;
      float bv = bias ? bias[col] : 0.f;
      #pragma unroll
      for (int rr = 0; rr < 4; ++rr) {
        int row = bm0 + (wm + i) * 16 + q * 4 + rr;
        float v = acc[i][j][rr] + bv;
        if (RELU) v = fmaxf(v, 0.f);
        C[(size_t)row * M + col] = v;
      }
    }
}

// ================= CSR build (merged kernels) =================
__global__ void hist2_k(const int* __restrict__ dm, int* __restrict__ hm,
                        const int* __restrict__ dd, int* __restrict__ ho) {
  int e = blockIdx.x * 256 + threadIdx.x;
  if (e < EM) atomicAdd(&hm[dm[e]], 1);
  else { int e2 = e - EM; if (e2 < EO) atomicAdd(&ho[dd[e2]], 1); }
}
__global__ void chunk_sum_k(const int* __restrict__ hist, int* __restrict__ partials, int N) {
  __shared__ int sd[256];
  int i = blockIdx.x * 256 + threadIdx.x;
  sd[threadIdx.x] = (i < N) ? hist[i] : 0;
  __syncthreads();
  for (int s = 128; s > 0; s >>= 1) {
    if (threadIdx.x < s) sd[threadIdx.x] += sd[threadIdx.x + s];
    __syncthreads();
  }
  if (threadIdx.x == 0) partials[blockIdx.x] = sd[0];
}
__global__ void scan_partials_k(int* __restrict__ p, int B) {  // one block, 512 thr
  __shared__ int sd[512];
  int t = threadIdx.x;
  int v = (t < B) ? p[t] : 0;
  sd[t] = v; __syncthreads();
  for (int off = 1; off < 512; off <<= 1) {
    int a = (t >= off) ? sd[t - off] : 0;
    __syncthreads();
    sd[t] += a;
    __syncthreads();
  }
  if (t < B) p[t] = sd[t] - v;   // exclusive
}
__global__ void scan_final_k(const int* __restrict__ hist, const int* __restrict__ partials,
                             int* __restrict__ offs, int* __restrict__ cursor, int N) {
  __shared__ int sd[256];
  int i = blockIdx.x * 256 + threadIdx.x;
  int v = (i < N) ? hist[i] : 0;
  sd[threadIdx.x] = v; __syncthreads();
  for (int off = 1; off < 256; off <<= 1) {
    int a = (threadIdx.x >= off) ? sd[threadIdx.x - off] : 0;
    __syncthreads();
    sd[threadIdx.x] += a;
    __syncthreads();
  }
  if (i < N) {
    int excl = sd[threadIdx.x] - v + partials[blockIdx.x];
    offs[i] = excl;
    cursor[i] = excl;
    if (i == N - 1) offs[N] = excl + v;
  }
}
__global__ void scatter2_k(const int* __restrict__ sm, const int* __restrict__ dm,
                           int* __restrict__ cm, int* __restrict__ km,
                           const int* __restrict__ so, const int* __restrict__ dd,
                           int* __restrict__ co, int* __restrict__ ko) {
  int e = blockIdx.x * 256 + threadIdx.x;
  if (e < EM) {
    int pos = atomicAdd(&cm[dm[e]], 1);
    km[pos] = sm[e];
  } else {
    int e2 = e - EM;
    if (e2 < EO) {
      int pos = atomicAdd(&co[dd[e2]], 1);
      ko[pos] = so[e2];
    }
  }
}
__global__ void dinv_k(const int* __restrict__ hist, float* __restrict__ dinv, int N) {
  int i = blockIdx.x * 256 + threadIdx.x;
  if (i < N) dinv[i] = 1.f / sqrtf(1.f + (float)hist[i]);
}

// ============ fused TransformerConv (bf16 streams): flash per dst + skip + gate ======
__global__ void __launch_bounds__(128)
attn_fused_k(unsigned short* qh, const unsigned short* __restrict__ kk,
             const unsigned short* __restrict__ vv, const unsigned short* __restrict__ skip,
             const int* __restrict__ offs, const int* __restrict__ csr,
             const float* __restrict__ Wg, const float* __restrict__ bg,
             float* __restrict__ gateOut) {
  const int g = threadIdx.x >> 5, lane = threadIdx.x & 31;
  const int n = blockIdx.x * 4 + g;
  float4 q = b4f(*(const ushort4*)(qh + (size_t)n * ED + lane * 4));
  int lo = offs[n], hi = offs[n + 1];
  float4 O = make_float4(0.f, 0.f, 0.f, 0.f);
  float m = -INFINITY, l = 0.f;
  for (int e = lo; e < hi; ++e) {
    int s = csr[e];
    float4 kt = b4f(*(const ushort4*)(kk + (size_t)s * ED + lane * 4));
    float4 vt = b4f(*(const ushort4*)(vv + (size_t)s * ED + lane * 4));
    float p = q.x * kt.x + q.y * kt.y + q.z * kt.z + q.w * kt.w;
    p += __shfl_xor(p, 1, 64);
    p += __shfl_xor(p, 2, 64);
    float sc = p * 0.25f;               // 1/sqrt(Dh)
    float mn = fmaxf(m, sc);
    float scale = __expf(m - mn);       // exp(-inf)=0 handles first edge
    float pe = __expf(sc - mn);
    l = l * scale + pe;
    O.x = O.x * scale + pe * vt.x; O.y = O.y * scale + pe * vt.y;
    O.z = O.z * scale + pe * vt.z; O.w = O.w * scale + pe * vt.w;
    m = mn;
  }
  float inv = 1.f / (l + 1e-16f);
  float4 sk = b4f(*(const ushort4*)(skip + (size_t)n * ED + lane * 4));
  float4 out = make_float4(O.x * inv + sk.x, O.y * inv + sk.y,
                           O.z * inv + sk.z, O.w * inv + sk.w);
  *(ushort4*)(qh + (size_t)n * ED + lane * 4) =
      make_ushort4(bf16_rne(out.x), bf16_rne(out.y), bf16_rne(out.z), bf16_rne(out.w));
  float4 wg = *(const float4*)(Wg + lane * 4);
  float ps = out.x * wg.x + out.y * wg.y + out.z * wg.z + out.w * wg.w;
  #pragma unroll
  for (int o = 1; o <= 16; o <<= 1) ps += __shfl_xor(ps, o, 64);
  if (lane == 0) gateOut[n] = ps + bg[0];
}

// ============ GCN gather (fp32): 4 nodes x 32 float4-lanes ============
__global__ void __launch_bounds__(128)
gcn_gather_k(const float* __restrict__ x, const float* __restrict__ dinv,
             const int* __restrict__ offs, const int* __restrict__ csr,
             const float* __restrict__ bias, float* __restrict__ out,
             const float* __restrict__ Wg, const float* __restrict__ bg,
             float* __restrict__ gateOut) {
  const int g = threadIdx.x >> 5, lane = threadIdx.x & 31;
  const int n = blockIdx.x * 4 + g;
  float di = dinv[n];
  float4 xs = *(const float4*)(x + (size_t)n * ED + lane * 4);
  float w0 = di * di;
  float4 acc = make_float4(w0 * xs.x, w0 * xs.y, w0 * xs.z, w0 * xs.w);
  int lo = offs[n], hi = offs[n + 1];
  for (int e = lo; e < hi; ++e) {
    int s = csr[e];
    float w = di * dinv[s];
    float4 v = *(const float4*)(x + (size_t)s * ED + lane * 4);
    acc.x = fmaf(w, v.x, acc.x); acc.y = fmaf(w, v.y, acc.y);
    acc.z = fmaf(w, v.z, acc.z); acc.w = fmaf(w, v.w, acc.w);
  }
  if (bias) {
    float4 b4 = *(const float4*)(bias + lane * 4);
    acc.x += b4.x; acc.y += b4.y; acc.z += b4.z; acc.w += b4.w;
  }
  *(float4*)(out + (size_t)n * ED + lane * 4) = acc;
  if (gateOut) {
    float4 wg = *(const float4*)(Wg + lane * 4);
    float ps = acc.x * wg.x + acc.y * wg.y + acc.z * wg.z + acc.w * wg.w;
    #pragma unroll
    for (int o = 1; o <= 16; o <<= 1) ps += __shfl_xor(ps, o, 64);
    if (lane == 0) gateOut[n] = ps + bg[0];
  }
}

// ============ global attention over contiguous (sorted) segments ============
static __device__ __forceinline__ int lower_bound_d(const int* a, int n, int key) {
  int lo = 0, hi = n;
  while (lo < hi) { int mid = (lo + hi) >> 1; if (a[mid] < key) lo = mid + 1; else hi = mid; }
  return lo;
}
template<bool COMBINE, bool XBF>
__global__ void __launch_bounds__(128)
gattn_k(const void* __restrict__ xv, const float* __restrict__ gate,
        const int* __restrict__ seg, int Ntot,
        const float* __restrict__ other, float* __restrict__ out) {
  const int g = threadIdx.x >> 5, lane = threadIdx.x & 31;
  const int n = blockIdx.x * 4 + g;
  __shared__ int sh[4][2];
  if (lane == 0) {
    sh[g][0] = lower_bound_d(seg, Ntot, n);
    sh[g][1] = lower_bound_d(seg, Ntot, n + 1);
  }
  __syncthreads();
  int lo = sh[g][0], hi = sh[g][1];
  float m = -INFINITY;
  for (int j = lo; j < hi; ++j) m = fmaxf(m, gate[j]);
  float ssum = 0.f;
  for (int j = lo; j < hi; ++j) ssum += __expf(gate[j] - m);
  float inv = 1.f / (ssum + 1e-16f);
  float4 acc = make_float4(0.f, 0.f, 0.f, 0.f);
  for (int j = lo; j < hi; ++j) {
    float a = __expf(gate[j] - m) * inv;
    float4 v;
    if (XBF) v = b4f(*((const ushort4*)((const unsigned short*)xv + (size_t)j * ED + lane * 4)));
    else     v = *((const float4*)((const float*)xv + (size_t)j * ED) + lane);
    acc.x = fmaf(a, v.x, acc.x); acc.y = fmaf(a, v.y, acc.y);
    acc.z = fmaf(a, v.z, acc.z); acc.w = fmaf(a, v.w, acc.w);
  }
  if (COMBINE) {
    float4 o4 = *(const float4*)(other + (size_t)n * ED + lane * 4);
    acc.x = (acc.x + o4.x) * 0.5f; acc.y = (acc.y + o4.y) * 0.5f;
    acc.z = (acc.z + o4.z) * 0.5f; acc.w = (acc.w + o4.w) * 0.5f;
  }
  *(float4*)(out + (size_t)n * ED + lane * 4) = acc;
}

// ---- cosine similarity: one wave per batch row ----
__global__ void cosine_k(const float* __restrict__ a, const float* __restrict__ b,
                         float* __restrict__ out) {
  int n = blockIdx.x, lane = threadIdx.x;
  float x0 = a[(size_t)n * ED + lane], x1 = a[(size_t)n * ED + 64 + lane];
  float y0 = b[(size_t)n * ED + lane], y1 = b[(size_t)n * ED + 64 + lane];
  float dot = x0 * y0 + x1 * y1;
  float na = x0 * x0 + x1 * x1;
  float nb = y0 * y0 + y1 * y1;
  #pragma unroll
  for (int o = 32; o > 0; o >>= 1) {
    dot += __shfl_down(dot, o, 64);
    na  += __shfl_down(na,  o, 64);
    nb  += __shfl_down(nb,  o, 64);
  }
  if (lane == 0)
    out[n] = dot / (fmaxf(sqrtf(na), 1e-8f) * fmaxf(sqrtf(nb), 1e-8f));
}

// ---- workspace layout (4-byte element offsets) ----
constexpr size_t OFF_HN    = 0;                                  // BB*ED
constexpr size_t OFF_STMT  = OFF_HN    + (size_t)BB * ED;        // NO*ED
constexpr size_t OFF_A     = OFF_STMT  + (size_t)NO * ED;        // NM*ED (miniE bf16 -> recycled)
constexpr size_t OFF_QHID  = OFF_A     + (size_t)NM * ED;        // NM*ED floats (bf16 q->hid in half)
constexpr size_t OFF_K     = OFF_QHID  + (size_t)NM * ED;        // NM*ED floats (bf16 k + bf16 skip)
constexpr size_t OFF_V     = OFF_K     + (size_t)NM * ED;        // NM*ED floats (bf16 v in half)
constexpr size_t T0        = OFF_V     + (size_t)NM * ED;
constexpr size_t OFF_GATE  = T0;                                 // NM
constexpr size_t OFF_GATE2 = OFF_GATE  + (size_t)NM;             // NO
constexpr size_t OFF_FNREP = OFF_GATE2 + (size_t)NO;             // BB*ED
constexpr size_t OFF_DINV  = OFF_FNREP + (size_t)BB * ED;        // NO
constexpr size_t OFF_HISTM = OFF_DINV  + (size_t)NO;             // NM (int)
constexpr size_t OFF_OFFSM = OFF_HISTM + (size_t)NM;             // NM+1
constexpr size_t OFF_CURM  = OFF_OFFSM + (size_t)NM + 1;         // NM
constexpr size_t OFF_CSRM  = OFF_CURM  + (size_t)NM;             // EM
constexpr size_t OFF_HISTO = OFF_CSRM  + (size_t)EM;             // NO
constexpr size_t OFF_OFFSO = OFF_HISTO + (size_t)NO;             // NO+1
constexpr size_t OFF_CURO  = OFF_OFFSO + (size_t)NO + 1;         // NO
constexpr size_t OFF_CSRO  = OFF_CURO  + (size_t)NO;             // EO
constexpr size_t OFF_PART  = OFF_CSRO  + (size_t)EO;             // 512 (int)
constexpr size_t OFF_WFHI  = OFF_PART  + 512;                    // 65536 floats
constexpr size_t OFF_WFLO  = OFF_WFHI  + 65536;                  // 65536 floats
constexpr size_t OFF_TBF   = OFF_WFLO  + 65536;                  // V*ED/2 floats (bf16 code_table)
constexpr size_t WO_Q  = 0, WO_K = 2048, WO_V = 4096, WO_S = 6144, WO_W2 = 8192, WO_W3 = 12288;
// region-A recycling after attn (miniE dead):
constexpr size_t OFF_MFN   = OFF_A;                              // NO*ED
constexpr size_t OFF_AGG   = OFF_MFN   + (size_t)NO * ED;        // NO*ED
constexpr size_t OFF_H     = OFF_AGG   + (size_t)NO * ED;        // NO*HIDD
constexpr size_t OFF_T     = OFF_H     + (size_t)NO * HIDD;      // NO*ED
constexpr size_t OFF_FIN   = OFF_T     + (size_t)NO * ED;        // NO*ED

extern "C" void kernel_launch(void* const* d_in, const int* in_sizes, int n_in,
                              void* d_out, int out_size, void* d_ws, size_t ws_size,
                              hipStream_t stream) {
  const int* desc_tokens = (const int*)d_in[0];
  const int* x_tokens    = (const int*)d_in[1];
  const int* mini_tokens = (const int*)d_in[2];
  const int* src         = (const int*)d_in[3];
  const int* dst         = (const int*)d_in[4];
  const int* mini_src    = (const int*)d_in[5];
  const int* mini_dst    = (const int*)d_in[6];
  const int* mini_batch  = (const int*)d_in[7];
  const int* node_batch  = (const int*)d_in[8];
  const float* desc_table  = (const float*)d_in[9];
  const float* code_table  = (const float*)d_in[10];
  const float* code_table2 = (const float*)d_in[11];
  const float* Wq = (const float*)d_in[12]; const float* bq = (const float*)d_in[13];
  const float* Wk = (const float*)d_in[14]; const float* bk = (const float*)d_in[15];
  const float* Wv = (const float*)d_in[16]; const float* bv = (const float*)d_in[17];
  const float* Wskip = (const float*)d_in[18]; const float* bskip = (const float*)d_in[19];
  const float* W2 = (const float*)d_in[20]; const float* b2 = (const float*)d_in[21];
  const float* W3 = (const float*)d_in[22]; const float* b3 = (const float*)d_in[23];
  const float* Wg = (const float*)d_in[24]; const float* bg = (const float*)d_in[25];

  float* ws = (float*)d_ws;
  float* h_n   = ws + OFF_HN;
  float* stmt  = ws + OFF_STMT;
  unsigned short* miniE_b = (unsigned short*)(ws + OFF_A);    // bf16 [NM][128]
  unsigned short* qhid_b = (unsigned short*)(ws + OFF_QHID);  // q -> hid, bf16
  unsigned short* kbuf_b = (unsigned short*)(ws + OFF_K);     // k, bf16
  unsigned short* skip_b = kbuf_b + (size_t)NM * ED;          // skip, bf16 (2nd half)
  unsigned short* vbuf_b = (unsigned short*)(ws + OFF_V);     // v, bf16
  float* gate  = ws + OFF_GATE;
  float* gate2 = ws + OFF_GATE2;
  float* fnrep = ws + OFF_FNREP;
  float* dinv  = ws + OFF_DINV;
  int* histm = (int*)(ws + OFF_HISTM);
  int* offsm = (int*)(ws + OFF_OFFSM);
  int* curm  = (int*)(ws + OFF_CURM);
  int* csrm  = (int*)(ws + OFF_CSRM);
  int* histo = (int*)(ws + OFF_HISTO);
  int* offso = (int*)(ws + OFF_OFFSO);
  int* curo  = (int*)(ws + OFF_CURO);
  int* csro  = (int*)(ws + OFF_CSRO);
  int* part  = (int*)(ws + OFF_PART);
  short8* wfhi = (short8*)(ws + OFF_WFHI);
  short8* wflo = (short8*)(ws + OFF_WFLO);
  unsigned short* ctab_b = (unsigned short*)(ws + OFF_TBF);
  float* mini_fn = ws + OFF_MFN;
  float* aggb    = ws + OFF_AGG;
  float* hbuf    = ws + OFF_H;
  float* tbuf    = ws + OFF_T;
  float* finalS  = ws + OFF_FIN;
  float* outp    = (float*)d_out;

  // ---- weight fragment conversion + code_table bf16 (tiny) ----
  wconv_k<<<8, 256, 0, stream>>>(Wq,    ED,   ED,   wfhi + WO_Q,  wflo + WO_Q);
  wconv_k<<<8, 256, 0, stream>>>(Wk,    ED,   ED,   wfhi + WO_K,  wflo + WO_K);
  wconv_k<<<8, 256, 0, stream>>>(Wv,    ED,   ED,   wfhi + WO_V,  wflo + WO_V);
  wconv_k<<<8, 256, 0, stream>>>(Wskip, ED,   ED,   wfhi + WO_S,  wflo + WO_S);
  wconv_k<<<16, 256, 0, stream>>>(W2,   ED,   HIDD, wfhi + WO_W2, wflo + WO_W2);
  wconv_k<<<16, 256, 0, stream>>>(W3,   HIDD, ED,   wfhi + WO_W3, wflo + WO_W3);
  tconv_k<<<nblk(VV * ED / 4, 256), 256, 0, stream>>>(code_table, ctab_b, VV * ED / 4);

  // ---- CSR build: merged hist + scans + merged scatter + degrees ----
  hipMemsetAsync(histm, 0, (size_t)NM * 4, stream);
  hipMemsetAsync(histo, 0, (size_t)NO * 4, stream);
  hist2_k<<<nblk(EM + EO, 256), 256, 0, stream>>>(mini_dst, histm, dst, histo);
  chunk_sum_k<<<NM / 256, 256, 0, stream>>>(histm, part, NM);
  scan_partials_k<<<1, 512, 0, stream>>>(part, NM / 256);
  scan_final_k<<<NM / 256, 256, 0, stream>>>(histm, part, offsm, curm, NM);
  chunk_sum_k<<<NO / 256, 256, 0, stream>>>(histo, part, NO);
  scan_partials_k<<<1, 512, 0, stream>>>(part, NO / 256);
  scan_final_k<<<NO / 256, 256, 0, stream>>>(histo, part, offso, curo, NO);
  scatter2_k<<<nblk(EM + EO, 256), 256, 0, stream>>>(mini_src, mini_dst, curm, csrm,
                                                     src, dst, curo, csro);
  dinv_k<<<nblk(NO, 256), 256, 0, stream>>>(histo, dinv, NO);

  // ---- embeddings ----
  embed_mean_k<LDE, false, false><<<BB / 8, 256, 0, stream>>>(desc_tokens, desc_table, h_n);
  embed_mean_k<LO,  false, false><<<NO / 8, 256, 0, stream>>>(x_tokens, code_table2, stmt);
  embed_mean_k<LM,  true,  true ><<<NM / 8, 256, 0, stream>>>(mini_tokens, ctab_b, miniE_b);

  // ---- Q,K,V,Skip projections: bf16 A staged once, 4 matrices per block ----
  QDesc4 g4;
  g4.d[0] = {wfhi + WO_Q, wflo + WO_Q, bq,    qhid_b};
  g4.d[1] = {wfhi + WO_K, wflo + WO_K, bk,    kbuf_b};
  g4.d[2] = {wfhi + WO_V, wflo + WO_V, bv,    vbuf_b};
  g4.d[3] = {wfhi + WO_S, wflo + WO_S, bskip, skip_b};
  mgemm_qkvs2_k<<<NM / 128, 256, 0, stream>>>(miniE_b, g4);

  // ---- fused transformer conv (flash per dst, bf16 streams) + gate ----
  attn_fused_k<<<NM / 4, 128, 0, stream>>>(qhid_b, kbuf_b, vbuf_b, skip_b,
                                           offsm, csrm, Wg, bg, gate);

  // ---- global attention mini -> NO, fused with (x + stmt)*0.5 ----
  gattn_k<true, true><<<NO / 4, 128, 0, stream>>>(qhid_b, gate, mini_batch, NM, stmt, mini_fn);

  // ---- GCN conv 1: agg = A_hat * mini_fn ; h = relu(agg @ W2 + b2) ----
  gcn_gather_k<<<NO / 4, 128, 0, stream>>>(mini_fn, dinv, offso, csro, nullptr, aggb,
                                           nullptr, nullptr, nullptr);
  { dim3 g(HIDD / 128, NO / 128);
    mgemm_k<true><<<g, 256, 0, stream>>>(aggb, wfhi + WO_W2, wflo + WO_W2, b2, hbuf, ED, HIDD); }

  // ---- GCN conv 2: t = h @ W3 ; final = A_hat * t + b3 (+ fused gate2) ----
  { dim3 g(1, NO / 128);
    mgemm_k<false><<<g, 256, 0, stream>>>(hbuf, wfhi + WO_W3, wflo + WO_W3, nullptr, tbuf, HIDD, ED); }
  gcn_gather_k<<<NO / 4, 128, 0, stream>>>(tbuf, dinv, offso, csro, b3, finalS, Wg, bg, gate2);

  // ---- global attention NO -> BB ----
  gattn_k<false, false><<<BB / 4, 128, 0, stream>>>(finalS, gate2, node_batch, NO, nullptr, fnrep);

  // ---- cosine similarity -> d_out [BB] ----
  cosine_k<<<BB, 64, 0, stream>>>(fnrep, h_n, outp);
}

// Round 8
// 385.162 us; speedup vs baseline: 3.7960x; 1.1126x over previous
//
#include <hip/hip_runtime.h>
#include <hip/hip_bf16.h>
#include <math.h>

// Problem dims (fixed by reference)
#define BB   256      // batch
#define LDE  64       // desc tokens len
#define NO   10240    // outer nodes
#define LO   32       // x tokens len
#define NM   81920    // mini nodes
#define LM   16       // mini tokens len
#define EO   81920    // outer edges
#define EM   327680   // mini edges
#define ED   128      // embed dim E
#define HIDD 256      // hidden
#define NH   8        // heads
#define DH   16       // head dim
#define VV   10000    // vocab

static inline int nblk(long long n, int b) { return (int)((n + b - 1) / b); }

typedef __attribute__((ext_vector_type(8))) short short8;
typedef __attribute__((ext_vector_type(4))) float f32x4;

// ---- fp32 <-> bf16 (RNE) helpers ----
static __device__ __forceinline__ unsigned short bf16_rne(float f) {
  unsigned u = __float_as_uint(f);
  return (unsigned short)((u + 0x7fffu + ((u >> 16) & 1u)) >> 16);
}
static __device__ __forceinline__ float bf16_to_f(unsigned short h) {
  return __uint_as_float(((unsigned)h) << 16);
}
static __device__ __forceinline__ float4 b4f(ushort4 h) {
  return make_float4(bf16_to_f(h.x), bf16_to_f(h.y), bf16_to_f(h.z), bf16_to_f(h.w));
}

// ============ merged conversion kernel: 6 weights -> split-bf16 frags, 2 tables -> bf16
struct WC { const float* W; int K, M; short8* hi; short8* lo; int base; };
struct WC6 { WC w[6]; };
// blocks [0,64): weight octets (16384 total). blocks [64,...): table quads (640000).
__global__ void __launch_bounds__(256)
conv_all_k(WC6 wc, const float* __restrict__ t1, unsigned short* __restrict__ o1,
           const float* __restrict__ t2, unsigned short* __restrict__ o2) {
  if (blockIdx.x < 64) {
    int g = blockIdx.x * 256 + threadIdx.x;   // octet id, 0..16383
    int wi = 0;
    #pragma unroll
    for (int i = 1; i < 6; ++i) if (g >= wc.w[i].base) wi = i;
    const WC c = wc.w[wi];
    int idx = g - c.base;
    int lane = idx & 63;
    int nt = (idx >> 6) % (c.M / 16);
    int kb = (idx >> 6) / (c.M / 16);
    int n = nt * 16 + (lane & 15);
    int k0 = kb * 32 + ((lane >> 4) << 3);
    short8 h, l;
    #pragma unroll
    for (int j = 0; j < 8; ++j) {
      float v = c.W[(size_t)(k0 + j) * c.M + n];
      unsigned short hb = bf16_rne(v);
      h[j] = (short)hb;
      l[j] = (short)bf16_rne(v - bf16_to_f(hb));
    }
    c.hi[idx] = h; c.lo[idx] = l;
  } else {
    int q = (blockIdx.x - 64) * 256 + threadIdx.x;   // quad id
    const int NT = VV * ED / 4;                       // 320000 per table
    if (q < NT) {
      float4 v = *(const float4*)(t1 + (size_t)q * 4);
      *(ushort4*)(o1 + (size_t)q * 4) =
          make_ushort4(bf16_rne(v.x), bf16_rne(v.y), bf16_rne(v.z), bf16_rne(v.w));
    } else if (q < 2 * NT) {
      int q2 = q - NT;
      float4 v = *(const float4*)(t2 + (size_t)q2 * 4);
      *(ushort4*)(o2 + (size_t)q2 * 4) =
          make_ushort4(bf16_rne(v.x), bf16_rne(v.y), bf16_rne(v.z), bf16_rne(v.w));
    }
  }
}

// ---- embedding masked mean body: 256 thr = 8 rows x 32 4-elem lanes ----
template<int L, bool TBF, bool OUTBF>
static __device__ __forceinline__ void embed_body(const int* __restrict__ tokens,
                                                  const void* __restrict__ table,
                                                  void* __restrict__ out, int blk) {
  const int r = threadIdx.x >> 5, lane = threadIdx.x & 31;
  const int n0 = blk * 8;
  __shared__ int toks[8][L];
  for (int i = threadIdx.x; i < 8 * L; i += 256)
    toks[i / L][i % L] = tokens[(size_t)n0 * L + i];
  __syncthreads();
  float4 acc = make_float4(0.f, 0.f, 0.f, 0.f);
  int cnt = 0;
  #pragma unroll
  for (int l = 0; l < L; ++l) {
    int t = toks[r][l];
    float4 v;
    if (TBF) v = b4f(*((const ushort4*)((const unsigned short*)table + (size_t)t * ED + lane * 4)));
    else     v = *(const float4*)((const float*)table + (size_t)t * ED + lane * 4);
    float msk = (t != 0) ? 1.f : 0.f;
    cnt += (t != 0);
    acc.x = fmaf(msk, v.x, acc.x); acc.y = fmaf(msk, v.y, acc.y);
    acc.z = fmaf(msk, v.z, acc.z); acc.w = fmaf(msk, v.w, acc.w);
  }
  float inv = 1.f / (float)(cnt > 0 ? cnt : 1);
  acc.x *= inv; acc.y *= inv; acc.z *= inv; acc.w *= inv;
  if (OUTBF)
    *(ushort4*)((unsigned short*)out + (size_t)(n0 + r) * ED + lane * 4) =
        make_ushort4(bf16_rne(acc.x), bf16_rne(acc.y), bf16_rne(acc.z), bf16_rne(acc.w));
  else
    *(float4*)((float*)out + (size_t)(n0 + r) * ED + lane * 4) = acc;
}

// all three embeddings in one launch: [0,32) desc | [32,1312) x | [1312,11552) mini
__global__ void __launch_bounds__(256)
embed_all_k(const int* __restrict__ desc_tokens, const float* __restrict__ desc_table,
            float* __restrict__ h_n,
            const int* __restrict__ x_tokens, const unsigned short* __restrict__ ctab2,
            float* __restrict__ stmt,
            const int* __restrict__ mini_tokens, const unsigned short* __restrict__ ctab,
            unsigned short* __restrict__ miniE) {
  int b = blockIdx.x;
  if (b < BB / 8) embed_body<LDE, false, false>(desc_tokens, desc_table, h_n, b);
  else if (b < BB / 8 + NO / 8) embed_body<LO, true, false>(x_tokens, ctab2, stmt, b - BB / 8);
  else embed_body<LM, true, true>(mini_tokens, ctab, miniE, b - BB / 8 - NO / 8);
}

// ========== QKVS GEMM: grid (4 matrices, NM/128 row-blocks); A bf16 staged to LDS =====
struct QDesc { const short8* bh; const short8* bl; const float* bias; unsigned short* C; };
struct QDesc4 { QDesc d[4]; };

__global__ void __launch_bounds__(256)
mgemm_qkvs3_k(const unsigned short* __restrict__ Ab, QDesc4 g4) {
  const QDesc d = g4.d[blockIdx.x];
  __shared__ unsigned short Asl[128][136];   // +8 pad
  const int tid = threadIdx.x;
  const int n0 = blockIdx.y * 128;
  #pragma unroll
  for (int i = 0; i < 8; ++i) {
    int c = tid + i * 256;
    int row = c >> 4, koct = c & 15;
    *(short8*)&Asl[row][koct * 8] =
        *(const short8*)(Ab + (size_t)(n0 + row) * ED + koct * 8);
  }
  __syncthreads();
  const int w = tid >> 6, lane = tid & 63;
  const int wm = (w & 1) * 4, wn = (w >> 1) * 4;
  const int r = lane & 15, qd = lane >> 4;
  f32x4 acc[4][4];
  #pragma unroll
  for (int i = 0; i < 4; ++i)
    #pragma unroll
    for (int j = 0; j < 4; ++j) acc[i][j] = (f32x4){0.f, 0.f, 0.f, 0.f};
  #pragma unroll
  for (int kb = 0; kb < 4; ++kb) {
    short8 bh[4], bl[4];
    #pragma unroll
    for (int j = 0; j < 4; ++j) {
      size_t bi = ((size_t)kb * 8 + wn + j) * 64 + lane;
      bh[j] = d.bh[bi]; bl[j] = d.bl[bi];
    }
    #pragma unroll
    for (int i = 0; i < 4; ++i) {
      short8 a = *(const short8*)&Asl[(wm + i) * 16 + r][kb * 32 + qd * 8];
      #pragma unroll
      for (int j = 0; j < 4; ++j) {
        acc[i][j] = __builtin_amdgcn_mfma_f32_16x16x32_bf16(a, bh[j], acc[i][j], 0, 0, 0);
        acc[i][j] = __builtin_amdgcn_mfma_f32_16x16x32_bf16(a, bl[j], acc[i][j], 0, 0, 0);
      }
    }
  }
  #pragma unroll
  for (int i = 0; i < 4; ++i)
    #pragma unroll
    for (int j = 0; j < 4; ++j) {
      int col = (wn + j) * 16 + r;
      float bv = d.bias[col];
      #pragma unroll
      for (int rr = 0; rr < 4; ++rr) {
        int row = (wm + i) * 16 + qd * 4 + rr;
        d.C[(size_t)(n0 + row) * ED + col] = bf16_rne(acc[i][j][rr] + bv);
      }
    }
}

// ================= MFMA GEMM (fp32 A, split-bf16 3-term): W2 / W3 path ==============
template<bool RELU>
__global__ void __launch_bounds__(256)
mgemm_k(const float* __restrict__ A, const short8* __restrict__ Bh,
        const short8* __restrict__ Bl, const float* __restrict__ bias,
        float* C, int K, int M) {
  __shared__ short8 Ah[8][64];
  __shared__ short8 Al[8][64];
  const int bm0 = blockIdx.y * 128, bn0 = blockIdx.x * 128;
  const int tid = threadIdx.x;
  const int w = tid >> 6, lane = tid & 63;
  const int wm = (w & 1) * 4, wn = (w >> 1) * 4;
  const int NTm = M / 16;
  f32x4 acc[4][4];
  #pragma unroll
  for (int i = 0; i < 4; ++i)
    #pragma unroll
    for (int j = 0; j < 4; ++j) acc[i][j] = (f32x4){0.f, 0.f, 0.f, 0.f};
  const int kbn = K / 32;
  for (int kb = 0; kb < kbn; ++kb) {
    __syncthreads();
    #pragma unroll
    for (int it = 0; it < 2; ++it) {
      int u = tid + it * 256;
      int mt = u >> 6, l = u & 63;
      int m = bm0 + mt * 16 + (l & 15);
      int k = kb * 32 + ((l >> 4) << 3);
      const float* ap = A + (size_t)m * K + k;
      float4 v0 = *(const float4*)ap;
      float4 v1 = *(const float4*)(ap + 4);
      float f[8] = {v0.x, v0.y, v0.z, v0.w, v1.x, v1.y, v1.z, v1.w};
      short8 hh, ll;
      #pragma unroll
      for (int j = 0; j < 8; ++j) {
        unsigned short hb = bf16_rne(f[j]);
        hh[j] = (short)hb;
        ll[j] = (short)bf16_rne(f[j] - bf16_to_f(hb));
      }
      Ah[mt][l] = hh; Al[mt][l] = ll;
    }
    __syncthreads();
    short8 bh[4], bl[4];
    #pragma unroll
    for (int j = 0; j < 4; ++j) {
      size_t bi = ((size_t)kb * NTm + (bn0 >> 4) + wn + j) * 64 + lane;
      bh[j] = Bh[bi]; bl[j] = Bl[bi];
    }
    #pragma unroll
    for (int i = 0; i < 4; ++i) {
      short8 ah = Ah[wm + i][lane];
      short8 al = Al[wm + i][lane];
      #pragma unroll
      for (int j = 0; j < 4; ++j) {
        acc[i][j] = __builtin_amdgcn_mfma_f32_16x16x32_bf16(ah, bh[j], acc[i][j], 0, 0, 0);
        acc[i][j] = __builtin_amdgcn_mfma_f32_16x16x32_bf16(ah, bl[j], acc[i][j], 0, 0, 0);
        acc[i][j] = __builtin_amdgcn_mfma_f32_16x16x32_bf16(al, bh[j], acc[i][j], 0, 0, 0);
      }
    }
  }
  const int q = lane >> 4, c = lane & 15;
  #pragma unroll
  for (int i = 0; i < 4; ++i)
    #pragma unroll
    for (int j = 0; j < 4; ++j) {
      int col = bn0 + (wn + j) * 16 + c;
      float bv = bias ? bias[col] : 0.f;
      #pragma unroll
      for (int rr = 0; rr < 4; ++rr) {
        int row = bm0 + (wm + i) * 16 + q * 4 + rr;
        float v = acc[i][j][rr] + bv;
        if (RELU) v = fmaxf(v, 0.f);
        C[(size_t)row * M + col] = v;
      }
    }
}

// ================= CSR build =================
__global__ void hist2_k(const int* __restrict__ dm, int* __restrict__ hm,
                        const int* __restrict__ dd, int* __restrict__ ho) {
  int e = blockIdx.x * 256 + threadIdx.x;
  if (e < EM) atomicAdd(&hm[dm[e]], 1);
  else { int e2 = e - EM; if (e2 < EO) atomicAdd(&ho[dd[e2]], 1); }
}
__global__ void chunk_sum_k(const int* __restrict__ hist, int* __restrict__ partials, int N) {
  __shared__ int sd[256];
  int i = blockIdx.x * 256 + threadIdx.x;
  sd[threadIdx.x] = (i < N) ? hist[i] : 0;
  __syncthreads();
  for (int s = 128; s > 0; s >>= 1) {
    if (threadIdx.x < s) sd[threadIdx.x] += sd[threadIdx.x + s];
    __syncthreads();
  }
  if (threadIdx.x == 0) partials[blockIdx.x] = sd[0];
}
__global__ void scan_partials_k(int* __restrict__ p, int B) {  // one block, 512 thr
  __shared__ int sd[512];
  int t = threadIdx.x;
  int v = (t < B) ? p[t] : 0;
  sd[t] = v; __syncthreads();
  for (int off = 1; off < 512; off <<= 1) {
    int a = (t >= off) ? sd[t - off] : 0;
    __syncthreads();
    sd[t] += a;
    __syncthreads();
  }
  if (t < B) p[t] = sd[t] - v;   // exclusive
}
// optional fused dinv output (GCN degree normalization)
__global__ void scan_final_k(const int* __restrict__ hist, const int* __restrict__ partials,
                             int* __restrict__ offs, int* __restrict__ cursor, int N,
                             float* __restrict__ dinv) {
  __shared__ int sd[256];
  int i = blockIdx.x * 256 + threadIdx.x;
  int v = (i < N) ? hist[i] : 0;
  sd[threadIdx.x] = v; __syncthreads();
  for (int off = 1; off < 256; off <<= 1) {
    int a = (threadIdx.x >= off) ? sd[threadIdx.x - off] : 0;
    __syncthreads();
    sd[threadIdx.x] += a;
    __syncthreads();
  }
  if (i < N) {
    int excl = sd[threadIdx.x] - v + partials[blockIdx.x];
    offs[i] = excl;
    cursor[i] = excl;
    if (i == N - 1) offs[N] = excl + v;
    if (dinv) dinv[i] = 1.f / sqrtf(1.f + (float)v);
  }
}
__global__ void scatter2_k(const int* __restrict__ sm, const int* __restrict__ dm,
                           int* __restrict__ cm, int* __restrict__ km,
                           const int* __restrict__ so, const int* __restrict__ dd,
                           int* __restrict__ co, int* __restrict__ ko) {
  int e = blockIdx.x * 256 + threadIdx.x;
  if (e < EM) {
    int pos = atomicAdd(&cm[dm[e]], 1);
    km[pos] = sm[e];
  } else {
    int e2 = e - EM;
    if (e2 < EO) {
      int pos = atomicAdd(&co[dd[e2]], 1);
      ko[pos] = so[e2];
    }
  }
}

// ============ fused TransformerConv (bf16 streams): flash per dst + skip + gate ======
__global__ void __launch_bounds__(128)
attn_fused_k(unsigned short* qh, const unsigned short* __restrict__ kk,
             const unsigned short* __restrict__ vv, const unsigned short* __restrict__ skip,
             const int* __restrict__ offs, const int* __restrict__ csr,
             const float* __restrict__ Wg, const float* __restrict__ bg,
             float* __restrict__ gateOut) {
  const int g = threadIdx.x >> 5, lane = threadIdx.x & 31;
  const int n = blockIdx.x * 4 + g;
  float4 q = b4f(*(const ushort4*)(qh + (size_t)n * ED + lane * 4));
  int lo = offs[n], hi = offs[n + 1];
  float4 O = make_float4(0.f, 0.f, 0.f, 0.f);
  float m = -INFINITY, l = 0.f;
  for (int e = lo; e < hi; ++e) {
    int s = csr[e];
    float4 kt = b4f(*(const ushort4*)(kk + (size_t)s * ED + lane * 4));
    float4 vt = b4f(*(const ushort4*)(vv + (size_t)s * ED + lane * 4));
    float p = q.x * kt.x + q.y * kt.y + q.z * kt.z + q.w * kt.w;
    p += __shfl_xor(p, 1, 64);
    p += __shfl_xor(p, 2, 64);
    float sc = p * 0.25f;               // 1/sqrt(Dh)
    float mn = fmaxf(m, sc);
    float scale = __expf(m - mn);       // exp(-inf)=0 handles first edge
    float pe = __expf(sc - mn);
    l = l * scale + pe;
    O.x = O.x * scale + pe * vt.x; O.y = O.y * scale + pe * vt.y;
    O.z = O.z * scale + pe * vt.z; O.w = O.w * scale + pe * vt.w;
    m = mn;
  }
  float inv = 1.f / (l + 1e-16f);
  float4 sk = b4f(*(const ushort4*)(skip + (size_t)n * ED + lane * 4));
  float4 out = make_float4(O.x * inv + sk.x, O.y * inv + sk.y,
                           O.z * inv + sk.z, O.w * inv + sk.w);
  *(ushort4*)(qh + (size_t)n * ED + lane * 4) =
      make_ushort4(bf16_rne(out.x), bf16_rne(out.y), bf16_rne(out.z), bf16_rne(out.w));
  float4 wg = *(const float4*)(Wg + lane * 4);
  float ps = out.x * wg.x + out.y * wg.y + out.z * wg.z + out.w * wg.w;
  #pragma unroll
  for (int o = 1; o <= 16; o <<= 1) ps += __shfl_xor(ps, o, 64);
  if (lane == 0) gateOut[n] = ps + bg[0];
}

// ============ GCN gather (fp32): 4 nodes x 32 float4-lanes ============
__global__ void __launch_bounds__(128)
gcn_gather_k(const float* __restrict__ x, const float* __restrict__ dinv,
             const int* __restrict__ offs, const int* __restrict__ csr,
             const float* __restrict__ bias, float* __restrict__ out,
             const float* __restrict__ Wg, const float* __restrict__ bg,
             float* __restrict__ gateOut) {
  const int g = threadIdx.x >> 5, lane = threadIdx.x & 31;
  const int n = blockIdx.x * 4 + g;
  float di = dinv[n];
  float4 xs = *(const float4*)(x + (size_t)n * ED + lane * 4);
  float w0 = di * di;
  float4 acc = make_float4(w0 * xs.x, w0 * xs.y, w0 * xs.z, w0 * xs.w);
  int lo = offs[n], hi = offs[n + 1];
  for (int e = lo; e < hi; ++e) {
    int s = csr[e];
    float w = di * dinv[s];
    float4 v = *(const float4*)(x + (size_t)s * ED + lane * 4);
    acc.x = fmaf(w, v.x, acc.x); acc.y = fmaf(w, v.y, acc.y);
    acc.z = fmaf(w, v.z, acc.z); acc.w = fmaf(w, v.w, acc.w);
  }
  if (bias) {
    float4 b4 = *(const float4*)(bias + lane * 4);
    acc.x += b4.x; acc.y += b4.y; acc.z += b4.z; acc.w += b4.w;
  }
  *(float4*)(out + (size_t)n * ED + lane * 4) = acc;
  if (gateOut) {
    float4 wg = *(const float4*)(Wg + lane * 4);
    float ps = acc.x * wg.x + acc.y * wg.y + acc.z * wg.z + acc.w * wg.w;
    #pragma unroll
    for (int o = 1; o <= 16; o <<= 1) ps += __shfl_xor(ps, o, 64);
    if (lane == 0) gateOut[n] = ps + bg[0];
  }
}

// ============ global attention over contiguous (sorted) segments ============
static __device__ __forceinline__ int lower_bound_d(const int* a, int n, int key) {
  int lo = 0, hi = n;
  while (lo < hi) { int mid = (lo + hi) >> 1; if (a[mid] < key) lo = mid + 1; else hi = mid; }
  return lo;
}
template<bool COMBINE, bool XBF>
__global__ void __launch_bounds__(128)
gattn_k(const void* __restrict__ xv, const float* __restrict__ gate,
        const int* __restrict__ seg, int Ntot,
        const float* __restrict__ other, float* __restrict__ out) {
  const int g = threadIdx.x >> 5, lane = threadIdx.x & 31;
  const int n = blockIdx.x * 4 + g;
  __shared__ int sh[4][2];
  if (lane == 0) {
    sh[g][0] = lower_bound_d(seg, Ntot, n);
    sh[g][1] = lower_bound_d(seg, Ntot, n + 1);
  }
  __syncthreads();
  int lo = sh[g][0], hi = sh[g][1];
  float m = -INFINITY;
  for (int j = lo; j < hi; ++j) m = fmaxf(m, gate[j]);
  float ssum = 0.f;
  for (int j = lo; j < hi; ++j) ssum += __expf(gate[j] - m);
  float inv = 1.f / (ssum + 1e-16f);
  float4 acc = make_float4(0.f, 0.f, 0.f, 0.f);
  for (int j = lo; j < hi; ++j) {
    float a = __expf(gate[j] - m) * inv;
    float4 v;
    if (XBF) v = b4f(*((const ushort4*)((const unsigned short*)xv + (size_t)j * ED + lane * 4)));
    else     v = *((const float4*)((const float*)xv + (size_t)j * ED) + lane);
    acc.x = fmaf(a, v.x, acc.x); acc.y = fmaf(a, v.y, acc.y);
    acc.z = fmaf(a, v.z, acc.z); acc.w = fmaf(a, v.w, acc.w);
  }
  if (COMBINE) {
    float4 o4 = *(const float4*)(other + (size_t)n * ED + lane * 4);
    acc.x = (acc.x + o4.x) * 0.5f; acc.y = (acc.y + o4.y) * 0.5f;
    acc.z = (acc.z + o4.z) * 0.5f; acc.w = (acc.w + o4.w) * 0.5f;
  }
  *(float4*)(out + (size_t)n * ED + lane * 4) = acc;
}

// ---- cosine similarity: one wave per batch row ----
__global__ void cosine_k(const float* __restrict__ a, const float* __restrict__ b,
                         float* __restrict__ out) {
  int n = blockIdx.x, lane = threadIdx.x;
  float x0 = a[(size_t)n * ED + lane], x1 = a[(size_t)n * ED + 64 + lane];
  float y0 = b[(size_t)n * ED + lane], y1 = b[(size_t)n * ED + 64 + lane];
  float dot = x0 * y0 + x1 * y1;
  float na = x0 * x0 + x1 * x1;
  float nb = y0 * y0 + y1 * y1;
  #pragma unroll
  for (int o = 32; o > 0; o >>= 1) {
    dot += __shfl_down(dot, o, 64);
    na  += __shfl_down(na,  o, 64);
    nb  += __shfl_down(nb,  o, 64);
  }
  if (lane == 0)
    out[n] = dot / (fmaxf(sqrtf(na), 1e-8f) * fmaxf(sqrtf(nb), 1e-8f));
}

// ---- workspace layout (4-byte element offsets) ----
constexpr size_t OFF_HN    = 0;                                  // BB*ED
constexpr size_t OFF_STMT  = OFF_HN    + (size_t)BB * ED;        // NO*ED
constexpr size_t OFF_A     = OFF_STMT  + (size_t)NO * ED;        // NM*ED (miniE bf16 -> recycled)
constexpr size_t OFF_QHID  = OFF_A     + (size_t)NM * ED;        // NM*ED floats (bf16 q->hid in 1st half)
constexpr size_t OFF_CT    = OFF_QHID  + (size_t)NM * ED / 2;    // 2nd half of QHID: bf16 tables
constexpr size_t OFF_K     = OFF_QHID  + (size_t)NM * ED;        // NM*ED floats (bf16 k + bf16 skip)
constexpr size_t OFF_V     = OFF_K     + (size_t)NM * ED;        // NM*ED floats (bf16 v in 1st half)
constexpr size_t T0        = OFF_V     + (size_t)NM * ED;
constexpr size_t OFF_GATE  = T0;                                 // NM
constexpr size_t OFF_GATE2 = OFF_GATE  + (size_t)NM;             // NO
constexpr size_t OFF_FNREP = OFF_GATE2 + (size_t)NO;             // BB*ED
constexpr size_t OFF_DINV  = OFF_FNREP + (size_t)BB * ED;        // NO
constexpr size_t OFF_HISTM = OFF_DINV  + (size_t)NO;             // NM (int)
constexpr size_t OFF_HISTO = OFF_HISTM + (size_t)NM;             // NO (adjacent -> one memset)
constexpr size_t OFF_OFFSM = OFF_HISTO + (size_t)NO;             // NM+1
constexpr size_t OFF_CURM  = OFF_OFFSM + (size_t)NM + 1;         // NM
constexpr size_t OFF_CSRM  = OFF_CURM  + (size_t)NM;             // EM
constexpr size_t OFF_OFFSO = OFF_CSRM  + (size_t)EM;             // NO+1
constexpr size_t OFF_CURO  = OFF_OFFSO + (size_t)NO + 1;         // NO
constexpr size_t OFF_CSRO  = OFF_CURO  + (size_t)NO;             // EO
constexpr size_t OFF_PART  = OFF_CSRO  + (size_t)EO;             // 512 (int)
constexpr size_t OFF_WFHI  = OFF_PART  + 512;                    // 65536 floats
constexpr size_t OFF_WFLO  = OFF_WFHI  + 65536;                  // 65536 floats
constexpr size_t WO_Q  = 0, WO_K = 2048, WO_V = 4096, WO_S = 6144, WO_W2 = 8192, WO_W3 = 12288;
// region-A recycling after attn (miniE dead):
constexpr size_t OFF_MFN   = OFF_A;                              // NO*ED
constexpr size_t OFF_AGG   = OFF_MFN   + (size_t)NO * ED;        // NO*ED
constexpr size_t OFF_H     = OFF_AGG   + (size_t)NO * ED;        // NO*HIDD
constexpr size_t OFF_T     = OFF_H     + (size_t)NO * HIDD;      // NO*ED
constexpr size_t OFF_FIN   = OFF_T     + (size_t)NO * ED;        // NO*ED

extern "C" void kernel_launch(void* const* d_in, const int* in_sizes, int n_in,
                              void* d_out, int out_size, void* d_ws, size_t ws_size,
                              hipStream_t stream) {
  const int* desc_tokens = (const int*)d_in[0];
  const int* x_tokens    = (const int*)d_in[1];
  const int* mini_tokens = (const int*)d_in[2];
  const int* src         = (const int*)d_in[3];
  const int* dst         = (const int*)d_in[4];
  const int* mini_src    = (const int*)d_in[5];
  const int* mini_dst    = (const int*)d_in[6];
  const int* mini_batch  = (const int*)d_in[7];
  const int* node_batch  = (const int*)d_in[8];
  const float* desc_table  = (const float*)d_in[9];
  const float* code_table  = (const float*)d_in[10];
  const float* code_table2 = (const float*)d_in[11];
  const float* Wq = (const float*)d_in[12]; const float* bq = (const float*)d_in[13];
  const float* Wk = (const float*)d_in[14]; const float* bk = (const float*)d_in[15];
  const float* Wv = (const float*)d_in[16]; const float* bv = (const float*)d_in[17];
  const float* Wskip = (const float*)d_in[18]; const float* bskip = (const float*)d_in[19];
  const float* W2 = (const float*)d_in[20]; const float* b2 = (const float*)d_in[21];
  const float* W3 = (const float*)d_in[22]; const float* b3 = (const float*)d_in[23];
  const float* Wg = (const float*)d_in[24]; const float* bg = (const float*)d_in[25];

  float* ws = (float*)d_ws;
  float* h_n   = ws + OFF_HN;
  float* stmt  = ws + OFF_STMT;
  unsigned short* miniE_b = (unsigned short*)(ws + OFF_A);    // bf16 [NM][128]
  unsigned short* qhid_b = (unsigned short*)(ws + OFF_QHID);  // q -> hid, bf16
  unsigned short* ctab_b  = (unsigned short*)(ws + OFF_CT);             // bf16 code_table
  unsigned short* ctab2_b = (unsigned short*)(ws + OFF_CT + (size_t)VV * ED / 2);
  unsigned short* kbuf_b = (unsigned short*)(ws + OFF_K);     // k, bf16
  unsigned short* skip_b = kbuf_b + (size_t)NM * ED;          // skip, bf16 (2nd half)
  unsigned short* vbuf_b = (unsigned short*)(ws + OFF_V);     // v, bf16
  float* gate  = ws + OFF_GATE;
  float* gate2 = ws + OFF_GATE2;
  float* fnrep = ws + OFF_FNREP;
  float* dinv  = ws + OFF_DINV;
  int* histm = (int*)(ws + OFF_HISTM);
  int* histo = (int*)(ws + OFF_HISTO);
  int* offsm = (int*)(ws + OFF_OFFSM);
  int* curm  = (int*)(ws + OFF_CURM);
  int* csrm  = (int*)(ws + OFF_CSRM);
  int* offso = (int*)(ws + OFF_OFFSO);
  int* curo  = (int*)(ws + OFF_CURO);
  int* csro  = (int*)(ws + OFF_CSRO);
  int* part  = (int*)(ws + OFF_PART);
  short8* wfhi = (short8*)(ws + OFF_WFHI);
  short8* wflo = (short8*)(ws + OFF_WFLO);
  float* mini_fn = ws + OFF_MFN;
  float* aggb    = ws + OFF_AGG;
  float* hbuf    = ws + OFF_H;
  float* tbuf    = ws + OFF_T;
  float* finalS  = ws + OFF_FIN;
  float* outp    = (float*)d_out;

  // ---- all conversions in ONE launch: 6 weights + 2 tables ----
  WC6 wc;
  wc.w[0] = {Wq,    ED,   ED,   wfhi + WO_Q,  wflo + WO_Q,  (int)WO_Q};
  wc.w[1] = {Wk,    ED,   ED,   wfhi + WO_K,  wflo + WO_K,  (int)WO_K};
  wc.w[2] = {Wv,    ED,   ED,   wfhi + WO_V,  wflo + WO_V,  (int)WO_V};
  wc.w[3] = {Wskip, ED,   ED,   wfhi + WO_S,  wflo + WO_S,  (int)WO_S};
  wc.w[4] = {W2,    ED,   HIDD, wfhi + WO_W2, wflo + WO_W2, (int)WO_W2};
  wc.w[5] = {W3,    HIDD, ED,   wfhi + WO_W3, wflo + WO_W3, (int)WO_W3};
  conv_all_k<<<64 + nblk(2 * VV * ED / 4, 256), 256, 0, stream>>>(
      wc, code_table, ctab_b, code_table2, ctab2_b);

  // ---- CSR build: one memset (adjacent hists), merged hist/scatter, fused dinv ----
  hipMemsetAsync(histm, 0, (size_t)(NM + NO) * 4, stream);
  hist2_k<<<nblk(EM + EO, 256), 256, 0, stream>>>(mini_dst, histm, dst, histo);
  chunk_sum_k<<<NM / 256, 256, 0, stream>>>(histm, part, NM);
  scan_partials_k<<<1, 512, 0, stream>>>(part, NM / 256);
  scan_final_k<<<NM / 256, 256, 0, stream>>>(histm, part, offsm, curm, NM, nullptr);
  chunk_sum_k<<<NO / 256, 256, 0, stream>>>(histo, part, NO);
  scan_partials_k<<<1, 512, 0, stream>>>(part, NO / 256);
  scan_final_k<<<NO / 256, 256, 0, stream>>>(histo, part, offso, curo, NO, dinv);
  scatter2_k<<<nblk(EM + EO, 256), 256, 0, stream>>>(mini_src, mini_dst, curm, csrm,
                                                     src, dst, curo, csro);

  // ---- all three embeddings in one launch ----
  embed_all_k<<<BB / 8 + NO / 8 + NM / 8, 256, 0, stream>>>(
      desc_tokens, desc_table, h_n, x_tokens, ctab2_b, stmt,
      mini_tokens, ctab_b, miniE_b);

  // ---- Q,K,V,Skip projections: grid (4 matrices, 640 row-blocks), bf16 A ----
  QDesc4 g4;
  g4.d[0] = {wfhi + WO_Q, wflo + WO_Q, bq,    qhid_b};
  g4.d[1] = {wfhi + WO_K, wflo + WO_K, bk,    kbuf_b};
  g4.d[2] = {wfhi + WO_V, wflo + WO_V, bv,    vbuf_b};
  g4.d[3] = {wfhi + WO_S, wflo + WO_S, bskip, skip_b};
  { dim3 g(4, NM / 128); mgemm_qkvs3_k<<<g, 256, 0, stream>>>(miniE_b, g4); }

  // ---- fused transformer conv (flash per dst, bf16 streams) + gate ----
  attn_fused_k<<<NM / 4, 128, 0, stream>>>(qhid_b, kbuf_b, vbuf_b, skip_b,
                                           offsm, csrm, Wg, bg, gate);

  // ---- global attention mini -> NO, fused with (x + stmt)*0.5 ----
  gattn_k<true, true><<<NO / 4, 128, 0, stream>>>(qhid_b, gate, mini_batch, NM, stmt, mini_fn);

  // ---- GCN conv 1: agg = A_hat * mini_fn ; h = relu(agg @ W2 + b2) ----
  gcn_gather_k<<<NO / 4, 128, 0, stream>>>(mini_fn, dinv, offso, csro, nullptr, aggb,
                                           nullptr, nullptr, nullptr);
  { dim3 g(HIDD / 128, NO / 128);
    mgemm_k<true><<<g, 256, 0, stream>>>(aggb, wfhi + WO_W2, wflo + WO_W2, b2, hbuf, ED, HIDD); }

  // ---- GCN conv 2: t = h @ W3 ; final = A_hat * t + b3 (+ fused gate2) ----
  { dim3 g(1, NO / 128);
    mgemm_k<false><<<g, 256, 0, stream>>>(hbuf, wfhi + WO_W3, wflo + WO_W3, nullptr, tbuf, HIDD, ED); }
  gcn_gather_k<<<NO / 4, 128, 0, stream>>>(tbuf, dinv, offso, csro, b3, finalS, Wg, bg, gate2);

  // ---- global attention NO -> BB ----
  gattn_k<false, false><<<BB / 4, 128, 0, stream>>>(finalS, gate2, node_batch, NO, nullptr, fnrep);

  // ---- cosine similarity -> d_out [BB] ----
  cosine_k<<<BB, 64, 0, stream>>>(fnrep, h_n, outp);
}